// Round 1
// baseline (2001.087 us; speedup 1.0000x reference)
//
#include <hip/hip_runtime.h>
#include <hip/hip_bf16.h>
#include <math.h>

#define N_CELLS 16384
#define G_GENES 32
#define IN_DIM  2000
#define HID     1024
#define OUT_DIM 30

// lexicographic (d2, idx) compare — matches jax.lax.top_k(-d2) tie-break (lower idx wins)
__device__ __forceinline__ bool key_lt(float d1, int i1, float d2, int i2) {
  return (d1 < d2) || (d1 == d2 && i1 < i2);
}

// ---------------- mean over cells (per gene), f64 accumulate ----------------
__global__ __launch_bounds__(256) void mean_kernel(const float* __restrict__ genes,
                                                   float* __restrict__ meanv) {
  const int g = blockIdx.x;
  double acc = 0.0;
  for (int i = threadIdx.x; i < N_CELLS; i += 256) acc += (double)genes[i * G_GENES + g];
  __shared__ double red[256];
  red[threadIdx.x] = acc;
  __syncthreads();
  for (int s = 128; s > 0; s >>= 1) {
    if (threadIdx.x < s) red[threadIdx.x] += red[threadIdx.x + s];
    __syncthreads();
  }
  if (threadIdx.x == 0) meanv[g] = (float)(red[0] / (double)N_CELLS);
}

// ---------------- center genes and pre-scale by 1/sqrt(k-1) ----------------
__global__ __launch_bounds__(256) void center_kernel(const float* __restrict__ genes,
                                                     const float* __restrict__ meanv,
                                                     float* __restrict__ gcent) {
  const int i = blockIdx.x * 256 + threadIdx.x;   // over N*G = 524288 exactly
  const int g = i & 31;
  gcent[i] = (genes[i] - meanv[g]) * 0.37796447300922722721f;  // 1/sqrt(7)
}

// ---------------- brute-force kNN: one wave per cell, 4 waves/block ----------------
__global__ __launch_bounds__(256) void knn_kernel(const float* __restrict__ coords,
                                                  int* __restrict__ nidx) {
  __shared__ float2 tile[2048];
  const int lane = threadIdx.x & 63;
  const int wv   = threadIdx.x >> 6;
  const int cell = (blockIdx.x << 2) + wv;
  const float cx = coords[cell * 2 + 0];
  const float cy = coords[cell * 2 + 1];
  // exactly mirror ref: sq = x*x + y*y (separate roundings)
  const float sqi = __fadd_rn(__fmul_rn(cx, cx), __fmul_rn(cy, cy));

  float bd[8]; int bi[8];
#pragma unroll
  for (int j = 0; j < 8; ++j) { bd[j] = INFINITY; bi[j] = 0x7fffffff; }

  const float2* cc = (const float2*)coords;
  for (int base = 0; base < N_CELLS; base += 2048) {
    __syncthreads();
#pragma unroll
    for (int t = 0; t < 8; ++t) tile[threadIdx.x + t * 256] = cc[base + threadIdx.x + t * 256];
    __syncthreads();
    for (int u = 0; u < 32; ++u) {
      const int j = (u << 6) + lane;
      const float2 p = tile[j];
      const float sqj = __fadd_rn(__fmul_rn(p.x, p.x), __fmul_rn(p.y, p.y));
      const float dot = __fmaf_rn(cy, p.y, __fmul_rn(cx, p.x));  // sgemm-style fma chain, K=2
      const float d2  = __fsub_rn(__fadd_rn(sqi, sqj), __fmul_rn(2.0f, dot));
      const int gi = base + j;
      if (key_lt(d2, gi, bd[7], bi[7])) {
        float cd = d2; int ci = gi;
#pragma unroll
        for (int s2 = 0; s2 < 8; ++s2) {
          const bool sw = key_lt(cd, ci, bd[s2], bi[s2]);
          const float od2 = bd[s2]; const int oi2 = bi[s2];
          if (sw) { bd[s2] = cd; bi[s2] = ci; cd = od2; ci = oi2; }
        }
      }
    }
  }

  // butterfly merge across 64 lanes: keep 8 smallest of two sorted 8-lists
#pragma unroll
  for (int st = 1; st < 64; st <<= 1) {
    float od[8]; int oi[8];
#pragma unroll
    for (int j = 0; j < 8; ++j) { od[j] = __shfl_xor(bd[j], st, 64); oi[j] = __shfl_xor(bi[j], st, 64); }
    float nd[8]; int ni[8];
#pragma unroll
    for (int j = 0; j < 8; ++j) {   // half-cleaner: c[j] = min(a[j], b[7-j]) -> bitonic
      const bool take = key_lt(od[7 - j], oi[7 - j], bd[j], bi[j]);
      nd[j] = take ? od[7 - j] : bd[j];
      ni[j] = take ? oi[7 - j] : bi[j];
    }
#define CE_(a, b) { const bool sw_ = key_lt(nd[b], ni[b], nd[a], ni[a]); \
    if (sw_) { const float t_ = nd[a]; nd[a] = nd[b]; nd[b] = t_; \
               const int u_ = ni[a]; ni[a] = ni[b]; ni[b] = u_; } }
    CE_(0, 4) CE_(1, 5) CE_(2, 6) CE_(3, 7)
    CE_(0, 2) CE_(1, 3) CE_(4, 6) CE_(5, 7)
    CE_(0, 1) CE_(2, 3) CE_(4, 5) CE_(6, 7)
#undef CE_
#pragma unroll
    for (int j = 0; j < 8; ++j) { bd[j] = nd[j]; bi[j] = ni[j]; }
  }
  if (lane == 0) {
#pragma unroll
    for (int j = 0; j < 8; ++j) nidx[cell * 8 + j] = bi[j];
  }
}

// ---------------- Gram matrix G = A A^T (8x8) per cell, one wave per cell ----------------
__global__ __launch_bounds__(64) void gram_kernel(const float* __restrict__ gcent,
                                                  const int* __restrict__ nidx,
                                                  float* __restrict__ Gws) {
  const int cell = blockIdx.x;
  const int lane = threadIdx.x;
  __shared__ float A[8][33];
#pragma unroll
  for (int q = 0; q < 4; ++q) {
    const int e = lane + (q << 6);
    const int n = e >> 5, g = e & 31;
    const int src = nidx[cell * 8 + n];
    A[n][g] = gcent[src * G_GENES + g];
  }
  __syncthreads();
  const int i = lane >> 3, j = lane & 7;
  float acc = 0.f;
#pragma unroll
  for (int g = 0; g < 32; ++g) acc = fmaf(A[i][g], A[j][g], acc);
  Gws[cell * 64 + lane] = acc;
}

// ---------------- 8x8 Jacobi eigensolver: one CELL per LANE, static indices ----------------
__global__ __launch_bounds__(256) void jacobi_kernel(const float* __restrict__ Gws,
                                                     float* __restrict__ Vws,
                                                     float* __restrict__ lamws) {
  const int cell = blockIdx.x * 256 + threadIdx.x;
  float Gm[8][8], V[8][8];
#pragma unroll
  for (int e = 0; e < 64; ++e) Gm[e >> 3][e & 7] = Gws[cell * 64 + e];
#pragma unroll
  for (int i = 0; i < 8; ++i)
#pragma unroll
    for (int j = 0; j < 8; ++j) V[i][j] = (i == j) ? 1.0f : 0.0f;

  for (int sweep = 0; sweep < 8; ++sweep) {
#pragma unroll
    for (int p = 0; p < 7; ++p) {
#pragma unroll
      for (int q = p + 1; q < 8; ++q) {
        const float apq = Gm[p][q];
        const float app = Gm[p][p], aqq = Gm[q][q];
        float t;
        if (apq != 0.0f) {
          const float tau = (aqq - app) / (2.0f * apq);
          const float r = sqrtf(fmaf(tau, tau, 1.0f));
          t = copysignf(1.0f, tau) / (fabsf(tau) + r);
        } else {
          t = 0.0f;
        }
        const float c = 1.0f / sqrtf(fmaf(t, t, 1.0f));
        const float s = t * c;
#pragma unroll
        for (int r2 = 0; r2 < 8; ++r2) {        // rows: G <- J^T G
          const float gp = Gm[p][r2], gq = Gm[q][r2];
          Gm[p][r2] = fmaf(c, gp, -s * gq);
          Gm[q][r2] = fmaf(s, gp,  c * gq);
        }
#pragma unroll
        for (int r2 = 0; r2 < 8; ++r2) {        // cols: G <- G J
          const float gp = Gm[r2][p], gq = Gm[r2][q];
          Gm[r2][p] = fmaf(c, gp, -s * gq);
          Gm[r2][q] = fmaf(s, gp,  c * gq);
        }
#pragma unroll
        for (int r2 = 0; r2 < 8; ++r2) {        // V <- V J
          const float vp = V[r2][p], vq = V[r2][q];
          V[r2][p] = fmaf(c, vp, -s * vq);
          V[r2][q] = fmaf(s, vp,  c * vq);
        }
      }
    }
  }
#pragma unroll
  for (int e = 0; e < 64; ++e) Vws[cell * 64 + e] = V[e >> 3][e & 7];
#pragma unroll
  for (int m = 0; m < 8; ++m) lamws[cell * 8 + m] = Gm[m][m];
}

// ---------------- covet = A^T V diag(lam^-1/2) V^T A, one wave per cell ----------------
__global__ __launch_bounds__(64) void recon_kernel(const float* __restrict__ gcent,
                                                   const int* __restrict__ nidx,
                                                   const float* __restrict__ Vws,
                                                   const float* __restrict__ lamws,
                                                   float* __restrict__ covet) {
  const int cell = blockIdx.x;
  const int lane = threadIdx.x;
  __shared__ float A[8][33];
  __shared__ float Ws[8][33];
  __shared__ float Vs[64];
  __shared__ float lamS[8];
#pragma unroll
  for (int q = 0; q < 4; ++q) {
    const int e = lane + (q << 6);
    const int n = e >> 5, g = e & 31;
    const int src = nidx[cell * 8 + n];
    A[n][g] = gcent[src * G_GENES + g];
  }
  Vs[lane] = Vws[cell * 64 + lane];
  if (lane < 8) lamS[lane] = lamws[cell * 8 + lane];
  __syncthreads();

  float maxl = 0.f;
#pragma unroll
  for (int m = 0; m < 8; ++m) maxl = fmaxf(maxl, lamS[m]);
  const float thr = maxl * 1e-8f;

  // W[m][g] = (v_m . A[:,g]) * lam_m^{-1/4}  (so covet = sum_m W W^T)
#pragma unroll
  for (int q = 0; q < 4; ++q) {
    const int e = lane + (q << 6);
    const int m = e >> 5, g = e & 31;
    float acc = 0.f;
#pragma unroll
    for (int i = 0; i < 8; ++i) acc = fmaf(Vs[i * 8 + m], A[i][g], acc);
    const float l = lamS[m];
    const float scm = (l > thr) ? sqrtf(1.0f / sqrtf(l)) : 0.0f;
    Ws[m][g] = acc * scm;
  }
  __syncthreads();
#pragma unroll
  for (int r = 0; r < 16; ++r) {
    const int o = (r << 6) + lane;
    const int g = o >> 5, hh = o & 31;
    float acc = 0.f;
#pragma unroll
    for (int m = 0; m < 8; ++m) acc = fmaf(Ws[m][g], Ws[m][hh], acc);
    covet[(size_t)cell * 1024 + o] = acc;
  }
}

// ---------------- GEMM1: h = relu([x | covet] @ W1 + b1), fp32 SIMT 128x128x16 ----------------
__global__ __launch_bounds__(256) void gemm1_kernel(const float* __restrict__ x,
                                                    const float* __restrict__ cov,
                                                    const float* __restrict__ W1,
                                                    const float* __restrict__ b1,
                                                    float* __restrict__ h) {
  __shared__ float As[16][132];   // transposed A tile: As[k][m]
  __shared__ float Bs[16][132];   // Bs[k][n]
  const int tid  = threadIdx.x;
  const int row0 = blockIdx.y << 7;
  const int col0 = blockIdx.x << 7;
  const int ty = tid >> 4, tx = tid & 15;
  const int m0 = ty << 3, n0 = tx << 3;
  const int arow = tid >> 2, ac4 = (tid & 3) << 2;
  const int brow = tid >> 5, bc  = (tid & 31) << 2;

  float acc[8][8];
#pragma unroll
  for (int i = 0; i < 8; ++i)
#pragma unroll
    for (int j = 0; j < 8; ++j) acc[i][j] = 0.f;

  for (int kt = 0; kt < 189; ++kt) {            // 2000 = 125*16; 1024 = 64*16
    const int k0 = kt << 4;
    float4 av0, av1, bv0, bv1;
    if (kt < 125) {
      const float* base = x + (size_t)(row0 + arow) * IN_DIM + (k0 + ac4);
      av0 = *(const float4*)base;
      av1 = *(const float4*)(base + (size_t)64 * IN_DIM);
    } else {
      const float* base = cov + (size_t)(row0 + arow) * 1024 + (k0 - IN_DIM + ac4);
      av0 = *(const float4*)base;
      av1 = *(const float4*)(base + (size_t)64 * 1024);
    }
    {
      const float* base = W1 + (size_t)(k0 + brow) * HID + (col0 + bc);
      bv0 = *(const float4*)base;
      bv1 = *(const float4*)(base + (size_t)8 * HID);
    }
    __syncthreads();
    As[ac4 + 0][arow] = av0.x; As[ac4 + 1][arow] = av0.y;
    As[ac4 + 2][arow] = av0.z; As[ac4 + 3][arow] = av0.w;
    As[ac4 + 0][arow + 64] = av1.x; As[ac4 + 1][arow + 64] = av1.y;
    As[ac4 + 2][arow + 64] = av1.z; As[ac4 + 3][arow + 64] = av1.w;
    *(float4*)&Bs[brow][bc]     = bv0;
    *(float4*)&Bs[brow + 8][bc] = bv1;
    __syncthreads();
#pragma unroll
    for (int k = 0; k < 16; ++k) {
      float a[8], b[8];
      *(float4*)&a[0] = *(const float4*)&As[k][m0];
      *(float4*)&a[4] = *(const float4*)&As[k][m0 + 4];
      *(float4*)&b[0] = *(const float4*)&Bs[k][n0];
      *(float4*)&b[4] = *(const float4*)&Bs[k][n0 + 4];
#pragma unroll
      for (int i = 0; i < 8; ++i)
#pragma unroll
        for (int j = 0; j < 8; ++j) acc[i][j] = fmaf(a[i], b[j], acc[i][j]);
    }
  }

  float bb[8];
#pragma unroll
  for (int j = 0; j < 8; ++j) bb[j] = b1[col0 + n0 + j];
#pragma unroll
  for (int i = 0; i < 8; ++i) {
    const size_t row = (size_t)(row0 + m0 + i);
#pragma unroll
    for (int j = 0; j < 8; ++j) {
      const float v = acc[i][j] + bb[j];
      h[row * HID + (col0 + n0 + j)] = fmaxf(v, 0.f);
    }
  }
}

// ---------------- GEMM2: out = h @ W2 + b2 ----------------
__global__ __launch_bounds__(256) void gemm2_kernel(const float* __restrict__ h,
                                                    const float* __restrict__ W2,
                                                    const float* __restrict__ b2,
                                                    float* __restrict__ out) {
  const int t = blockIdx.x * 256 + threadIdx.x;
  const int n = t >> 5, o = t & 31;
  if (o >= OUT_DIM) return;
  const float* hrow = h + (size_t)n * HID;
  float acc = 0.f;
#pragma unroll 8
  for (int k = 0; k < HID; ++k) acc = fmaf(hrow[k], W2[k * OUT_DIM + o], acc);
  out[n * OUT_DIM + o] = acc + b2[o];
}

extern "C" void kernel_launch(void* const* d_in, const int* in_sizes, int n_in,
                              void* d_out, int out_size, void* d_ws, size_t ws_size,
                              hipStream_t stream) {
  (void)in_sizes; (void)n_in; (void)out_size;
  const float* x      = (const float*)d_in[0];
  const float* coords = (const float*)d_in[1];
  const float* genes  = (const float*)d_in[2];
  const float* W1     = (const float*)d_in[3];
  const float* b1     = (const float*)d_in[4];
  const float* W2     = (const float*)d_in[5];
  const float* b2     = (const float*)d_in[6];
  float* out = (float*)d_out;

  char* ws = (char*)d_ws;
  size_t off = 0;
  auto alloc = [&](size_t bytes) -> void* {
    void* p = ws + off;
    off = (off + bytes + 255) & ~(size_t)255;
    return p;
  };
  float* covet = (float*)alloc((size_t)N_CELLS * 1024 * 4);   // 67 MB
  float* h     = (float*)alloc((size_t)N_CELLS * HID * 4);    // 67 MB
  float* gcent = (float*)alloc((size_t)N_CELLS * G_GENES * 4);
  float* Gws   = (float*)alloc((size_t)N_CELLS * 64 * 4);
  float* Vws   = (float*)alloc((size_t)N_CELLS * 64 * 4);
  float* lamws = (float*)alloc((size_t)N_CELLS * 8 * 4);
  int*   nidx  = (int*)alloc((size_t)N_CELLS * 8 * 4);
  float* meanv = (float*)alloc(G_GENES * 4);
  if (off > ws_size) return;   // workspace too small: fail validation rather than corrupt

  hipLaunchKernelGGL(mean_kernel,   dim3(G_GENES),            dim3(256), 0, stream, genes, meanv);
  hipLaunchKernelGGL(center_kernel, dim3(N_CELLS * G_GENES / 256), dim3(256), 0, stream, genes, meanv, gcent);
  hipLaunchKernelGGL(knn_kernel,    dim3(N_CELLS / 4),        dim3(256), 0, stream, coords, nidx);
  hipLaunchKernelGGL(gram_kernel,   dim3(N_CELLS),            dim3(64),  0, stream, gcent, nidx, Gws);
  hipLaunchKernelGGL(jacobi_kernel, dim3(N_CELLS / 256),      dim3(256), 0, stream, Gws, Vws, lamws);
  hipLaunchKernelGGL(recon_kernel,  dim3(N_CELLS),            dim3(64),  0, stream, gcent, nidx, Vws, lamws, covet);
  hipLaunchKernelGGL(gemm1_kernel,  dim3(HID / 128, N_CELLS / 128), dim3(256), 0, stream, x, covet, W1, b1, h);
  hipLaunchKernelGGL(gemm2_kernel,  dim3(N_CELLS * 32 / 256), dim3(256), 0, stream, h, W2, b2, out);
}

// Round 2
// 1067.452 us; speedup vs baseline: 1.8746x; 1.8746x over previous
//
#include <hip/hip_runtime.h>
#include <hip/hip_bf16.h>
#include <math.h>

#define N_CELLS 16384
#define G_GENES 32
#define IN_DIM  2000
#define HID     1024
#define OUT_DIM 30
#define K_TOT   3024      // IN_DIM + 1024
#define K_PAD   3040      // 95 * 32

typedef unsigned short ushort_t;
typedef __attribute__((ext_vector_type(8))) short bf16x8;
typedef __attribute__((ext_vector_type(4))) float f32x4;

// lexicographic (d2, idx) compare — matches jax.lax.top_k(-d2) tie-break (lower idx wins)
__device__ __forceinline__ bool key_lt(float d1, int i1, float d2, int i2) {
  return (d1 < d2) || (d1 == d2 && i1 < i2);
}

// ---------------- mean over cells (per gene), f64 accumulate ----------------
__global__ __launch_bounds__(256) void mean_kernel(const float* __restrict__ genes,
                                                   float* __restrict__ meanv) {
  const int g = blockIdx.x;
  double acc = 0.0;
  for (int i = threadIdx.x; i < N_CELLS; i += 256) acc += (double)genes[i * G_GENES + g];
  __shared__ double red[256];
  red[threadIdx.x] = acc;
  __syncthreads();
  for (int s = 128; s > 0; s >>= 1) {
    if (threadIdx.x < s) red[threadIdx.x] += red[threadIdx.x + s];
    __syncthreads();
  }
  if (threadIdx.x == 0) meanv[g] = (float)(red[0] / (double)N_CELLS);
}

// ---------------- center genes and pre-scale by 1/sqrt(k-1) ----------------
__global__ __launch_bounds__(256) void center_kernel(const float* __restrict__ genes,
                                                     const float* __restrict__ meanv,
                                                     float* __restrict__ gcent) {
  const int i = blockIdx.x * 256 + threadIdx.x;   // over N*G = 524288 exactly
  const int g = i & 31;
  gcent[i] = (genes[i] - meanv[g]) * 0.37796447300922722721f;  // 1/sqrt(7)
}

// ---------------- brute-force kNN: one wave per cell, 4 waves/block ----------------
__global__ __launch_bounds__(256) void knn_kernel(const float* __restrict__ coords,
                                                  int* __restrict__ nidx) {
  __shared__ float2 tile[2048];
  const int lane = threadIdx.x & 63;
  const int wv   = threadIdx.x >> 6;
  const int cell = (blockIdx.x << 2) + wv;
  const float cx = coords[cell * 2 + 0];
  const float cy = coords[cell * 2 + 1];
  const float sqi = __fadd_rn(__fmul_rn(cx, cx), __fmul_rn(cy, cy));

  float bd[8]; int bi[8];
#pragma unroll
  for (int j = 0; j < 8; ++j) { bd[j] = INFINITY; bi[j] = 0x7fffffff; }

  const float2* cc = (const float2*)coords;
  for (int base = 0; base < N_CELLS; base += 2048) {
    __syncthreads();
#pragma unroll
    for (int t = 0; t < 8; ++t) tile[threadIdx.x + t * 256] = cc[base + threadIdx.x + t * 256];
    __syncthreads();
    for (int u = 0; u < 32; ++u) {
      const int j = (u << 6) + lane;
      const float2 p = tile[j];
      const float sqj = __fadd_rn(__fmul_rn(p.x, p.x), __fmul_rn(p.y, p.y));
      const float dot = __fmaf_rn(cy, p.y, __fmul_rn(cx, p.x));
      const float d2  = __fsub_rn(__fadd_rn(sqi, sqj), __fmul_rn(2.0f, dot));
      const int gi = base + j;
      if (key_lt(d2, gi, bd[7], bi[7])) {
        float cd = d2; int ci = gi;
#pragma unroll
        for (int s2 = 0; s2 < 8; ++s2) {
          const bool sw = key_lt(cd, ci, bd[s2], bi[s2]);
          const float od2 = bd[s2]; const int oi2 = bi[s2];
          if (sw) { bd[s2] = cd; bi[s2] = ci; cd = od2; ci = oi2; }
        }
      }
    }
  }

#pragma unroll
  for (int st = 1; st < 64; st <<= 1) {
    float od[8]; int oi[8];
#pragma unroll
    for (int j = 0; j < 8; ++j) { od[j] = __shfl_xor(bd[j], st, 64); oi[j] = __shfl_xor(bi[j], st, 64); }
    float nd[8]; int ni[8];
#pragma unroll
    for (int j = 0; j < 8; ++j) {
      const bool take = key_lt(od[7 - j], oi[7 - j], bd[j], bi[j]);
      nd[j] = take ? od[7 - j] : bd[j];
      ni[j] = take ? oi[7 - j] : bi[j];
    }
#define CE_(a, b) { const bool sw_ = key_lt(nd[b], ni[b], nd[a], ni[a]); \
    if (sw_) { const float t_ = nd[a]; nd[a] = nd[b]; nd[b] = t_; \
               const int u_ = ni[a]; ni[a] = ni[b]; ni[b] = u_; } }
    CE_(0, 4) CE_(1, 5) CE_(2, 6) CE_(3, 7)
    CE_(0, 2) CE_(1, 3) CE_(4, 6) CE_(5, 7)
    CE_(0, 1) CE_(2, 3) CE_(4, 5) CE_(6, 7)
#undef CE_
#pragma unroll
    for (int j = 0; j < 8; ++j) { bd[j] = nd[j]; bi[j] = ni[j]; }
  }
  if (lane == 0) {
#pragma unroll
    for (int j = 0; j < 8; ++j) nidx[cell * 8 + j] = bi[j];
  }
}

// ---------------- Gram matrix G = A A^T (8x8) per cell, one wave per cell ----------------
__global__ __launch_bounds__(64) void gram_kernel(const float* __restrict__ gcent,
                                                  const int* __restrict__ nidx,
                                                  float* __restrict__ Gws) {
  const int cell = blockIdx.x;
  const int lane = threadIdx.x;
  __shared__ float A[8][33];
#pragma unroll
  for (int q = 0; q < 4; ++q) {
    const int e = lane + (q << 6);
    const int n = e >> 5, g = e & 31;
    const int src = nidx[cell * 8 + n];
    A[n][g] = gcent[src * G_GENES + g];
  }
  __syncthreads();
  const int i = lane >> 3, j = lane & 7;
  float acc = 0.f;
#pragma unroll
  for (int g = 0; g < 32; ++g) acc = fmaf(A[i][g], A[j][g], acc);
  Gws[cell * 64 + lane] = acc;
}

// ---------------- 8x8 Jacobi eigensolver: one CELL per LANE, static indices ----------------
__global__ __launch_bounds__(256) void jacobi_kernel(const float* __restrict__ Gws,
                                                     float* __restrict__ Vws,
                                                     float* __restrict__ lamws) {
  const int cell = blockIdx.x * 256 + threadIdx.x;
  float Gm[8][8], V[8][8];
#pragma unroll
  for (int e = 0; e < 64; ++e) Gm[e >> 3][e & 7] = Gws[cell * 64 + e];
#pragma unroll
  for (int i = 0; i < 8; ++i)
#pragma unroll
    for (int j = 0; j < 8; ++j) V[i][j] = (i == j) ? 1.0f : 0.0f;

  for (int sweep = 0; sweep < 8; ++sweep) {
#pragma unroll
    for (int p = 0; p < 7; ++p) {
#pragma unroll
      for (int q = p + 1; q < 8; ++q) {
        const float apq = Gm[p][q];
        const float app = Gm[p][p], aqq = Gm[q][q];
        float t;
        if (apq != 0.0f) {
          const float tau = (aqq - app) / (2.0f * apq);
          const float r = sqrtf(fmaf(tau, tau, 1.0f));
          t = copysignf(1.0f, tau) / (fabsf(tau) + r);
        } else {
          t = 0.0f;
        }
        const float c = 1.0f / sqrtf(fmaf(t, t, 1.0f));
        const float s = t * c;
#pragma unroll
        for (int r2 = 0; r2 < 8; ++r2) {
          const float gp = Gm[p][r2], gq = Gm[q][r2];
          Gm[p][r2] = fmaf(c, gp, -s * gq);
          Gm[q][r2] = fmaf(s, gp,  c * gq);
        }
#pragma unroll
        for (int r2 = 0; r2 < 8; ++r2) {
          const float gp = Gm[r2][p], gq = Gm[r2][q];
          Gm[r2][p] = fmaf(c, gp, -s * gq);
          Gm[r2][q] = fmaf(s, gp,  c * gq);
        }
#pragma unroll
        for (int r2 = 0; r2 < 8; ++r2) {
          const float vp = V[r2][p], vq = V[r2][q];
          V[r2][p] = fmaf(c, vp, -s * vq);
          V[r2][q] = fmaf(s, vp,  c * vq);
        }
      }
    }
  }
#pragma unroll
  for (int e = 0; e < 64; ++e) Vws[cell * 64 + e] = V[e >> 3][e & 7];
#pragma unroll
  for (int m = 0; m < 8; ++m) lamws[cell * 8 + m] = Gm[m][m];
}

// ---------------- covet = A^T V diag(lam^-1/2) V^T A, one wave per cell ----------------
__global__ __launch_bounds__(64) void recon_kernel(const float* __restrict__ gcent,
                                                   const int* __restrict__ nidx,
                                                   const float* __restrict__ Vws,
                                                   const float* __restrict__ lamws,
                                                   float* __restrict__ covet) {
  const int cell = blockIdx.x;
  const int lane = threadIdx.x;
  __shared__ float A[8][33];
  __shared__ float Ws[8][33];
  __shared__ float Vs[64];
  __shared__ float lamS[8];
#pragma unroll
  for (int q = 0; q < 4; ++q) {
    const int e = lane + (q << 6);
    const int n = e >> 5, g = e & 31;
    const int src = nidx[cell * 8 + n];
    A[n][g] = gcent[src * G_GENES + g];
  }
  Vs[lane] = Vws[cell * 64 + lane];
  if (lane < 8) lamS[lane] = lamws[cell * 8 + lane];
  __syncthreads();

  float maxl = 0.f;
#pragma unroll
  for (int m = 0; m < 8; ++m) maxl = fmaxf(maxl, lamS[m]);
  const float thr = maxl * 1e-8f;

#pragma unroll
  for (int q = 0; q < 4; ++q) {
    const int e = lane + (q << 6);
    const int m = e >> 5, g = e & 31;
    float acc = 0.f;
#pragma unroll
    for (int i = 0; i < 8; ++i) acc = fmaf(Vs[i * 8 + m], A[i][g], acc);
    const float l = lamS[m];
    const float scm = (l > thr) ? sqrtf(1.0f / sqrtf(l)) : 0.0f;
    Ws[m][g] = acc * scm;
  }
  __syncthreads();
#pragma unroll
  for (int r = 0; r < 16; ++r) {
    const int o = (r << 6) + lane;
    const int g = o >> 5, hh = o & 31;
    float acc = 0.f;
#pragma unroll
    for (int m = 0; m < 8; ++m) acc = fmaf(Ws[m][g], Ws[m][hh], acc);
    covet[(size_t)cell * 1024 + o] = acc;
  }
}

// ---------------- pack W1 -> W_hi^T / W_lo^T  [HID][K_PAD] bf16, zero-padded ----------------
__global__ __launch_bounds__(256) void packw_kernel(const float* __restrict__ W1,
                                                    ushort_t* __restrict__ Whi,
                                                    ushort_t* __restrict__ Wlo) {
  __shared__ float t[64][65];
  const int k0 = blockIdx.y * 64, n0 = blockIdx.x * 64;
  const int tid = threadIdx.x;
  {
    const int r = tid >> 2;
    const int c0 = (tid & 3) * 16;
#pragma unroll
    for (int u = 0; u < 4; ++u) {
      const int c = c0 + u * 4;
      float4 v = make_float4(0.f, 0.f, 0.f, 0.f);
      if (k0 + r < K_TOT) v = *(const float4*)(W1 + (size_t)(k0 + r) * HID + n0 + c);
      t[r][c + 0] = v.x; t[r][c + 1] = v.y; t[r][c + 2] = v.z; t[r][c + 3] = v.w;
    }
  }
  __syncthreads();
  const int nl = tid & 63;
  const int kc = (tid >> 6) * 16;
  if (k0 + kc >= K_PAD) return;
  ushort_t hi[16], lo[16];
#pragma unroll
  for (int e = 0; e < 16; ++e) {
    const float v = (k0 + kc + e < K_TOT) ? t[kc + e][nl] : 0.f;
    const __hip_bfloat16 hb = __float2bfloat16(v);
    const float hf = __bfloat162float(hb);
    const __hip_bfloat16 lb = __float2bfloat16(v - hf);
    hi[e] = __builtin_bit_cast(ushort_t, hb);
    lo[e] = __builtin_bit_cast(ushort_t, lb);
  }
  ushort_t* dh = Whi + (size_t)(n0 + nl) * K_PAD + k0 + kc;
  ushort_t* dl = Wlo + (size_t)(n0 + nl) * K_PAD + k0 + kc;
  *(bf16x8*)(dh + 0) = *(const bf16x8*)&hi[0];
  *(bf16x8*)(dh + 8) = *(const bf16x8*)&hi[8];
  *(bf16x8*)(dl + 0) = *(const bf16x8*)&lo[0];
  *(bf16x8*)(dl + 8) = *(const bf16x8*)&lo[8];
}

// ---------------- GEMM1: h = relu([x|covet] @ W1 + b1) via split-bf16 MFMA ----------------
// 128x128 tile, BK=32, 4 waves x (64x64), 16x16x32 bf16 MFMA, 3-product hi/lo.
__global__ __launch_bounds__(256, 2) void gemm1_kernel(const float* __restrict__ x,
                                                       const float* __restrict__ cov,
                                                       const ushort_t* __restrict__ Whi,
                                                       const ushort_t* __restrict__ Wlo,
                                                       const float* __restrict__ b1,
                                                       float* __restrict__ h) {
  __shared__ ushort_t As_hi[128 * 40];   // stride 40 bf16 (80 B) -> 2-way banks max
  __shared__ ushort_t As_lo[128 * 40];
  __shared__ ushort_t Bs_hi[128 * 40];   // [n][k] = W^T rows
  __shared__ ushort_t Bs_lo[128 * 40];

  const int tid = threadIdx.x;
  // XCD-bijective swizzle: nwg = 1024, 8 col-blocks per row-panel stay on one XCD
  const int id  = blockIdx.x;
  const int swz = (id & 7) * 128 + (id >> 3);
  const int bx  = swz & 7, by = swz >> 3;
  const int row0 = by << 7, col0 = bx << 7;

  const int arow = tid >> 1;              // 0..127 (A row / B n-row)
  const int acol = (tid & 1) << 4;        // 0/16 k-offset
  const int lane = tid & 63, wv = tid >> 6;
  const int m_base = (wv >> 1) << 6, n_base = (wv & 1) << 6;
  const int l15 = lane & 15, l4 = lane >> 4;

  f32x4 acc[4][4];
#pragma unroll
  for (int i = 0; i < 4; ++i)
#pragma unroll
    for (int j = 0; j < 4; ++j) acc[i][j] = (f32x4){0.f, 0.f, 0.f, 0.f};

  float4 sa[4], sbh0, sbh1, sbl0, sbl1;

  auto load_tile = [&](int t) {
    const int k0 = t << 5;
    const int rg = row0 + arow;
#pragma unroll
    for (int c = 0; c < 4; ++c) {
      const int kg = k0 + acol + (c << 2);
      if (kg < IN_DIM)      sa[c] = *(const float4*)(x + (size_t)rg * IN_DIM + kg);
      else if (kg < K_TOT)  sa[c] = *(const float4*)(cov + ((size_t)rg << 10) + (kg - IN_DIM));
      else                  sa[c] = make_float4(0.f, 0.f, 0.f, 0.f);
    }
    const size_t bo = (size_t)(col0 + arow) * K_PAD + k0 + acol;
    sbh0 = *(const float4*)(Whi + bo);
    sbh1 = *(const float4*)(Whi + bo + 8);
    sbl0 = *(const float4*)(Wlo + bo);
    sbl1 = *(const float4*)(Wlo + bo + 8);
  };

  auto store_tile = [&]() {
    ushort_t hi[16], lo[16];
#pragma unroll
    for (int c = 0; c < 4; ++c) {
      const float* vv = (const float*)&sa[c];
#pragma unroll
      for (int e = 0; e < 4; ++e) {
        const float v = vv[e];
        const __hip_bfloat16 hb = __float2bfloat16(v);
        const float hf = __bfloat162float(hb);
        const __hip_bfloat16 lb = __float2bfloat16(v - hf);
        hi[c * 4 + e] = __builtin_bit_cast(ushort_t, hb);
        lo[c * 4 + e] = __builtin_bit_cast(ushort_t, lb);
      }
    }
    const int ao = arow * 40 + acol;
    *(bf16x8*)(As_hi + ao)     = *(const bf16x8*)&hi[0];
    *(bf16x8*)(As_hi + ao + 8) = *(const bf16x8*)&hi[8];
    *(bf16x8*)(As_lo + ao)     = *(const bf16x8*)&lo[0];
    *(bf16x8*)(As_lo + ao + 8) = *(const bf16x8*)&lo[8];
    *(bf16x8*)(Bs_hi + ao)     = __builtin_bit_cast(bf16x8, sbh0);
    *(bf16x8*)(Bs_hi + ao + 8) = __builtin_bit_cast(bf16x8, sbh1);
    *(bf16x8*)(Bs_lo + ao)     = __builtin_bit_cast(bf16x8, sbl0);
    *(bf16x8*)(Bs_lo + ao + 8) = __builtin_bit_cast(bf16x8, sbl1);
  };

  load_tile(0);
  store_tile();
  __syncthreads();

  for (int t = 0; t < K_PAD / 32; ++t) {
    if (t < K_PAD / 32 - 1) load_tile(t + 1);   // in flight during compute

    bf16x8 ah[4], al[4], bh[4], bl[4];
#pragma unroll
    for (int i = 0; i < 4; ++i) {
      const int off = (m_base + i * 16 + l15) * 40 + l4 * 8;
      ah[i] = *(const bf16x8*)(As_hi + off);
      al[i] = *(const bf16x8*)(As_lo + off);
    }
#pragma unroll
    for (int j = 0; j < 4; ++j) {
      const int off = (n_base + j * 16 + l15) * 40 + l4 * 8;
      bh[j] = *(const bf16x8*)(Bs_hi + off);
      bl[j] = *(const bf16x8*)(Bs_lo + off);
    }
#pragma unroll
    for (int i = 0; i < 4; ++i)
#pragma unroll
      for (int j = 0; j < 4; ++j) {
        acc[i][j] = __builtin_amdgcn_mfma_f32_16x16x32_bf16(ah[i], bh[j], acc[i][j], 0, 0, 0);
        acc[i][j] = __builtin_amdgcn_mfma_f32_16x16x32_bf16(ah[i], bl[j], acc[i][j], 0, 0, 0);
        acc[i][j] = __builtin_amdgcn_mfma_f32_16x16x32_bf16(al[i], bh[j], acc[i][j], 0, 0, 0);
      }

    __syncthreads();
    if (t < K_PAD / 32 - 1) store_tile();
    __syncthreads();
  }

  float bb[4];
#pragma unroll
  for (int j = 0; j < 4; ++j) bb[j] = b1[col0 + n_base + j * 16 + l15];
#pragma unroll
  for (int i = 0; i < 4; ++i) {
    const int rbase = row0 + m_base + i * 16 + l4 * 4;
#pragma unroll
    for (int j = 0; j < 4; ++j) {
      const int c = col0 + n_base + j * 16 + l15;
#pragma unroll
      for (int q = 0; q < 4; ++q) {
        h[(size_t)(rbase + q) * HID + c] = fmaxf(acc[i][j][q] + bb[j], 0.f);
      }
    }
  }
}

// ---------------- GEMM2: out = h @ W2 + b2 ----------------
__global__ __launch_bounds__(256) void gemm2_kernel(const float* __restrict__ h,
                                                    const float* __restrict__ W2,
                                                    const float* __restrict__ b2,
                                                    float* __restrict__ out) {
  const int t = blockIdx.x * 256 + threadIdx.x;
  const int n = t >> 5, o = t & 31;
  if (o >= OUT_DIM) return;
  const float* hrow = h + (size_t)n * HID;
  float acc = 0.f;
#pragma unroll 8
  for (int k = 0; k < HID; ++k) acc = fmaf(hrow[k], W2[k * OUT_DIM + o], acc);
  out[n * OUT_DIM + o] = acc + b2[o];
}

extern "C" void kernel_launch(void* const* d_in, const int* in_sizes, int n_in,
                              void* d_out, int out_size, void* d_ws, size_t ws_size,
                              hipStream_t stream) {
  (void)in_sizes; (void)n_in; (void)out_size;
  const float* x      = (const float*)d_in[0];
  const float* coords = (const float*)d_in[1];
  const float* genes  = (const float*)d_in[2];
  const float* W1     = (const float*)d_in[3];
  const float* b1     = (const float*)d_in[4];
  const float* W2     = (const float*)d_in[5];
  const float* b2     = (const float*)d_in[6];
  float* out = (float*)d_out;

  char* ws = (char*)d_ws;
  size_t off = 0;
  auto alloc = [&](size_t bytes) -> void* {
    void* p = ws + off;
    off = (off + bytes + 255) & ~(size_t)255;
    return p;
  };
  float*    covet = (float*)alloc((size_t)N_CELLS * 1024 * 4);   // 67 MB
  float*    h     = (float*)alloc((size_t)N_CELLS * HID * 4);    // 67 MB
  ushort_t* Whi   = (ushort_t*)alloc((size_t)HID * K_PAD * 2);   // 6.2 MB
  ushort_t* Wlo   = (ushort_t*)alloc((size_t)HID * K_PAD * 2);   // 6.2 MB
  float*    gcent = (float*)alloc((size_t)N_CELLS * G_GENES * 4);
  float*    Gws   = (float*)alloc((size_t)N_CELLS * 64 * 4);
  float*    Vws   = (float*)alloc((size_t)N_CELLS * 64 * 4);
  float*    lamws = (float*)alloc((size_t)N_CELLS * 8 * 4);
  int*      nidx  = (int*)alloc((size_t)N_CELLS * 8 * 4);
  float*    meanv = (float*)alloc(G_GENES * 4);
  if (off > ws_size) return;

  hipLaunchKernelGGL(packw_kernel,  dim3(HID / 64, K_PAD / 64), dim3(256), 0, stream, W1, Whi, Wlo);
  hipLaunchKernelGGL(mean_kernel,   dim3(G_GENES),              dim3(256), 0, stream, genes, meanv);
  hipLaunchKernelGGL(center_kernel, dim3(N_CELLS * G_GENES / 256), dim3(256), 0, stream, genes, meanv, gcent);
  hipLaunchKernelGGL(knn_kernel,    dim3(N_CELLS / 4),          dim3(256), 0, stream, coords, nidx);
  hipLaunchKernelGGL(gram_kernel,   dim3(N_CELLS),              dim3(64),  0, stream, gcent, nidx, Gws);
  hipLaunchKernelGGL(jacobi_kernel, dim3(N_CELLS / 256),        dim3(256), 0, stream, Gws, Vws, lamws);
  hipLaunchKernelGGL(recon_kernel,  dim3(N_CELLS),              dim3(64),  0, stream, gcent, nidx, Vws, lamws, covet);
  hipLaunchKernelGGL(gemm1_kernel,  dim3(1024),                 dim3(256), 0, stream, x, covet, Whi, Wlo, b1, h);
  hipLaunchKernelGGL(gemm2_kernel,  dim3(N_CELLS * 32 / 256),   dim3(256), 0, stream, h, W2, b2, out);
}

// Round 3
// 609.204 us; speedup vs baseline: 3.2848x; 1.7522x over previous
//
#include <hip/hip_runtime.h>
#include <hip/hip_bf16.h>
#include <math.h>

#define N_CELLS 16384
#define G_GENES 32
#define IN_DIM  2000
#define HID     1024
#define OUT_DIM 30
#define K_TOT   3024      // IN_DIM + 1024
#define K_PAD   3040      // 95 * 32
#define NT      95
#define GRID_B  128
#define NBINS   (GRID_B * GRID_B)
#define SCELL   (100.0f / (float)GRID_B)

typedef unsigned short ushort_t;
typedef __attribute__((ext_vector_type(8))) short bf16x8;
typedef __attribute__((ext_vector_type(4))) float f32x4;

// global_load_lds: 16B per lane, LDS dest = wave-uniform base + lane*16
__device__ __forceinline__ void glds16(const void* g, void* l) {
  __builtin_amdgcn_global_load_lds(
      (const __attribute__((address_space(1))) unsigned int*)g,
      (__attribute__((address_space(3))) unsigned int*)l, 16, 0, 0);
}

// ---------------- mean (two-stage, deterministic f64) ----------------
__global__ __launch_bounds__(256) void mean_part(const float* __restrict__ genes,
                                                 double* __restrict__ part) {
  const int b = blockIdx.x;                 // 128 blocks, 128 cells each
  const int tid = threadIdx.x;
  const int g = tid & 31, cs = tid >> 5;    // 8 cell-substreams
  double acc = 0.0;
#pragma unroll
  for (int it = 0; it < 16; ++it) {
    const int cell = b * 128 + cs + it * 8;
    acc += (double)genes[cell * G_GENES + g];
  }
  __shared__ double red[256];
  red[tid] = acc;
  __syncthreads();
  if (tid < 32) {
    double s = red[tid];
#pragma unroll
    for (int u = 1; u < 8; ++u) s += red[tid + u * 32];
    part[b * 32 + tid] = s;
  }
}

__global__ __launch_bounds__(64) void mean_fin(const double* __restrict__ part,
                                               float* __restrict__ meanv) {
  const int g = threadIdx.x;
  if (g >= 32) return;
  double s = 0.0;
  for (int b = 0; b < 128; ++b) s += part[b * 32 + g];
  meanv[g] = (float)(s / (double)N_CELLS);
}

// ---------------- center genes, pre-scale by 1/sqrt(k-1) ----------------
__global__ __launch_bounds__(256) void center_kernel(const float* __restrict__ genes,
                                                     const float* __restrict__ meanv,
                                                     float* __restrict__ gcent) {
  const int i = blockIdx.x * 256 + threadIdx.x;
  const int g = i & 31;
  gcent[i] = (genes[i] - meanv[g]) * 0.37796447300922722721f;  // 1/sqrt(7)
}

// ---------------- grid-binned exact kNN ----------------
__global__ __launch_bounds__(256) void bin_count(const float* __restrict__ coords,
                                                 int* __restrict__ cnt,
                                                 int* __restrict__ binOf) {
  const int i = blockIdx.x * 256 + threadIdx.x;
  const float2 p = ((const float2*)coords)[i];
  const float inv_s = (float)GRID_B / 100.0f;
  const int bx = min(GRID_B - 1, max(0, (int)(p.x * inv_s)));
  const int by = min(GRID_B - 1, max(0, (int)(p.y * inv_s)));
  const int b = by * GRID_B + bx;
  binOf[i] = b;
  atomicAdd(&cnt[b], 1);
}

__global__ __launch_bounds__(256) void bin_scan(const int* __restrict__ cnt,
                                                int* __restrict__ binStart,
                                                int* __restrict__ cursor) {
  __shared__ int ps[256];
  const int tid = threadIdx.x;
  int s = 0;
  for (int i = 0; i < 64; ++i) s += cnt[tid * 64 + i];
  ps[tid] = s;
  __syncthreads();
  for (int off = 1; off < 256; off <<= 1) {
    const int add = (tid >= off) ? ps[tid - off] : 0;
    __syncthreads();
    ps[tid] += add;
    __syncthreads();
  }
  int run = ps[tid] - s;   // exclusive prefix
  for (int i = 0; i < 64; ++i) {
    const int b = tid * 64 + i;
    binStart[b] = run;
    cursor[b] = run;
    run += cnt[b];
  }
  if (tid == 255) binStart[NBINS] = run;
}

__global__ __launch_bounds__(256) void bin_scatter(const int* __restrict__ binOf,
                                                   int* __restrict__ cursor,
                                                   int* __restrict__ binPts) {
  const int i = blockIdx.x * 256 + threadIdx.x;
  const int pos = atomicAdd(&cursor[binOf[i]], 1);
  binPts[pos] = i;
}

__global__ __launch_bounds__(256) void knn_search(const float* __restrict__ coords,
                                                  const int* __restrict__ binStart,
                                                  const int* __restrict__ binPts,
                                                  int* __restrict__ nidx) {
  const int cell = blockIdx.x * 256 + threadIdx.x;
  const float qx = coords[cell * 2 + 0], qy = coords[cell * 2 + 1];
  const float sqi = __fadd_rn(__fmul_rn(qx, qx), __fmul_rn(qy, qy));
  const float inv_s = (float)GRID_B / 100.0f;
  const int bx = min(GRID_B - 1, max(0, (int)(qx * inv_s)));
  const int by = min(GRID_B - 1, max(0, (int)(qy * inv_s)));

  unsigned long long kk[8];
#pragma unroll
  for (int i = 0; i < 8; ++i) kk[i] = ~0ull;

  auto scan_bin = [&](int bxx, int byy) {
    if (bxx < 0 || bxx >= GRID_B || byy < 0 || byy >= GRID_B) return;
    const int b = byy * GRID_B + bxx;
    const int s = binStart[b], e = binStart[b + 1];
    for (int p = s; p < e; ++p) {
      const int j = binPts[p];
      const float2 pc = ((const float2*)coords)[j];
      // EXACT same rounding sequence as reference mimic (rounds 1-2, passed)
      const float sqj = __fadd_rn(__fmul_rn(pc.x, pc.x), __fmul_rn(pc.y, pc.y));
      const float dot = __fmaf_rn(qy, pc.y, __fmul_rn(qx, pc.x));
      const float d2  = __fsub_rn(__fadd_rn(sqi, sqj), __fmul_rn(2.0f, dot));
      unsigned int sb = __float_as_uint(d2);
      sb = (sb & 0x80000000u) ? ~sb : (sb | 0x80000000u);   // sortable float
      unsigned long long key = ((unsigned long long)sb << 32) | (unsigned int)j;
      if (key < kk[7]) {
#pragma unroll
        for (int q2 = 0; q2 < 8; ++q2) {
          const bool lt = key < kk[q2];
          const unsigned long long tmp = kk[q2];
          kk[q2] = lt ? key : kk[q2];
          key = lt ? tmp : key;
        }
      }
    }
  };

  bool done = false;
  for (int r = 0; r < GRID_B; ++r) {
    if (!done) {
      if (r == 0) {
        scan_bin(bx, by);
      } else {
        for (int dx = -r; dx <= r; ++dx) { scan_bin(bx + dx, by - r); scan_bin(bx + dx, by + r); }
        for (int dy = -r + 1; dy <= r - 1; ++dy) { scan_bin(bx - r, by + dy); scan_bin(bx + r, by + dy); }
      }
      if (kk[7] != ~0ull) {
        const unsigned int sb = (unsigned int)(kk[7] >> 32);
        const float wd2 = __uint_as_float((sb & 0x80000000u) ? (sb ^ 0x80000000u) : ~sb);
        const float bnd = (float)r * SCELL;   // unscanned rings >= r+1 -> gap >= r*s
        if (wd2 < bnd * bnd * 0.998f - 0.05f) done = true;
      }
    }
    if (!__any(!done)) break;
  }
#pragma unroll
  for (int i = 0; i < 8; ++i) nidx[cell * 8 + i] = (int)(kk[i] & 0xFFFFFFFFu);
}

// ---------------- Gram matrix G = A A^T (8x8) per cell ----------------
__global__ __launch_bounds__(64) void gram_kernel(const float* __restrict__ gcent,
                                                  const int* __restrict__ nidx,
                                                  float* __restrict__ Gws) {
  const int cell = blockIdx.x;
  const int lane = threadIdx.x;
  __shared__ float A[8][33];
#pragma unroll
  for (int q = 0; q < 4; ++q) {
    const int e = lane + (q << 6);
    const int n = e >> 5, g = e & 31;
    const int src = nidx[cell * 8 + n];
    A[n][g] = gcent[src * G_GENES + g];
  }
  __syncthreads();
  const int i = lane >> 3, j = lane & 7;
  float acc = 0.f;
#pragma unroll
  for (int g = 0; g < 32; ++g) acc = fmaf(A[i][g], A[j][g], acc);
  Gws[cell * 64 + lane] = acc;
}

// ---------------- 8x8 Jacobi eigensolver: one cell per lane ----------------
__global__ __launch_bounds__(256) void jacobi_kernel(const float* __restrict__ Gws,
                                                     float* __restrict__ Vws,
                                                     float* __restrict__ lamws) {
  const int cell = blockIdx.x * 256 + threadIdx.x;
  float Gm[8][8], V[8][8];
#pragma unroll
  for (int e = 0; e < 64; ++e) Gm[e >> 3][e & 7] = Gws[cell * 64 + e];
#pragma unroll
  for (int i = 0; i < 8; ++i)
#pragma unroll
    for (int j = 0; j < 8; ++j) V[i][j] = (i == j) ? 1.0f : 0.0f;

  for (int sweep = 0; sweep < 8; ++sweep) {
#pragma unroll
    for (int p = 0; p < 7; ++p) {
#pragma unroll
      for (int q = p + 1; q < 8; ++q) {
        const float apq = Gm[p][q];
        const float app = Gm[p][p], aqq = Gm[q][q];
        float t;
        if (apq != 0.0f) {
          const float tau = (aqq - app) / (2.0f * apq);
          const float r = sqrtf(fmaf(tau, tau, 1.0f));
          t = copysignf(1.0f, tau) / (fabsf(tau) + r);
        } else {
          t = 0.0f;
        }
        const float c = 1.0f / sqrtf(fmaf(t, t, 1.0f));
        const float s = t * c;
#pragma unroll
        for (int r2 = 0; r2 < 8; ++r2) {
          const float gp = Gm[p][r2], gq = Gm[q][r2];
          Gm[p][r2] = fmaf(c, gp, -s * gq);
          Gm[q][r2] = fmaf(s, gp,  c * gq);
        }
#pragma unroll
        for (int r2 = 0; r2 < 8; ++r2) {
          const float gp = Gm[r2][p], gq = Gm[r2][q];
          Gm[r2][p] = fmaf(c, gp, -s * gq);
          Gm[r2][q] = fmaf(s, gp,  c * gq);
        }
#pragma unroll
        for (int r2 = 0; r2 < 8; ++r2) {
          const float vp = V[r2][p], vq = V[r2][q];
          V[r2][p] = fmaf(c, vp, -s * vq);
          V[r2][q] = fmaf(s, vp,  c * vq);
        }
      }
    }
  }
#pragma unroll
  for (int e = 0; e < 64; ++e) Vws[cell * 64 + e] = V[e >> 3][e & 7];
#pragma unroll
  for (int m = 0; m < 8; ++m) lamws[cell * 8 + m] = Gm[m][m];
}

// ---------------- covet = A^T V diag(lam^-1/2) V^T A ----------------
__global__ __launch_bounds__(64) void recon_kernel(const float* __restrict__ gcent,
                                                   const int* __restrict__ nidx,
                                                   const float* __restrict__ Vws,
                                                   const float* __restrict__ lamws,
                                                   float* __restrict__ covet) {
  const int cell = blockIdx.x;
  const int lane = threadIdx.x;
  __shared__ float A[8][33];
  __shared__ float Ws[8][33];
  __shared__ float Vs[64];
  __shared__ float lamS[8];
#pragma unroll
  for (int q = 0; q < 4; ++q) {
    const int e = lane + (q << 6);
    const int n = e >> 5, g = e & 31;
    const int src = nidx[cell * 8 + n];
    A[n][g] = gcent[src * G_GENES + g];
  }
  Vs[lane] = Vws[cell * 64 + lane];
  if (lane < 8) lamS[lane] = lamws[cell * 8 + lane];
  __syncthreads();

  float maxl = 0.f;
#pragma unroll
  for (int m = 0; m < 8; ++m) maxl = fmaxf(maxl, lamS[m]);
  const float thr = maxl * 1e-8f;

#pragma unroll
  for (int q = 0; q < 4; ++q) {
    const int e = lane + (q << 6);
    const int m = e >> 5, g = e & 31;
    float acc = 0.f;
#pragma unroll
    for (int i = 0; i < 8; ++i) acc = fmaf(Vs[i * 8 + m], A[i][g], acc);
    const float l = lamS[m];
    const float scm = (l > thr) ? sqrtf(1.0f / sqrtf(l)) : 0.0f;
    Ws[m][g] = acc * scm;
  }
  __syncthreads();
#pragma unroll
  for (int r = 0; r < 16; ++r) {
    const int o = (r << 6) + lane;
    const int g = o >> 5, hh = o & 31;
    float acc = 0.f;
#pragma unroll
    for (int m = 0; m < 8; ++m) acc = fmaf(Ws[m][g], Ws[m][hh], acc);
    covet[(size_t)cell * 1024 + o] = acc;
  }
}

// ---------------- pack W1^T into swizzled bf16 hi/lo tiles ----------------
// Layout: tile(cb,t) = 4096 elems; chunk ch (0..511) = 16B; ch = r*4 + cpos,
// position cpos holds data k-chunk (cpos ^ ((r>>1)&3))  [bank-conflict-free reads]
__global__ __launch_bounds__(256) void packb_kernel(const float* __restrict__ W1,
                                                    ushort_t* __restrict__ Bh,
                                                    ushort_t* __restrict__ Bl) {
  const int cb = blockIdx.x;   // 0..7 column block
  const int t  = blockIdx.y;   // 0..94 k-step
  const int tid = threadIdx.x;
  __shared__ float L[32][129];
  const int k0 = t * 32, n0 = cb * 128;
  {
    const int kl = tid >> 3;
    const int nw = tid & 7;
#pragma unroll
    for (int u = 0; u < 4; ++u) {
      const int nl = (nw + u * 8) * 4;
      float4 v = make_float4(0.f, 0.f, 0.f, 0.f);
      if (k0 + kl < K_TOT) v = *(const float4*)(W1 + (size_t)(k0 + kl) * HID + n0 + nl);
      L[kl][nl + 0] = v.x; L[kl][nl + 1] = v.y; L[kl][nl + 2] = v.z; L[kl][nl + 3] = v.w;
    }
  }
  __syncthreads();
  const size_t tileBase = ((size_t)cb * NT + t) * 4096;
#pragma unroll
  for (int qq = 0; qq < 2; ++qq) {
    const int ch = tid + 256 * qq;
    const int r = ch >> 2, cpos = ch & 3;
    const int cdata = cpos ^ ((r >> 1) & 3);
    ushort_t hi[8], lo[8];
#pragma unroll
    for (int e = 0; e < 8; ++e) {
      const int kl = cdata * 8 + e;
      const float v = (k0 + kl < K_TOT) ? L[kl][r] : 0.f;
      const __hip_bfloat16 hb = __float2bfloat16(v);
      hi[e] = __builtin_bit_cast(ushort_t, hb);
      lo[e] = __builtin_bit_cast(ushort_t, __float2bfloat16(v - __bfloat162float(hb)));
    }
    *(bf16x8*)(Bh + tileBase + ch * 8) = *(const bf16x8*)hi;
    *(bf16x8*)(Bl + tileBase + ch * 8) = *(const bf16x8*)lo;
  }
}

// ---------------- GEMM1: h = relu([x|covet] @ W1 + b1), bf16 MFMA ----------------
// A = bf16(A) (hi only), B = hi+lo. B staged via global_load_lds (dbuf, swizzled).
__global__ __launch_bounds__(256, 3) void gemm1_kernel(const float* __restrict__ x,
                                                       const float* __restrict__ cov,
                                                       const ushort_t* __restrict__ Bh,
                                                       const ushort_t* __restrict__ Bl,
                                                       const float* __restrict__ b1,
                                                       ushort_t* __restrict__ h) {
  __shared__ ushort_t As[128 * 40];       // stride 40 ushorts (80B)
  __shared__ ushort_t Bhs[2][4096];       // [row 0..127][32k], 16B-chunk swizzled
  __shared__ ushort_t Bls[2][4096];

  const int tid = threadIdx.x;
  const int id  = blockIdx.x;
  const int swz = (id & 7) * 128 + (id >> 3);  // XCD-contiguous chunks (1024 % 8 == 0)
  const int bx  = swz & 7, by = swz >> 3;
  const int row0 = by << 7, col0 = bx << 7;

  const int arow = tid >> 1, acol = (tid & 1) << 4;
  const int lane = tid & 63, wv = tid >> 6;
  const int m_base = (wv >> 1) << 6, n_base = (wv & 1) << 6;
  const int l15 = lane & 15, l4 = lane >> 4;

  f32x4 acc[4][4];
#pragma unroll
  for (int i = 0; i < 4; ++i)
#pragma unroll
    for (int j = 0; j < 4; ++j) acc[i][j] = (f32x4){0.f, 0.f, 0.f, 0.f};

  float4 sa[4];

  auto loadA = [&](int t) {
    const int k0 = t << 5;
    const int rg = row0 + arow;
#pragma unroll
    for (int c = 0; c < 4; ++c) {
      const int kg = k0 + acol + (c << 2);
      if (kg < IN_DIM)      sa[c] = *(const float4*)(x + (size_t)rg * IN_DIM + kg);
      else if (kg < K_TOT)  sa[c] = *(const float4*)(cov + ((size_t)rg << 10) + (kg - IN_DIM));
      else                  sa[c] = make_float4(0.f, 0.f, 0.f, 0.f);
    }
  };
  auto storeA = [&]() {
    ushort_t hi[16];
#pragma unroll
    for (int c = 0; c < 4; ++c) {
      const float* vv = (const float*)&sa[c];
#pragma unroll
      for (int e = 0; e < 4; ++e)
        hi[c * 4 + e] = __builtin_bit_cast(ushort_t, __float2bfloat16(vv[e]));
    }
    const int ao = arow * 40 + acol;
    *(bf16x8*)(As + ao)     = *(const bf16x8*)&hi[0];
    *(bf16x8*)(As + ao + 8) = *(const bf16x8*)&hi[8];
  };
  auto gloadB = [&](int t, int buf) {
    const size_t go = ((size_t)bx * NT + t) * 4096;
    glds16(Bh + go + tid * 8,        &Bhs[buf][tid * 8]);
    glds16(Bh + go + 2048 + tid * 8, &Bhs[buf][2048 + tid * 8]);
    glds16(Bl + go + tid * 8,        &Bls[buf][tid * 8]);
    glds16(Bl + go + 2048 + tid * 8, &Bls[buf][2048 + tid * 8]);
  };

  loadA(0);
  gloadB(0, 0);
  storeA();
  __syncthreads();   // drains vmcnt(0) -> B tile 0 ready

  for (int t = 0; t < NT; ++t) {
    const int cur = t & 1;
    if (t < NT - 1) { loadA(t + 1); gloadB(t + 1, cur ^ 1); }

    bf16x8 ah[4], bh[4], bl[4];
#pragma unroll
    for (int i = 0; i < 4; ++i)
      ah[i] = *(const bf16x8*)(As + (m_base + i * 16 + l15) * 40 + l4 * 8);
#pragma unroll
    for (int j = 0; j < 4; ++j) {
      const int row = n_base + j * 16 + l15;
      const int cp  = l4 ^ ((row >> 1) & 3);
      bh[j] = *(const bf16x8*)(&Bhs[cur][row * 32 + cp * 8]);
      bl[j] = *(const bf16x8*)(&Bls[cur][row * 32 + cp * 8]);
    }
#pragma unroll
    for (int i = 0; i < 4; ++i)
#pragma unroll
      for (int j = 0; j < 4; ++j) {
        acc[i][j] = __builtin_amdgcn_mfma_f32_16x16x32_bf16(ah[i], bh[j], acc[i][j], 0, 0, 0);
        acc[i][j] = __builtin_amdgcn_mfma_f32_16x16x32_bf16(ah[i], bl[j], acc[i][j], 0, 0, 0);
      }

    __syncthreads();                 // frag reads done + next B tile landed
    if (t < NT - 1) storeA();
    __syncthreads();                 // A tile visible
  }

  float bb[4];
#pragma unroll
  for (int j = 0; j < 4; ++j) bb[j] = b1[col0 + n_base + j * 16 + l15];
#pragma unroll
  for (int i = 0; i < 4; ++i) {
    const int rbase = row0 + m_base + i * 16 + l4 * 4;
#pragma unroll
    for (int j = 0; j < 4; ++j) {
      const int c = col0 + n_base + j * 16 + l15;
#pragma unroll
      for (int q = 0; q < 4; ++q) {
        const float v = fmaxf(acc[i][j][q] + bb[j], 0.f);
        h[(size_t)(rbase + q) * HID + c] = __builtin_bit_cast(ushort_t, __float2bfloat16(v));
      }
    }
  }
}

// ---------------- GEMM2: out = h @ W2 + b2 (h is bf16) ----------------
__global__ __launch_bounds__(256) void gemm2_kernel(const ushort_t* __restrict__ h,
                                                    const float* __restrict__ W2,
                                                    const float* __restrict__ b2,
                                                    float* __restrict__ out) {
  const int t = blockIdx.x * 256 + threadIdx.x;
  const int n = t >> 5, o = t & 31;
  if (o >= OUT_DIM) return;
  const ushort_t* hrow = h + (size_t)n * HID;
  float acc0 = 0.f, acc1 = 0.f;
  for (int k = 0; k < HID; k += 8) {
    const bf16x8 hv = *(const bf16x8*)(hrow + k);
#pragma unroll
    for (int e = 0; e < 8; ++e) {
      const float hf = __builtin_bit_cast(float, (unsigned)((ushort_t)hv[e]) << 16);
      if (e & 1) acc1 = fmaf(hf, W2[(k + e) * OUT_DIM + o], acc1);
      else       acc0 = fmaf(hf, W2[(k + e) * OUT_DIM + o], acc0);
    }
  }
  out[n * OUT_DIM + o] = acc0 + acc1 + b2[o];
}

extern "C" void kernel_launch(void* const* d_in, const int* in_sizes, int n_in,
                              void* d_out, int out_size, void* d_ws, size_t ws_size,
                              hipStream_t stream) {
  (void)in_sizes; (void)n_in; (void)out_size;
  const float* x      = (const float*)d_in[0];
  const float* coords = (const float*)d_in[1];
  const float* genes  = (const float*)d_in[2];
  const float* W1     = (const float*)d_in[3];
  const float* b1     = (const float*)d_in[4];
  const float* W2     = (const float*)d_in[5];
  const float* b2     = (const float*)d_in[6];
  float* out = (float*)d_out;

  char* ws = (char*)d_ws;
  size_t off = 0;
  auto alloc = [&](size_t bytes) -> void* {
    void* p = ws + off;
    off = (off + bytes + 255) & ~(size_t)255;
    return p;
  };
  float*    covet  = (float*)alloc((size_t)N_CELLS * 1024 * 4);       // 67 MB
  ushort_t* hbf    = (ushort_t*)alloc((size_t)N_CELLS * HID * 2);     // 33.5 MB
  ushort_t* Bh     = (ushort_t*)alloc((size_t)8 * NT * 4096 * 2);     // 6.2 MB
  ushort_t* Bl     = (ushort_t*)alloc((size_t)8 * NT * 4096 * 2);     // 6.2 MB
  float*    gcent  = (float*)alloc((size_t)N_CELLS * G_GENES * 4);
  float*    Gws    = (float*)alloc((size_t)N_CELLS * 64 * 4);
  float*    Vws    = (float*)alloc((size_t)N_CELLS * 64 * 4);
  float*    lamws  = (float*)alloc((size_t)N_CELLS * 8 * 4);
  int*      nidx   = (int*)alloc((size_t)N_CELLS * 8 * 4);
  double*   part   = (double*)alloc((size_t)128 * 32 * 8);
  float*    meanv  = (float*)alloc(G_GENES * 4);
  int*      binCnt = (int*)alloc((size_t)NBINS * 4);
  int*      binSt  = (int*)alloc((size_t)(NBINS + 1) * 4);
  int*      cursor = (int*)alloc((size_t)NBINS * 4);
  int*      binOf  = (int*)alloc((size_t)N_CELLS * 4);
  int*      binPts = (int*)alloc((size_t)N_CELLS * 4);
  if (off > ws_size) return;

  hipMemsetAsync(binCnt, 0, (size_t)NBINS * 4, stream);

  hipLaunchKernelGGL(packb_kernel, dim3(8, NT),   dim3(256), 0, stream, W1, Bh, Bl);
  hipLaunchKernelGGL(mean_part,    dim3(128),     dim3(256), 0, stream, genes, part);
  hipLaunchKernelGGL(mean_fin,     dim3(1),       dim3(64),  0, stream, part, meanv);
  hipLaunchKernelGGL(center_kernel,dim3(2048),    dim3(256), 0, stream, genes, meanv, gcent);
  hipLaunchKernelGGL(bin_count,    dim3(64),      dim3(256), 0, stream, coords, binCnt, binOf);
  hipLaunchKernelGGL(bin_scan,     dim3(1),       dim3(256), 0, stream, binCnt, binSt, cursor);
  hipLaunchKernelGGL(bin_scatter,  dim3(64),      dim3(256), 0, stream, binOf, cursor, binPts);
  hipLaunchKernelGGL(knn_search,   dim3(64),      dim3(256), 0, stream, coords, binSt, binPts, nidx);
  hipLaunchKernelGGL(gram_kernel,  dim3(N_CELLS), dim3(64),  0, stream, gcent, nidx, Gws);
  hipLaunchKernelGGL(jacobi_kernel,dim3(64),      dim3(256), 0, stream, Gws, Vws, lamws);
  hipLaunchKernelGGL(recon_kernel, dim3(N_CELLS), dim3(64),  0, stream, gcent, nidx, Vws, lamws, covet);
  hipLaunchKernelGGL(gemm1_kernel, dim3(1024),    dim3(256), 0, stream, x, covet, Bh, Bl, b1, hbf);
  hipLaunchKernelGGL(gemm2_kernel, dim3(2048),    dim3(256), 0, stream, hbf, W2, b2, out);
}

// Round 4
// 542.481 us; speedup vs baseline: 3.6888x; 1.1230x over previous
//
#include <hip/hip_runtime.h>
#include <hip/hip_bf16.h>
#include <math.h>

#define N_CELLS 16384
#define G_GENES 32
#define IN_DIM  2000
#define HID     1024
#define OUT_DIM 30
#define K_TOT   3024      // IN_DIM + 1024
#define K_PAD   3040      // 95 * 32
#define NT      95
#define GRID_B  128
#define NBINS   (GRID_B * GRID_B)
#define SCELL   (100.0f / (float)GRID_B)

typedef unsigned short ushort_t;
typedef __attribute__((ext_vector_type(8))) short bf16x8;
typedef __attribute__((ext_vector_type(4))) float f32x4;

// global_load_lds: 16B per lane, LDS dest = wave-uniform base + lane*16
__device__ __forceinline__ void glds16(const void* g, void* l) {
  __builtin_amdgcn_global_load_lds(
      (const __attribute__((address_space(1))) unsigned int*)g,
      (__attribute__((address_space(3))) unsigned int*)l, 16, 0, 0);
}

// ---------------- mean (two-stage, deterministic f64) ----------------
__global__ __launch_bounds__(256) void mean_part(const float* __restrict__ genes,
                                                 double* __restrict__ part) {
  const int b = blockIdx.x;                 // 128 blocks, 128 cells each
  const int tid = threadIdx.x;
  const int g = tid & 31, cs = tid >> 5;    // 8 cell-substreams
  double acc = 0.0;
#pragma unroll
  for (int it = 0; it < 16; ++it) {
    const int cell = b * 128 + cs + it * 8;
    acc += (double)genes[cell * G_GENES + g];
  }
  __shared__ double red[256];
  red[tid] = acc;
  __syncthreads();
  if (tid < 32) {
    double s = red[tid];
#pragma unroll
    for (int u = 1; u < 8; ++u) s += red[tid + u * 32];
    part[b * 32 + tid] = s;
  }
}

__global__ __launch_bounds__(64) void mean_fin(const double* __restrict__ part,
                                               float* __restrict__ meanv) {
  const int g = threadIdx.x;
  if (g >= 32) return;
  double s = 0.0;
  for (int b = 0; b < 128; ++b) s += part[b * 32 + g];
  meanv[g] = (float)(s / (double)N_CELLS);
}

// ---------------- center genes, pre-scale by 1/sqrt(k-1) ----------------
__global__ __launch_bounds__(256) void center_kernel(const float* __restrict__ genes,
                                                     const float* __restrict__ meanv,
                                                     float* __restrict__ gcent) {
  const int i = blockIdx.x * 256 + threadIdx.x;
  const int g = i & 31;
  gcent[i] = (genes[i] - meanv[g]) * 0.37796447300922722721f;  // 1/sqrt(7)
}

// ---------------- grid-binned exact kNN ----------------
__global__ __launch_bounds__(256) void bin_count(const float* __restrict__ coords,
                                                 int* __restrict__ cnt,
                                                 int* __restrict__ binOf) {
  const int i = blockIdx.x * 256 + threadIdx.x;
  const float2 p = ((const float2*)coords)[i];
  const float inv_s = (float)GRID_B / 100.0f;
  const int bx = min(GRID_B - 1, max(0, (int)(p.x * inv_s)));
  const int by = min(GRID_B - 1, max(0, (int)(p.y * inv_s)));
  const int b = by * GRID_B + bx;
  binOf[i] = b;
  atomicAdd(&cnt[b], 1);
}

__global__ __launch_bounds__(256) void bin_scan(const int* __restrict__ cnt,
                                                int* __restrict__ binStart,
                                                int* __restrict__ cursor) {
  __shared__ int ps[256];
  const int tid = threadIdx.x;
  int s = 0;
  for (int i = 0; i < 64; ++i) s += cnt[tid * 64 + i];
  ps[tid] = s;
  __syncthreads();
  for (int off = 1; off < 256; off <<= 1) {
    const int add = (tid >= off) ? ps[tid - off] : 0;
    __syncthreads();
    ps[tid] += add;
    __syncthreads();
  }
  int run = ps[tid] - s;   // exclusive prefix
  for (int i = 0; i < 64; ++i) {
    const int b = tid * 64 + i;
    binStart[b] = run;
    cursor[b] = run;
    run += cnt[b];
  }
  if (tid == 255) binStart[NBINS] = run;
}

__global__ __launch_bounds__(256) void bin_scatter(const int* __restrict__ binOf,
                                                   int* __restrict__ cursor,
                                                   int* __restrict__ binPts) {
  const int i = blockIdx.x * 256 + threadIdx.x;
  const int pos = atomicAdd(&cursor[binOf[i]], 1);
  binPts[pos] = i;
}

__global__ __launch_bounds__(256) void knn_search(const float* __restrict__ coords,
                                                  const int* __restrict__ binStart,
                                                  const int* __restrict__ binPts,
                                                  int* __restrict__ nidx) {
  const int cell = blockIdx.x * 256 + threadIdx.x;
  const float qx = coords[cell * 2 + 0], qy = coords[cell * 2 + 1];
  const float sqi = __fadd_rn(__fmul_rn(qx, qx), __fmul_rn(qy, qy));
  const float inv_s = (float)GRID_B / 100.0f;
  const int bx = min(GRID_B - 1, max(0, (int)(qx * inv_s)));
  const int by = min(GRID_B - 1, max(0, (int)(qy * inv_s)));

  unsigned long long kk[8];
#pragma unroll
  for (int i = 0; i < 8; ++i) kk[i] = ~0ull;

  auto scan_bin = [&](int bxx, int byy) {
    if (bxx < 0 || bxx >= GRID_B || byy < 0 || byy >= GRID_B) return;
    const int b = byy * GRID_B + bxx;
    const int s = binStart[b], e = binStart[b + 1];
    for (int p = s; p < e; ++p) {
      const int j = binPts[p];
      const float2 pc = ((const float2*)coords)[j];
      // EXACT same rounding sequence as reference mimic (rounds 1-3, passed)
      const float sqj = __fadd_rn(__fmul_rn(pc.x, pc.x), __fmul_rn(pc.y, pc.y));
      const float dot = __fmaf_rn(qy, pc.y, __fmul_rn(qx, pc.x));
      const float d2  = __fsub_rn(__fadd_rn(sqi, sqj), __fmul_rn(2.0f, dot));
      unsigned int sb = __float_as_uint(d2);
      sb = (sb & 0x80000000u) ? ~sb : (sb | 0x80000000u);   // sortable float
      unsigned long long key = ((unsigned long long)sb << 32) | (unsigned int)j;
      if (key < kk[7]) {
#pragma unroll
        for (int q2 = 0; q2 < 8; ++q2) {
          const bool lt = key < kk[q2];
          const unsigned long long tmp = kk[q2];
          kk[q2] = lt ? key : kk[q2];
          key = lt ? tmp : key;
        }
      }
    }
  };

  bool done = false;
  for (int r = 0; r < GRID_B; ++r) {
    if (!done) {
      if (r == 0) {
        scan_bin(bx, by);
      } else {
        for (int dx = -r; dx <= r; ++dx) { scan_bin(bx + dx, by - r); scan_bin(bx + dx, by + r); }
        for (int dy = -r + 1; dy <= r - 1; ++dy) { scan_bin(bx - r, by + dy); scan_bin(bx + r, by + dy); }
      }
      if (kk[7] != ~0ull) {
        const unsigned int sb = (unsigned int)(kk[7] >> 32);
        const float wd2 = __uint_as_float((sb & 0x80000000u) ? (sb ^ 0x80000000u) : ~sb);
        const float bnd = (float)r * SCELL;   // unscanned rings >= r+1 -> gap >= r*s
        if (wd2 < bnd * bnd * 0.998f - 0.05f) done = true;
      }
    }
    if (!__any(!done)) break;
  }
#pragma unroll
  for (int i = 0; i < 8; ++i) nidx[cell * 8 + i] = (int)(kk[i] & 0xFFFFFFFFu);
}

// ---------------- Gram matrix G = A A^T (8x8) per cell ----------------
__global__ __launch_bounds__(64) void gram_kernel(const float* __restrict__ gcent,
                                                  const int* __restrict__ nidx,
                                                  float* __restrict__ Gws) {
  const int cell = blockIdx.x;
  const int lane = threadIdx.x;
  __shared__ float A[8][33];
#pragma unroll
  for (int q = 0; q < 4; ++q) {
    const int e = lane + (q << 6);
    const int n = e >> 5, g = e & 31;
    const int src = nidx[cell * 8 + n];
    A[n][g] = gcent[src * G_GENES + g];
  }
  __syncthreads();
  const int i = lane >> 3, j = lane & 7;
  float acc = 0.f;
#pragma unroll
  for (int g = 0; g < 32; ++g) acc = fmaf(A[i][g], A[j][g], acc);
  Gws[cell * 64 + lane] = acc;
}

// ---------------- 8x8 Jacobi eigensolver: one cell per lane ----------------
__global__ __launch_bounds__(256) void jacobi_kernel(const float* __restrict__ Gws,
                                                     float* __restrict__ Vws,
                                                     float* __restrict__ lamws) {
  const int cell = blockIdx.x * 256 + threadIdx.x;
  float Gm[8][8], V[8][8];
#pragma unroll
  for (int e = 0; e < 64; ++e) Gm[e >> 3][e & 7] = Gws[cell * 64 + e];
#pragma unroll
  for (int i = 0; i < 8; ++i)
#pragma unroll
    for (int j = 0; j < 8; ++j) V[i][j] = (i == j) ? 1.0f : 0.0f;

  for (int sweep = 0; sweep < 8; ++sweep) {
#pragma unroll
    for (int p = 0; p < 7; ++p) {
#pragma unroll
      for (int q = p + 1; q < 8; ++q) {
        const float apq = Gm[p][q];
        const float app = Gm[p][p], aqq = Gm[q][q];
        float t;
        if (apq != 0.0f) {
          const float tau = (aqq - app) / (2.0f * apq);
          const float r = sqrtf(fmaf(tau, tau, 1.0f));
          t = copysignf(1.0f, tau) / (fabsf(tau) + r);
        } else {
          t = 0.0f;
        }
        const float c = 1.0f / sqrtf(fmaf(t, t, 1.0f));
        const float s = t * c;
#pragma unroll
        for (int r2 = 0; r2 < 8; ++r2) {
          const float gp = Gm[p][r2], gq = Gm[q][r2];
          Gm[p][r2] = fmaf(c, gp, -s * gq);
          Gm[q][r2] = fmaf(s, gp,  c * gq);
        }
#pragma unroll
        for (int r2 = 0; r2 < 8; ++r2) {
          const float gp = Gm[r2][p], gq = Gm[r2][q];
          Gm[r2][p] = fmaf(c, gp, -s * gq);
          Gm[r2][q] = fmaf(s, gp,  c * gq);
        }
#pragma unroll
        for (int r2 = 0; r2 < 8; ++r2) {
          const float vp = V[r2][p], vq = V[r2][q];
          V[r2][p] = fmaf(c, vp, -s * vq);
          V[r2][q] = fmaf(s, vp,  c * vq);
        }
      }
    }
  }
#pragma unroll
  for (int e = 0; e < 64; ++e) Vws[cell * 64 + e] = V[e >> 3][e & 7];
#pragma unroll
  for (int m = 0; m < 8; ++m) lamws[cell * 8 + m] = Gm[m][m];
}

// ---------------- covet = A^T V diag(lam^-1/2) V^T A ----------------
__global__ __launch_bounds__(64) void recon_kernel(const float* __restrict__ gcent,
                                                   const int* __restrict__ nidx,
                                                   const float* __restrict__ Vws,
                                                   const float* __restrict__ lamws,
                                                   float* __restrict__ covet) {
  const int cell = blockIdx.x;
  const int lane = threadIdx.x;
  __shared__ float A[8][33];
  __shared__ float Ws[8][33];
  __shared__ float Vs[64];
  __shared__ float lamS[8];
#pragma unroll
  for (int q = 0; q < 4; ++q) {
    const int e = lane + (q << 6);
    const int n = e >> 5, g = e & 31;
    const int src = nidx[cell * 8 + n];
    A[n][g] = gcent[src * G_GENES + g];
  }
  Vs[lane] = Vws[cell * 64 + lane];
  if (lane < 8) lamS[lane] = lamws[cell * 8 + lane];
  __syncthreads();

  float maxl = 0.f;
#pragma unroll
  for (int m = 0; m < 8; ++m) maxl = fmaxf(maxl, lamS[m]);
  const float thr = maxl * 1e-8f;

#pragma unroll
  for (int q = 0; q < 4; ++q) {
    const int e = lane + (q << 6);
    const int m = e >> 5, g = e & 31;
    float acc = 0.f;
#pragma unroll
    for (int i = 0; i < 8; ++i) acc = fmaf(Vs[i * 8 + m], A[i][g], acc);
    const float l = lamS[m];
    const float scm = (l > thr) ? sqrtf(1.0f / sqrtf(l)) : 0.0f;
    Ws[m][g] = acc * scm;
  }
  __syncthreads();
#pragma unroll
  for (int r = 0; r < 16; ++r) {
    const int o = (r << 6) + lane;
    const int g = o >> 5, hh = o & 31;
    float acc = 0.f;
#pragma unroll
    for (int m = 0; m < 8; ++m) acc = fmaf(Ws[m][g], Ws[m][hh], acc);
    covet[(size_t)cell * 1024 + o] = acc;
  }
}

// ---------------- pack W1^T into swizzled bf16 tiles (hi only) ----------------
// Layout: tile(cb,t) = 4096 elems; chunk ch (0..511) = 16B; ch = r*4 + cpos,
// position cpos holds data k-chunk (cpos ^ ((r>>1)&3))  [bank-conflict-free reads]
__global__ __launch_bounds__(256) void packb_kernel(const float* __restrict__ W1,
                                                    ushort_t* __restrict__ Bh) {
  const int cb = blockIdx.x;   // 0..7 column block
  const int t  = blockIdx.y;   // 0..94 k-step
  const int tid = threadIdx.x;
  __shared__ float L[32][129];
  const int k0 = t * 32, n0 = cb * 128;
  {
    const int kl = tid >> 3;
    const int nw = tid & 7;
#pragma unroll
    for (int u = 0; u < 4; ++u) {
      const int nl = (nw + u * 8) * 4;
      float4 v = make_float4(0.f, 0.f, 0.f, 0.f);
      if (k0 + kl < K_TOT) v = *(const float4*)(W1 + (size_t)(k0 + kl) * HID + n0 + nl);
      L[kl][nl + 0] = v.x; L[kl][nl + 1] = v.y; L[kl][nl + 2] = v.z; L[kl][nl + 3] = v.w;
    }
  }
  __syncthreads();
  const size_t tileBase = ((size_t)cb * NT + t) * 4096;
#pragma unroll
  for (int qq = 0; qq < 2; ++qq) {
    const int ch = tid + 256 * qq;
    const int r = ch >> 2, cpos = ch & 3;
    const int cdata = cpos ^ ((r >> 1) & 3);
    ushort_t hi[8];
#pragma unroll
    for (int e = 0; e < 8; ++e) {
      const int kl = cdata * 8 + e;
      const float v = (k0 + kl < K_TOT) ? L[kl][r] : 0.f;
      hi[e] = __builtin_bit_cast(ushort_t, __float2bfloat16(v));
    }
    *(bf16x8*)(Bh + tileBase + ch * 8) = *(const bf16x8*)hi;
  }
}

// ---------------- GEMM1: h = relu([x|covet] @ W1 + b1), bf16 MFMA ----------------
// A,B both bf16 (hi). A double-buffered in LDS (reg-staged cvt), B via
// global_load_lds dbuf. ONE __syncthreads per K-step.
__global__ __launch_bounds__(256, 4) void gemm1_kernel(const float* __restrict__ x,
                                                       const float* __restrict__ cov,
                                                       const ushort_t* __restrict__ Bh,
                                                       const float* __restrict__ b1,
                                                       ushort_t* __restrict__ h) {
  __shared__ ushort_t As[2][128 * 40];    // stride 40 ushorts (80B), dbuf
  __shared__ ushort_t Bhs[2][4096];       // 16B-chunk swizzled, dbuf

  const int tid = threadIdx.x;
  const int id  = blockIdx.x;
  const int swz = (id & 7) * 128 + (id >> 3);  // XCD-contiguous chunks (1024 % 8 == 0)
  const int bx  = swz & 7, by = swz >> 3;
  const int row0 = by << 7, col0 = bx << 7;

  const int arow = tid >> 1, acol = (tid & 1) << 4;
  const int lane = tid & 63, wv = tid >> 6;
  const int m_base = (wv >> 1) << 6, n_base = (wv & 1) << 6;
  const int l15 = lane & 15, l4 = lane >> 4;

  f32x4 acc[4][4];
#pragma unroll
  for (int i = 0; i < 4; ++i)
#pragma unroll
    for (int j = 0; j < 4; ++j) acc[i][j] = (f32x4){0.f, 0.f, 0.f, 0.f};

  float4 sa[4];

  auto loadA = [&](int t) {
    const int k0 = t << 5;
    const int rg = row0 + arow;
#pragma unroll
    for (int c = 0; c < 4; ++c) {
      const int kg = k0 + acol + (c << 2);
      if (kg < IN_DIM)      sa[c] = *(const float4*)(x + (size_t)rg * IN_DIM + kg);
      else if (kg < K_TOT)  sa[c] = *(const float4*)(cov + ((size_t)rg << 10) + (kg - IN_DIM));
      else                  sa[c] = make_float4(0.f, 0.f, 0.f, 0.f);
    }
  };
  auto storeA = [&](int buf) {
    ushort_t hi[16];
#pragma unroll
    for (int c = 0; c < 4; ++c) {
      const float* vv = (const float*)&sa[c];
#pragma unroll
      for (int e = 0; e < 4; ++e)
        hi[c * 4 + e] = __builtin_bit_cast(ushort_t, __float2bfloat16(vv[e]));
    }
    const int ao = arow * 40 + acol;
    *(bf16x8*)(&As[buf][ao])     = *(const bf16x8*)&hi[0];
    *(bf16x8*)(&As[buf][ao + 8]) = *(const bf16x8*)&hi[8];
  };
  auto gloadB = [&](int t, int buf) {
    const size_t go = ((size_t)bx * NT + t) * 4096;
    glds16(Bh + go + tid * 8,        &Bhs[buf][tid * 8]);
    glds16(Bh + go + 2048 + tid * 8, &Bhs[buf][2048 + tid * 8]);
  };

  loadA(0);
  gloadB(0, 0);
  storeA(0);
  __syncthreads();   // drains vmcnt(0): B tile 0 landed; A tile 0 visible

  for (int t = 0; t < NT; ++t) {
    const int cur = t & 1;
    if (t < NT - 1) { loadA(t + 1); gloadB(t + 1, cur ^ 1); }

    bf16x8 ah[4], bh[4];
#pragma unroll
    for (int i = 0; i < 4; ++i)
      ah[i] = *(const bf16x8*)(&As[cur][(m_base + i * 16 + l15) * 40 + l4 * 8]);
#pragma unroll
    for (int j = 0; j < 4; ++j) {
      const int row = n_base + j * 16 + l15;
      const int cp  = l4 ^ ((row >> 1) & 3);
      bh[j] = *(const bf16x8*)(&Bhs[cur][row * 32 + cp * 8]);
    }
#pragma unroll
    for (int i = 0; i < 4; ++i)
#pragma unroll
      for (int j = 0; j < 4; ++j)
        acc[i][j] = __builtin_amdgcn_mfma_f32_16x16x32_bf16(ah[i], bh[j], acc[i][j], 0, 0, 0);

    if (t < NT - 1) storeA(cur ^ 1);   // hides loadA latency under MFMAs
    __syncthreads();                   // orders reads(cur) before next writes(cur);
                                       // drains glds(t+1) into Bhs[cur^1]
  }

  float bb[4];
#pragma unroll
  for (int j = 0; j < 4; ++j) bb[j] = b1[col0 + n_base + j * 16 + l15];
#pragma unroll
  for (int i = 0; i < 4; ++i) {
    const int rbase = row0 + m_base + i * 16 + l4 * 4;
#pragma unroll
    for (int j = 0; j < 4; ++j) {
      const int c = col0 + n_base + j * 16 + l15;
#pragma unroll
      for (int q = 0; q < 4; ++q) {
        const float v = fmaxf(acc[i][j][q] + bb[j], 0.f);
        h[(size_t)(rbase + q) * HID + c] = __builtin_bit_cast(ushort_t, __float2bfloat16(v));
      }
    }
  }
}

// ---------------- GEMM2: out = h @ W2 + b2 (h is bf16) ----------------
__global__ __launch_bounds__(256) void gemm2_kernel(const ushort_t* __restrict__ h,
                                                    const float* __restrict__ W2,
                                                    const float* __restrict__ b2,
                                                    float* __restrict__ out) {
  const int t = blockIdx.x * 256 + threadIdx.x;
  const int n = t >> 5, o = t & 31;
  if (o >= OUT_DIM) return;
  const ushort_t* hrow = h + (size_t)n * HID;
  float acc0 = 0.f, acc1 = 0.f;
  for (int k = 0; k < HID; k += 8) {
    const bf16x8 hv = *(const bf16x8*)(hrow + k);
#pragma unroll
    for (int e = 0; e < 8; ++e) {
      const float hf = __builtin_bit_cast(float, (unsigned)((ushort_t)hv[e]) << 16);
      if (e & 1) acc1 = fmaf(hf, W2[(k + e) * OUT_DIM + o], acc1);
      else       acc0 = fmaf(hf, W2[(k + e) * OUT_DIM + o], acc0);
    }
  }
  out[n * OUT_DIM + o] = acc0 + acc1 + b2[o];
}

extern "C" void kernel_launch(void* const* d_in, const int* in_sizes, int n_in,
                              void* d_out, int out_size, void* d_ws, size_t ws_size,
                              hipStream_t stream) {
  (void)in_sizes; (void)n_in; (void)out_size;
  const float* x      = (const float*)d_in[0];
  const float* coords = (const float*)d_in[1];
  const float* genes  = (const float*)d_in[2];
  const float* W1     = (const float*)d_in[3];
  const float* b1     = (const float*)d_in[4];
  const float* W2     = (const float*)d_in[5];
  const float* b2     = (const float*)d_in[6];
  float* out = (float*)d_out;

  char* ws = (char*)d_ws;
  size_t off = 0;
  auto alloc = [&](size_t bytes) -> void* {
    void* p = ws + off;
    off = (off + bytes + 255) & ~(size_t)255;
    return p;
  };
  float*    covet  = (float*)alloc((size_t)N_CELLS * 1024 * 4);       // 67 MB
  ushort_t* hbf    = (ushort_t*)alloc((size_t)N_CELLS * HID * 2);     // 33.5 MB
  ushort_t* Bh     = (ushort_t*)alloc((size_t)8 * NT * 4096 * 2);     // 6.2 MB
  float*    gcent  = (float*)alloc((size_t)N_CELLS * G_GENES * 4);
  float*    Gws    = (float*)alloc((size_t)N_CELLS * 64 * 4);
  float*    Vws    = (float*)alloc((size_t)N_CELLS * 64 * 4);
  float*    lamws  = (float*)alloc((size_t)N_CELLS * 8 * 4);
  int*      nidx   = (int*)alloc((size_t)N_CELLS * 8 * 4);
  double*   part   = (double*)alloc((size_t)128 * 32 * 8);
  float*    meanv  = (float*)alloc(G_GENES * 4);
  int*      binCnt = (int*)alloc((size_t)NBINS * 4);
  int*      binSt  = (int*)alloc((size_t)(NBINS + 1) * 4);
  int*      cursor = (int*)alloc((size_t)NBINS * 4);
  int*      binOf  = (int*)alloc((size_t)N_CELLS * 4);
  int*      binPts = (int*)alloc((size_t)N_CELLS * 4);
  if (off > ws_size) return;

  hipMemsetAsync(binCnt, 0, (size_t)NBINS * 4, stream);

  hipLaunchKernelGGL(packb_kernel, dim3(8, NT),   dim3(256), 0, stream, W1, Bh);
  hipLaunchKernelGGL(mean_part,    dim3(128),     dim3(256), 0, stream, genes, part);
  hipLaunchKernelGGL(mean_fin,     dim3(1),       dim3(64),  0, stream, part, meanv);
  hipLaunchKernelGGL(center_kernel,dim3(2048),    dim3(256), 0, stream, genes, meanv, gcent);
  hipLaunchKernelGGL(bin_count,    dim3(64),      dim3(256), 0, stream, coords, binCnt, binOf);
  hipLaunchKernelGGL(bin_scan,     dim3(1),       dim3(256), 0, stream, binCnt, binSt, cursor);
  hipLaunchKernelGGL(bin_scatter,  dim3(64),      dim3(256), 0, stream, binOf, cursor, binPts);
  hipLaunchKernelGGL(knn_search,   dim3(64),      dim3(256), 0, stream, coords, binSt, binPts, nidx);
  hipLaunchKernelGGL(gram_kernel,  dim3(N_CELLS), dim3(64),  0, stream, gcent, nidx, Gws);
  hipLaunchKernelGGL(jacobi_kernel,dim3(64),      dim3(256), 0, stream, Gws, Vws, lamws);
  hipLaunchKernelGGL(recon_kernel, dim3(N_CELLS), dim3(64),  0, stream, gcent, nidx, Vws, lamws, covet);
  hipLaunchKernelGGL(gemm1_kernel, dim3(1024),    dim3(256), 0, stream, x, covet, Bh, b1, hbf);
  hipLaunchKernelGGL(gemm2_kernel, dim3(2048),    dim3(256), 0, stream, hbf, W2, b2, out);
}

// Round 5
// 465.703 us; speedup vs baseline: 4.2969x; 1.1649x over previous
//
#include <hip/hip_runtime.h>
#include <hip/hip_bf16.h>
#include <math.h>

#define N_CELLS 16384
#define G_GENES 32
#define IN_DIM  2000
#define HID     1024
#define OUT_DIM 30
#define K_TOT   3024      // IN_DIM + 1024
#define K_PAD   3040      // 95 * 32
#define NT      95
#define GRID_B  128
#define NBINS   (GRID_B * GRID_B)
#define SCELL   (100.0f / (float)GRID_B)

typedef unsigned short ushort_t;
typedef __attribute__((ext_vector_type(8))) short bf16x8;
typedef __attribute__((ext_vector_type(4))) float f32x4;

// global_load_lds: 16B per lane, LDS dest = wave-uniform base + lane*16
__device__ __forceinline__ void glds16(const void* g, void* l) {
  __builtin_amdgcn_global_load_lds(
      (const __attribute__((address_space(1))) unsigned int*)g,
      (__attribute__((address_space(3))) unsigned int*)l, 16, 0, 0);
}

// counted waits + raw barrier (T4: never vmcnt(0) in main loop)
#define WAIT_VM6_BAR()  { asm volatile("s_waitcnt vmcnt(6)" ::: "memory"); \
                          asm volatile("s_waitcnt lgkmcnt(0)" ::: "memory"); \
                          __builtin_amdgcn_s_barrier(); \
                          __builtin_amdgcn_sched_barrier(0); }
#define WAIT_VM0()      { asm volatile("s_waitcnt vmcnt(0)" ::: "memory"); \
                          __builtin_amdgcn_sched_barrier(0); }
#define WAIT_LGKM_BAR() { asm volatile("s_waitcnt lgkmcnt(0)" ::: "memory"); \
                          __builtin_amdgcn_s_barrier(); \
                          __builtin_amdgcn_sched_barrier(0); }

// ---------------- mean (two-stage, deterministic f64) ----------------
__global__ __launch_bounds__(256) void mean_part(const float* __restrict__ genes,
                                                 double* __restrict__ part) {
  const int b = blockIdx.x;
  const int tid = threadIdx.x;
  const int g = tid & 31, cs = tid >> 5;
  double acc = 0.0;
#pragma unroll
  for (int it = 0; it < 16; ++it) {
    const int cell = b * 128 + cs + it * 8;
    acc += (double)genes[cell * G_GENES + g];
  }
  __shared__ double red[256];
  red[tid] = acc;
  __syncthreads();
  if (tid < 32) {
    double s = red[tid];
#pragma unroll
    for (int u = 1; u < 8; ++u) s += red[tid + u * 32];
    part[b * 32 + tid] = s;
  }
}

__global__ __launch_bounds__(64) void mean_fin(const double* __restrict__ part,
                                               float* __restrict__ meanv) {
  const int g = threadIdx.x;
  if (g >= 32) return;
  double s = 0.0;
  for (int b = 0; b < 128; ++b) s += part[b * 32 + g];
  meanv[g] = (float)(s / (double)N_CELLS);
}

// ---------------- center genes, pre-scale by 1/sqrt(k-1) ----------------
__global__ __launch_bounds__(256) void center_kernel(const float* __restrict__ genes,
                                                     const float* __restrict__ meanv,
                                                     float* __restrict__ gcent) {
  const int i = blockIdx.x * 256 + threadIdx.x;
  const int g = i & 31;
  gcent[i] = (genes[i] - meanv[g]) * 0.37796447300922722721f;  // 1/sqrt(7)
}

// ---------------- grid-binned exact kNN ----------------
__global__ __launch_bounds__(256) void bin_count(const float* __restrict__ coords,
                                                 int* __restrict__ cnt,
                                                 int* __restrict__ binOf) {
  const int i = blockIdx.x * 256 + threadIdx.x;
  const float2 p = ((const float2*)coords)[i];
  const float inv_s = (float)GRID_B / 100.0f;
  const int bx = min(GRID_B - 1, max(0, (int)(p.x * inv_s)));
  const int by = min(GRID_B - 1, max(0, (int)(p.y * inv_s)));
  const int b = by * GRID_B + bx;
  binOf[i] = b;
  atomicAdd(&cnt[b], 1);
}

__global__ __launch_bounds__(256) void bin_scan(const int* __restrict__ cnt,
                                                int* __restrict__ binStart,
                                                int* __restrict__ cursor) {
  __shared__ int ps[256];
  const int tid = threadIdx.x;
  int s = 0;
  for (int i = 0; i < 64; ++i) s += cnt[tid * 64 + i];
  ps[tid] = s;
  __syncthreads();
  for (int off = 1; off < 256; off <<= 1) {
    const int add = (tid >= off) ? ps[tid - off] : 0;
    __syncthreads();
    ps[tid] += add;
    __syncthreads();
  }
  int run = ps[tid] - s;
  for (int i = 0; i < 64; ++i) {
    const int b = tid * 64 + i;
    binStart[b] = run;
    cursor[b] = run;
    run += cnt[b];
  }
  if (tid == 255) binStart[NBINS] = run;
}

__global__ __launch_bounds__(256) void bin_scatter(const int* __restrict__ binOf,
                                                   int* __restrict__ cursor,
                                                   int* __restrict__ binPts) {
  const int i = blockIdx.x * 256 + threadIdx.x;
  const int pos = atomicAdd(&cursor[binOf[i]], 1);
  binPts[pos] = i;
}

__global__ __launch_bounds__(256) void knn_search(const float* __restrict__ coords,
                                                  const int* __restrict__ binStart,
                                                  const int* __restrict__ binPts,
                                                  int* __restrict__ nidx) {
  const int cell = blockIdx.x * 256 + threadIdx.x;
  const float qx = coords[cell * 2 + 0], qy = coords[cell * 2 + 1];
  const float sqi = __fadd_rn(__fmul_rn(qx, qx), __fmul_rn(qy, qy));
  const float inv_s = (float)GRID_B / 100.0f;
  const int bx = min(GRID_B - 1, max(0, (int)(qx * inv_s)));
  const int by = min(GRID_B - 1, max(0, (int)(qy * inv_s)));

  unsigned long long kk[8];
#pragma unroll
  for (int i = 0; i < 8; ++i) kk[i] = ~0ull;

  auto scan_bin = [&](int bxx, int byy) {
    if (bxx < 0 || bxx >= GRID_B || byy < 0 || byy >= GRID_B) return;
    const int b = byy * GRID_B + bxx;
    const int s = binStart[b], e = binStart[b + 1];
    for (int p = s; p < e; ++p) {
      const int j = binPts[p];
      const float2 pc = ((const float2*)coords)[j];
      const float sqj = __fadd_rn(__fmul_rn(pc.x, pc.x), __fmul_rn(pc.y, pc.y));
      const float dot = __fmaf_rn(qy, pc.y, __fmul_rn(qx, pc.x));
      const float d2  = __fsub_rn(__fadd_rn(sqi, sqj), __fmul_rn(2.0f, dot));
      unsigned int sb = __float_as_uint(d2);
      sb = (sb & 0x80000000u) ? ~sb : (sb | 0x80000000u);
      unsigned long long key = ((unsigned long long)sb << 32) | (unsigned int)j;
      if (key < kk[7]) {
#pragma unroll
        for (int q2 = 0; q2 < 8; ++q2) {
          const bool lt = key < kk[q2];
          const unsigned long long tmp = kk[q2];
          kk[q2] = lt ? key : kk[q2];
          key = lt ? tmp : key;
        }
      }
    }
  };

  bool done = false;
  for (int r = 0; r < GRID_B; ++r) {
    if (!done) {
      if (r == 0) {
        scan_bin(bx, by);
      } else {
        for (int dx = -r; dx <= r; ++dx) { scan_bin(bx + dx, by - r); scan_bin(bx + dx, by + r); }
        for (int dy = -r + 1; dy <= r - 1; ++dy) { scan_bin(bx - r, by + dy); scan_bin(bx + r, by + dy); }
      }
      if (kk[7] != ~0ull) {
        const unsigned int sb = (unsigned int)(kk[7] >> 32);
        const float wd2 = __uint_as_float((sb & 0x80000000u) ? (sb ^ 0x80000000u) : ~sb);
        const float bnd = (float)r * SCELL;
        if (wd2 < bnd * bnd * 0.998f - 0.05f) done = true;
      }
    }
    if (!__any(!done)) break;
  }
#pragma unroll
  for (int i = 0; i < 8; ++i) nidx[cell * 8 + i] = (int)(kk[i] & 0xFFFFFFFFu);
}

// ---------------- Gram matrix G = A A^T (8x8) per cell ----------------
__global__ __launch_bounds__(64) void gram_kernel(const float* __restrict__ gcent,
                                                  const int* __restrict__ nidx,
                                                  float* __restrict__ Gws) {
  const int cell = blockIdx.x;
  const int lane = threadIdx.x;
  __shared__ float A[8][33];
#pragma unroll
  for (int q = 0; q < 4; ++q) {
    const int e = lane + (q << 6);
    const int n = e >> 5, g = e & 31;
    const int src = nidx[cell * 8 + n];
    A[n][g] = gcent[src * G_GENES + g];
  }
  __syncthreads();
  const int i = lane >> 3, j = lane & 7;
  float acc = 0.f;
#pragma unroll
  for (int g = 0; g < 32; ++g) acc = fmaf(A[i][g], A[j][g], acc);
  Gws[cell * 64 + lane] = acc;
}

// ---------------- 8x8 Jacobi eigensolver: one cell per lane ----------------
__global__ __launch_bounds__(256) void jacobi_kernel(const float* __restrict__ Gws,
                                                     float* __restrict__ Vws,
                                                     float* __restrict__ lamws) {
  const int cell = blockIdx.x * 256 + threadIdx.x;
  float Gm[8][8], V[8][8];
#pragma unroll
  for (int e = 0; e < 64; ++e) Gm[e >> 3][e & 7] = Gws[cell * 64 + e];
#pragma unroll
  for (int i = 0; i < 8; ++i)
#pragma unroll
    for (int j = 0; j < 8; ++j) V[i][j] = (i == j) ? 1.0f : 0.0f;

  for (int sweep = 0; sweep < 8; ++sweep) {
#pragma unroll
    for (int p = 0; p < 7; ++p) {
#pragma unroll
      for (int q = p + 1; q < 8; ++q) {
        const float apq = Gm[p][q];
        const float app = Gm[p][p], aqq = Gm[q][q];
        float t;
        if (apq != 0.0f) {
          const float tau = (aqq - app) / (2.0f * apq);
          const float r = sqrtf(fmaf(tau, tau, 1.0f));
          t = copysignf(1.0f, tau) / (fabsf(tau) + r);
        } else {
          t = 0.0f;
        }
        const float c = 1.0f / sqrtf(fmaf(t, t, 1.0f));
        const float s = t * c;
#pragma unroll
        for (int r2 = 0; r2 < 8; ++r2) {
          const float gp = Gm[p][r2], gq = Gm[q][r2];
          Gm[p][r2] = fmaf(c, gp, -s * gq);
          Gm[q][r2] = fmaf(s, gp,  c * gq);
        }
#pragma unroll
        for (int r2 = 0; r2 < 8; ++r2) {
          const float gp = Gm[r2][p], gq = Gm[r2][q];
          Gm[r2][p] = fmaf(c, gp, -s * gq);
          Gm[r2][q] = fmaf(s, gp,  c * gq);
        }
#pragma unroll
        for (int r2 = 0; r2 < 8; ++r2) {
          const float vp = V[r2][p], vq = V[r2][q];
          V[r2][p] = fmaf(c, vp, -s * vq);
          V[r2][q] = fmaf(s, vp,  c * vq);
        }
      }
    }
  }
#pragma unroll
  for (int e = 0; e < 64; ++e) Vws[cell * 64 + e] = V[e >> 3][e & 7];
#pragma unroll
  for (int m = 0; m < 8; ++m) lamws[cell * 8 + m] = Gm[m][m];
}

// ---------------- covet = A^T V diag(lam^-1/2) V^T A ----------------
__global__ __launch_bounds__(64) void recon_kernel(const float* __restrict__ gcent,
                                                   const int* __restrict__ nidx,
                                                   const float* __restrict__ Vws,
                                                   const float* __restrict__ lamws,
                                                   float* __restrict__ covet) {
  const int cell = blockIdx.x;
  const int lane = threadIdx.x;
  __shared__ float A[8][33];
  __shared__ float Ws[8][33];
  __shared__ float Vs[64];
  __shared__ float lamS[8];
#pragma unroll
  for (int q = 0; q < 4; ++q) {
    const int e = lane + (q << 6);
    const int n = e >> 5, g = e & 31;
    const int src = nidx[cell * 8 + n];
    A[n][g] = gcent[src * G_GENES + g];
  }
  Vs[lane] = Vws[cell * 64 + lane];
  if (lane < 8) lamS[lane] = lamws[cell * 8 + lane];
  __syncthreads();

  float maxl = 0.f;
#pragma unroll
  for (int m = 0; m < 8; ++m) maxl = fmaxf(maxl, lamS[m]);
  const float thr = maxl * 1e-8f;

#pragma unroll
  for (int q = 0; q < 4; ++q) {
    const int e = lane + (q << 6);
    const int m = e >> 5, g = e & 31;
    float acc = 0.f;
#pragma unroll
    for (int i = 0; i < 8; ++i) acc = fmaf(Vs[i * 8 + m], A[i][g], acc);
    const float l = lamS[m];
    const float scm = (l > thr) ? sqrtf(1.0f / sqrtf(l)) : 0.0f;
    Ws[m][g] = acc * scm;
  }
  __syncthreads();
#pragma unroll
  for (int r = 0; r < 16; ++r) {
    const int o = (r << 6) + lane;
    const int g = o >> 5, hh = o & 31;
    float acc = 0.f;
#pragma unroll
    for (int m = 0; m < 8; ++m) acc = fmaf(Ws[m][g], Ws[m][hh], acc);
    covet[(size_t)cell * 1024 + o] = acc;
  }
}

// ---------------- pack W1^T into swizzled bf16 tiles (hi only) ----------------
__global__ __launch_bounds__(256) void packb_kernel(const float* __restrict__ W1,
                                                    ushort_t* __restrict__ Bh) {
  const int cb = blockIdx.x;   // 0..7 column block
  const int t  = blockIdx.y;   // 0..94 k-step
  const int tid = threadIdx.x;
  __shared__ float L[32][129];
  const int k0 = t * 32, n0 = cb * 128;
  {
    const int kl = tid >> 3;
    const int nw = tid & 7;
#pragma unroll
    for (int u = 0; u < 4; ++u) {
      const int nl = (nw + u * 8) * 4;
      float4 v = make_float4(0.f, 0.f, 0.f, 0.f);
      if (k0 + kl < K_TOT) v = *(const float4*)(W1 + (size_t)(k0 + kl) * HID + n0 + nl);
      L[kl][nl + 0] = v.x; L[kl][nl + 1] = v.y; L[kl][nl + 2] = v.z; L[kl][nl + 3] = v.w;
    }
  }
  __syncthreads();
  const size_t tileBase = ((size_t)cb * NT + t) * 4096;
#pragma unroll
  for (int qq = 0; qq < 2; ++qq) {
    const int ch = tid + 256 * qq;
    const int r = ch >> 2, cpos = ch & 3;
    const int cdata = cpos ^ ((r >> 1) & 3);
    ushort_t hi[8];
#pragma unroll
    for (int e = 0; e < 8; ++e) {
      const int kl = cdata * 8 + e;
      const float v = (k0 + kl < K_TOT) ? L[kl][r] : 0.f;
      hi[e] = __builtin_bit_cast(ushort_t, __float2bfloat16(v));
    }
    *(bf16x8*)(Bh + tileBase + ch * 8) = *(const bf16x8*)hi;
  }
}

// ---------------- GEMM1: counted-vmcnt pipeline, bf16 MFMA ----------------
// B: 3-buffer glds, 2 tiles in flight; A: reg ping-pong 2 ahead + LDS dbuf.
// One raw s_barrier/iter, vmcnt(6) (never 0 in main loop).
__global__ __launch_bounds__(256, 3) void gemm1_kernel(const float* __restrict__ x,
                                                       const float* __restrict__ cov,
                                                       const ushort_t* __restrict__ Bh,
                                                       const float* __restrict__ b1,
                                                       ushort_t* __restrict__ h) {
  __shared__ ushort_t As[2][128 * 40];    // 20 KB, stride 40 ushorts
  __shared__ ushort_t Bhs[3][4096];       // 24 KB, 16B-chunk swizzled

  const int tid = threadIdx.x;
  const int id  = blockIdx.x;
  const int swz = (id & 7) * 128 + (id >> 3);  // XCD-bijective (1024 % 8 == 0)
  const int bx  = swz & 7, by = swz >> 3;
  const int row0 = by << 7, col0 = bx << 7;

  const int arow = tid >> 1, acol = (tid & 1) << 4;
  const int lane = tid & 63, wv = tid >> 6;
  const int m_base = (wv >> 1) << 6, n_base = (wv & 1) << 6;
  const int l15 = lane & 15, l4 = lane >> 4;

  f32x4 acc[4][4];
#pragma unroll
  for (int i = 0; i < 4; ++i)
#pragma unroll
    for (int j = 0; j < 4; ++j) acc[i][j] = (f32x4){0.f, 0.f, 0.f, 0.f};

  float4 pA[4], pB[4];   // two named reg sets (rule #20: static indexing)

  // branchless: ALWAYS 4 global_load_dwordx4 (uniform vmcnt accounting);
  // pad region reads clamped covet addr, zeroed at store time.
  auto loadA = [&](int t, float4* sa) {
    const int k0 = t << 5;
    const int rg = row0 + arow;
#pragma unroll
    for (int c = 0; c < 4; ++c) {
      const int kg = k0 + acol + (c << 2);
      const float* p = (kg < IN_DIM)
          ? (x + (size_t)rg * IN_DIM + kg)
          : (cov + ((size_t)rg << 10) + min(kg - IN_DIM, 1020));
      sa[c] = *(const float4*)p;
    }
  };
  auto storeA = [&](const float4* sa, int buf) {
    ushort_t hi[16];
#pragma unroll
    for (int c = 0; c < 4; ++c) {
      const float* vv = (const float*)&sa[c];
#pragma unroll
      for (int e = 0; e < 4; ++e)
        hi[c * 4 + e] = __builtin_bit_cast(ushort_t, __float2bfloat16(vv[e]));
    }
    const int ao = arow * 40 + acol;
    *(bf16x8*)(&As[buf][ao])     = *(const bf16x8*)&hi[0];
    *(bf16x8*)(&As[buf][ao + 8]) = *(const bf16x8*)&hi[8];
  };
  auto storeA_mask = [&](const float4* sa, int buf, int t) {  // last tile: zero pad
    const int k0 = t << 5;
    ushort_t hi[16];
#pragma unroll
    for (int c = 0; c < 4; ++c) {
      const float* vv = (const float*)&sa[c];
#pragma unroll
      for (int e = 0; e < 4; ++e) {
        const int kg = k0 + acol + c * 4 + e;
        const float v = (kg < K_TOT) ? vv[e] : 0.f;
        hi[c * 4 + e] = __builtin_bit_cast(ushort_t, __float2bfloat16(v));
      }
    }
    const int ao = arow * 40 + acol;
    *(bf16x8*)(&As[buf][ao])     = *(const bf16x8*)&hi[0];
    *(bf16x8*)(&As[buf][ao + 8]) = *(const bf16x8*)&hi[8];
  };
  auto gldsB = [&](int t, int buf) {
    const size_t go = ((size_t)bx * NT + t) * 4096;
    glds16(Bh + go + tid * 8,        &Bhs[buf][tid * 8]);
    glds16(Bh + go + 2048 + tid * 8, &Bhs[buf][2048 + tid * 8]);
  };
  auto compute = [&](int s) {
    bf16x8 ah[4], bh[4];
    const ushort_t* Ab = &As[s & 1][0];
    const ushort_t* Bb = &Bhs[s % 3][0];
#pragma unroll
    for (int i = 0; i < 4; ++i)
      ah[i] = *(const bf16x8*)(Ab + (m_base + i * 16 + l15) * 40 + l4 * 8);
#pragma unroll
    for (int j = 0; j < 4; ++j) {
      const int row = n_base + j * 16 + l15;
      const int cp  = l4 ^ ((row >> 1) & 3);
      bh[j] = *(const bf16x8*)(Bb + row * 32 + cp * 8);
    }
#pragma unroll
    for (int i = 0; i < 4; ++i)
#pragma unroll
      for (int j = 0; j < 4; ++j)
        acc[i][j] = __builtin_amdgcn_mfma_f32_16x16x32_bf16(ah[i], bh[j], acc[i][j], 0, 0, 0);
  };

  // prologue: issue tiles 0 and 1 (order: gldsB before loadA each tile)
  gldsB(0, 0);
  loadA(0, pA);
  gldsB(1, 1);
  loadA(1, pB);
  storeA(pA, 0);          // compiler waits vmcnt(6) for pA; retires gldsB(0) too
  WAIT_VM6_BAR();

  // main loop: s = 0..91, unrolled in pairs for static reg-set names
  for (int tp = 0; tp < 46; ++tp) {
    const int s0 = 2 * tp;
    {   // s = s0 (even): prefetch tile s0+2 -> pA; store A(s0+1) from pB
      gldsB(s0 + 2, (s0 + 2) % 3);
      loadA(s0 + 2, pA);
      compute(s0);
      storeA(pB, 1);
      WAIT_VM6_BAR();
    }
    {   // s = s0+1 (odd): prefetch tile s0+3 -> pB; store A(s0+2) from pA
      gldsB(s0 + 3, (s0 + 3) % 3);
      loadA(s0 + 3, pB);
      compute(s0 + 1);
      storeA(pA, 0);
      WAIT_VM6_BAR();
    }
  }
  // s = 92: prefetch tile 94 -> pA; store A(93) from pB
  gldsB(94, 94 % 3);
  loadA(94, pA);
  compute(92);
  storeA(pB, 1);
  WAIT_VM6_BAR();
  // s = 93: no prefetch; drain; store A(94) masked from pA
  compute(93);
  WAIT_VM0();
  storeA_mask(pA, 0, 94);
  WAIT_LGKM_BAR();
  // s = 94
  compute(94);

  float bb[4];
#pragma unroll
  for (int j = 0; j < 4; ++j) bb[j] = b1[col0 + n_base + j * 16 + l15];
#pragma unroll
  for (int i = 0; i < 4; ++i) {
    const int rbase = row0 + m_base + i * 16 + l4 * 4;
#pragma unroll
    for (int j = 0; j < 4; ++j) {
      const int c = col0 + n_base + j * 16 + l15;
#pragma unroll
      for (int q = 0; q < 4; ++q) {
        const float v = fmaxf(acc[i][j][q] + bb[j], 0.f);
        h[(size_t)(rbase + q) * HID + c] = __builtin_bit_cast(ushort_t, __float2bfloat16(v));
      }
    }
  }
}

// ---------------- pack W2 -> W2t bf16 [32][1024] (pad 30->32) ----------------
__global__ __launch_bounds__(256) void packw2_kernel(const float* __restrict__ W2,
                                                     ushort_t* __restrict__ W2t) {
  const int k = blockIdx.x * 256 + threadIdx.x;  // 0..1023
#pragma unroll
  for (int o = 0; o < 32; ++o) {
    const float v = (o < OUT_DIM) ? W2[k * OUT_DIM + o] : 0.f;
    W2t[o * HID + k] = __builtin_bit_cast(ushort_t, __float2bfloat16(v));
  }
}

// ---------------- GEMM2: out = h @ W2 + b2 via bf16 MFMA ----------------
// block = 32 rows; 4 waves = 2 row-tiles x 2 col-tiles of 16x16
__global__ __launch_bounds__(256) void gemm2_kernel(const ushort_t* __restrict__ h,
                                                    const ushort_t* __restrict__ W2t,
                                                    const float* __restrict__ b2,
                                                    float* __restrict__ out) {
  const int tid = threadIdx.x;
  const int lane = tid & 63, wv = tid >> 6;
  const int rowt = wv & 1, colt = wv >> 1;
  const int l15 = lane & 15, l4 = lane >> 4;
  const int row0 = blockIdx.x * 32 + rowt * 16;
  const int col  = colt * 16 + l15;

  f32x4 acc = (f32x4){0.f, 0.f, 0.f, 0.f};
  const ushort_t* ha = h + (size_t)(row0 + l15) * HID + l4 * 8;
  const ushort_t* wb = W2t + (size_t)col * HID + l4 * 8;
#pragma unroll 8
  for (int k0 = 0; k0 < HID; k0 += 32) {
    const bf16x8 av = *(const bf16x8*)(ha + k0);
    const bf16x8 bv = *(const bf16x8*)(wb + k0);
    acc = __builtin_amdgcn_mfma_f32_16x16x32_bf16(av, bv, acc, 0, 0, 0);
  }
  if (col < OUT_DIM) {
    const float bias = b2[col];
#pragma unroll
    for (int q = 0; q < 4; ++q) {
      const int r = row0 + l4 * 4 + q;
      out[(size_t)r * OUT_DIM + col] = acc[q] + bias;
    }
  }
}

extern "C" void kernel_launch(void* const* d_in, const int* in_sizes, int n_in,
                              void* d_out, int out_size, void* d_ws, size_t ws_size,
                              hipStream_t stream) {
  (void)in_sizes; (void)n_in; (void)out_size;
  const float* x      = (const float*)d_in[0];
  const float* coords = (const float*)d_in[1];
  const float* genes  = (const float*)d_in[2];
  const float* W1     = (const float*)d_in[3];
  const float* b1     = (const float*)d_in[4];
  const float* W2     = (const float*)d_in[5];
  const float* b2     = (const float*)d_in[6];
  float* out = (float*)d_out;

  char* ws = (char*)d_ws;
  size_t off = 0;
  auto alloc = [&](size_t bytes) -> void* {
    void* p = ws + off;
    off = (off + bytes + 255) & ~(size_t)255;
    return p;
  };
  float*    covet  = (float*)alloc((size_t)N_CELLS * 1024 * 4);       // 67 MB
  ushort_t* hbf    = (ushort_t*)alloc((size_t)N_CELLS * HID * 2);     // 33.5 MB
  ushort_t* Bh     = (ushort_t*)alloc((size_t)8 * NT * 4096 * 2);     // 6.2 MB
  ushort_t* W2t    = (ushort_t*)alloc((size_t)32 * HID * 2);          // 64 KB
  float*    gcent  = (float*)alloc((size_t)N_CELLS * G_GENES * 4);
  float*    Gws    = (float*)alloc((size_t)N_CELLS * 64 * 4);
  float*    Vws    = (float*)alloc((size_t)N_CELLS * 64 * 4);
  float*    lamws  = (float*)alloc((size_t)N_CELLS * 8 * 4);
  int*      nidx   = (int*)alloc((size_t)N_CELLS * 8 * 4);
  double*   part   = (double*)alloc((size_t)128 * 32 * 8);
  float*    meanv  = (float*)alloc(G_GENES * 4);
  int*      binCnt = (int*)alloc((size_t)NBINS * 4);
  int*      binSt  = (int*)alloc((size_t)(NBINS + 1) * 4);
  int*      cursor = (int*)alloc((size_t)NBINS * 4);
  int*      binOf  = (int*)alloc((size_t)N_CELLS * 4);
  int*      binPts = (int*)alloc((size_t)N_CELLS * 4);
  if (off > ws_size) return;

  hipMemsetAsync(binCnt, 0, (size_t)NBINS * 4, stream);

  hipLaunchKernelGGL(packb_kernel, dim3(8, NT),   dim3(256), 0, stream, W1, Bh);
  hipLaunchKernelGGL(packw2_kernel,dim3(4),       dim3(256), 0, stream, W2, W2t);
  hipLaunchKernelGGL(mean_part,    dim3(128),     dim3(256), 0, stream, genes, part);
  hipLaunchKernelGGL(mean_fin,     dim3(1),       dim3(64),  0, stream, part, meanv);
  hipLaunchKernelGGL(center_kernel,dim3(2048),    dim3(256), 0, stream, genes, meanv, gcent);
  hipLaunchKernelGGL(bin_count,    dim3(64),      dim3(256), 0, stream, coords, binCnt, binOf);
  hipLaunchKernelGGL(bin_scan,     dim3(1),       dim3(256), 0, stream, binCnt, binSt, cursor);
  hipLaunchKernelGGL(bin_scatter,  dim3(64),      dim3(256), 0, stream, binOf, cursor, binPts);
  hipLaunchKernelGGL(knn_search,   dim3(64),      dim3(256), 0, stream, coords, binSt, binPts, nidx);
  hipLaunchKernelGGL(gram_kernel,  dim3(N_CELLS), dim3(64),  0, stream, gcent, nidx, Gws);
  hipLaunchKernelGGL(jacobi_kernel,dim3(64),      dim3(256), 0, stream, Gws, Vws, lamws);
  hipLaunchKernelGGL(recon_kernel, dim3(N_CELLS), dim3(64),  0, stream, gcent, nidx, Vws, lamws, covet);
  hipLaunchKernelGGL(gemm1_kernel, dim3(1024),    dim3(256), 0, stream, x, covet, Bh, b1, hbf);
  hipLaunchKernelGGL(gemm2_kernel, dim3(512),     dim3(256), 0, stream, hbf, W2t, b2, out);
}

// Round 6
// 366.287 us; speedup vs baseline: 5.4632x; 1.2714x over previous
//
#include <hip/hip_runtime.h>
#include <hip/hip_bf16.h>
#include <math.h>

#define N_CELLS 16384
#define G_GENES 32
#define IN_DIM  2000
#define HID     1024
#define OUT_DIM 30
#define K_TOT   3024      // IN_DIM + 1024
#define K_PAD   3040      // 95 * 32
#define NT      95
#define GRID_B  128
#define NBINS   (GRID_B * GRID_B)
#define SCELL   (100.0f / (float)GRID_B)

typedef unsigned short ushort_t;
typedef __attribute__((ext_vector_type(8))) short bf16x8;
typedef __attribute__((ext_vector_type(4))) float f32x4;

__device__ __forceinline__ ushort_t f2bf(float v) {
  return __builtin_bit_cast(ushort_t, __float2bfloat16(v));
}

// global_load_lds: 16B per lane, LDS dest = wave-uniform base + lane*16
__device__ __forceinline__ void glds16(const void* g, void* l) {
  __builtin_amdgcn_global_load_lds(
      (const __attribute__((address_space(1))) unsigned int*)g,
      (__attribute__((address_space(3))) unsigned int*)l, 16, 0, 0);
}

// ---------------- mean (two-stage, deterministic f64) ----------------
__global__ __launch_bounds__(256) void mean_part(const float* __restrict__ genes,
                                                 double* __restrict__ part) {
  const int b = blockIdx.x;
  const int tid = threadIdx.x;
  const int g = tid & 31, cs = tid >> 5;
  double acc = 0.0;
#pragma unroll
  for (int it = 0; it < 16; ++it) {
    const int cell = b * 128 + cs + it * 8;
    acc += (double)genes[cell * G_GENES + g];
  }
  __shared__ double red[256];
  red[tid] = acc;
  __syncthreads();
  if (tid < 32) {
    double s = red[tid];
#pragma unroll
    for (int u = 1; u < 8; ++u) s += red[tid + u * 32];
    part[b * 32 + tid] = s;
  }
}

__global__ __launch_bounds__(64) void mean_fin(const double* __restrict__ part,
                                               float* __restrict__ meanv) {
  const int g = threadIdx.x;
  if (g >= 32) return;
  double s = 0.0;
  for (int b = 0; b < 128; ++b) s += part[b * 32 + g];
  meanv[g] = (float)(s / (double)N_CELLS);
}

// ---------------- center genes, pre-scale by 1/sqrt(k-1) ----------------
__global__ __launch_bounds__(256) void center_kernel(const float* __restrict__ genes,
                                                     const float* __restrict__ meanv,
                                                     float* __restrict__ gcent) {
  const int i = blockIdx.x * 256 + threadIdx.x;
  const int g = i & 31;
  gcent[i] = (genes[i] - meanv[g]) * 0.37796447300922722721f;  // 1/sqrt(7)
}

// ---------------- convert x -> Abf (bf16) and zero the k-pad ----------------
__global__ __launch_bounds__(256) void convx_kernel(const float* __restrict__ x,
                                                    ushort_t* __restrict__ Abf) {
  const int row = blockIdx.x;
  const int t = threadIdx.x;
  if (t < 250) {
    const float4 v0 = *(const float4*)(x + (size_t)row * IN_DIM + t * 8);
    const float4 v1 = *(const float4*)(x + (size_t)row * IN_DIM + t * 8 + 4);
    ushort_t o[8] = { f2bf(v0.x), f2bf(v0.y), f2bf(v0.z), f2bf(v0.w),
                      f2bf(v1.x), f2bf(v1.y), f2bf(v1.z), f2bf(v1.w) };
    *(bf16x8*)(Abf + (size_t)row * K_PAD + t * 8) = *(const bf16x8*)o;
  } else if (t < 252) {
    const int u = t - 250;
    const bf16x8 z = (bf16x8){0, 0, 0, 0, 0, 0, 0, 0};
    *(bf16x8*)(Abf + (size_t)row * K_PAD + K_TOT + u * 8) = z;
  }
}

// ---------------- grid-binned exact kNN ----------------
__global__ __launch_bounds__(256) void bin_count(const float* __restrict__ coords,
                                                 int* __restrict__ cnt,
                                                 int* __restrict__ binOf) {
  const int i = blockIdx.x * 256 + threadIdx.x;
  const float2 p = ((const float2*)coords)[i];
  const float inv_s = (float)GRID_B / 100.0f;
  const int bx = min(GRID_B - 1, max(0, (int)(p.x * inv_s)));
  const int by = min(GRID_B - 1, max(0, (int)(p.y * inv_s)));
  const int b = by * GRID_B + bx;
  binOf[i] = b;
  atomicAdd(&cnt[b], 1);
}

__global__ __launch_bounds__(256) void bin_scan(const int* __restrict__ cnt,
                                                int* __restrict__ binStart,
                                                int* __restrict__ cursor) {
  __shared__ int ps[256];
  const int tid = threadIdx.x;
  int s = 0;
  for (int i = 0; i < 64; ++i) s += cnt[tid * 64 + i];
  ps[tid] = s;
  __syncthreads();
  for (int off = 1; off < 256; off <<= 1) {
    const int add = (tid >= off) ? ps[tid - off] : 0;
    __syncthreads();
    ps[tid] += add;
    __syncthreads();
  }
  int run = ps[tid] - s;
  for (int i = 0; i < 64; ++i) {
    const int b = tid * 64 + i;
    binStart[b] = run;
    cursor[b] = run;
    run += cnt[b];
  }
  if (tid == 255) binStart[NBINS] = run;
}

__global__ __launch_bounds__(256) void bin_scatter(const int* __restrict__ binOf,
                                                   int* __restrict__ cursor,
                                                   int* __restrict__ binPts) {
  const int i = blockIdx.x * 256 + threadIdx.x;
  const int pos = atomicAdd(&cursor[binOf[i]], 1);
  binPts[pos] = i;
}

__global__ __launch_bounds__(256) void knn_search(const float* __restrict__ coords,
                                                  const int* __restrict__ binStart,
                                                  const int* __restrict__ binPts,
                                                  int* __restrict__ nidx) {
  const int cell = blockIdx.x * 256 + threadIdx.x;
  const float qx = coords[cell * 2 + 0], qy = coords[cell * 2 + 1];
  const float sqi = __fadd_rn(__fmul_rn(qx, qx), __fmul_rn(qy, qy));
  const float inv_s = (float)GRID_B / 100.0f;
  const int bx = min(GRID_B - 1, max(0, (int)(qx * inv_s)));
  const int by = min(GRID_B - 1, max(0, (int)(qy * inv_s)));

  unsigned long long kk[8];
#pragma unroll
  for (int i = 0; i < 8; ++i) kk[i] = ~0ull;

  auto scan_bin = [&](int bxx, int byy) {
    if (bxx < 0 || bxx >= GRID_B || byy < 0 || byy >= GRID_B) return;
    const int b = byy * GRID_B + bxx;
    const int s = binStart[b], e = binStart[b + 1];
    for (int p = s; p < e; ++p) {
      const int j = binPts[p];
      const float2 pc = ((const float2*)coords)[j];
      const float sqj = __fadd_rn(__fmul_rn(pc.x, pc.x), __fmul_rn(pc.y, pc.y));
      const float dot = __fmaf_rn(qy, pc.y, __fmul_rn(qx, pc.x));
      const float d2  = __fsub_rn(__fadd_rn(sqi, sqj), __fmul_rn(2.0f, dot));
      unsigned int sb = __float_as_uint(d2);
      sb = (sb & 0x80000000u) ? ~sb : (sb | 0x80000000u);
      unsigned long long key = ((unsigned long long)sb << 32) | (unsigned int)j;
      if (key < kk[7]) {
#pragma unroll
        for (int q2 = 0; q2 < 8; ++q2) {
          const bool lt = key < kk[q2];
          const unsigned long long tmp = kk[q2];
          kk[q2] = lt ? key : kk[q2];
          key = lt ? tmp : key;
        }
      }
    }
  };

  bool done = false;
  for (int r = 0; r < GRID_B; ++r) {
    if (!done) {
      if (r == 0) {
        scan_bin(bx, by);
      } else {
        for (int dx = -r; dx <= r; ++dx) { scan_bin(bx + dx, by - r); scan_bin(bx + dx, by + r); }
        for (int dy = -r + 1; dy <= r - 1; ++dy) { scan_bin(bx - r, by + dy); scan_bin(bx + r, by + dy); }
      }
      if (kk[7] != ~0ull) {
        const unsigned int sb = (unsigned int)(kk[7] >> 32);
        const float wd2 = __uint_as_float((sb & 0x80000000u) ? (sb ^ 0x80000000u) : ~sb);
        const float bnd = (float)r * SCELL;
        if (wd2 < bnd * bnd * 0.998f - 0.05f) done = true;
      }
    }
    if (!__any(!done)) break;
  }
#pragma unroll
  for (int i = 0; i < 8; ++i) nidx[cell * 8 + i] = (int)(kk[i] & 0xFFFFFFFFu);
}

// ---------------- Gram matrix G = A A^T (8x8), 4 cells (waves) per block ----------------
__global__ __launch_bounds__(256) void gram_kernel(const float* __restrict__ gcent,
                                                   const int* __restrict__ nidx,
                                                   float* __restrict__ Gws) {
  const int wv = threadIdx.x >> 6, lane = threadIdx.x & 63;
  const int cell = blockIdx.x * 4 + wv;
  __shared__ float A[4][8][33];
#pragma unroll
  for (int q = 0; q < 4; ++q) {
    const int e = lane + (q << 6);
    const int n = e >> 5, g = e & 31;
    const int src = nidx[cell * 8 + n];
    A[wv][n][g] = gcent[src * G_GENES + g];
  }
  __syncthreads();
  const int i = lane >> 3, j = lane & 7;
  float acc = 0.f;
#pragma unroll
  for (int g = 0; g < 32; ++g) acc = fmaf(A[wv][i][g], A[wv][j][g], acc);
  Gws[cell * 64 + lane] = acc;
}

// ---------------- 8x8 Jacobi eigensolver: one cell per lane ----------------
__global__ __launch_bounds__(256) void jacobi_kernel(const float* __restrict__ Gws,
                                                     float* __restrict__ Vws,
                                                     float* __restrict__ lamws) {
  const int cell = blockIdx.x * 256 + threadIdx.x;
  float Gm[8][8], V[8][8];
#pragma unroll
  for (int e = 0; e < 64; ++e) Gm[e >> 3][e & 7] = Gws[cell * 64 + e];
#pragma unroll
  for (int i = 0; i < 8; ++i)
#pragma unroll
    for (int j = 0; j < 8; ++j) V[i][j] = (i == j) ? 1.0f : 0.0f;

  for (int sweep = 0; sweep < 8; ++sweep) {
#pragma unroll
    for (int p = 0; p < 7; ++p) {
#pragma unroll
      for (int q = p + 1; q < 8; ++q) {
        const float apq = Gm[p][q];
        const float app = Gm[p][p], aqq = Gm[q][q];
        float t;
        if (apq != 0.0f) {
          const float tau = (aqq - app) / (2.0f * apq);
          const float r = sqrtf(fmaf(tau, tau, 1.0f));
          t = copysignf(1.0f, tau) / (fabsf(tau) + r);
        } else {
          t = 0.0f;
        }
        const float c = 1.0f / sqrtf(fmaf(t, t, 1.0f));
        const float s = t * c;
#pragma unroll
        for (int r2 = 0; r2 < 8; ++r2) {
          const float gp = Gm[p][r2], gq = Gm[q][r2];
          Gm[p][r2] = fmaf(c, gp, -s * gq);
          Gm[q][r2] = fmaf(s, gp,  c * gq);
        }
#pragma unroll
        for (int r2 = 0; r2 < 8; ++r2) {
          const float gp = Gm[r2][p], gq = Gm[r2][q];
          Gm[r2][p] = fmaf(c, gp, -s * gq);
          Gm[r2][q] = fmaf(s, gp,  c * gq);
        }
#pragma unroll
        for (int r2 = 0; r2 < 8; ++r2) {
          const float vp = V[r2][p], vq = V[r2][q];
          V[r2][p] = fmaf(c, vp, -s * vq);
          V[r2][q] = fmaf(s, vp,  c * vq);
        }
      }
    }
  }
#pragma unroll
  for (int e = 0; e < 64; ++e) Vws[cell * 64 + e] = V[e >> 3][e & 7];
#pragma unroll
  for (int m = 0; m < 8; ++m) lamws[cell * 8 + m] = Gm[m][m];
}

// ---------------- covet (bf16) -> Abf cols 2000..3023, 4 cells per block ----------------
__global__ __launch_bounds__(256) void recon_kernel(const float* __restrict__ gcent,
                                                    const int* __restrict__ nidx,
                                                    const float* __restrict__ Vws,
                                                    const float* __restrict__ lamws,
                                                    ushort_t* __restrict__ Abf) {
  const int wv = threadIdx.x >> 6, lane = threadIdx.x & 63;
  const int cell = blockIdx.x * 4 + wv;
  __shared__ float A[4][8][33];
  __shared__ float Ws[4][8][33];
  __shared__ float Vs[4][64];
  __shared__ float lamS[4][8];
#pragma unroll
  for (int q = 0; q < 4; ++q) {
    const int e = lane + (q << 6);
    const int n = e >> 5, g = e & 31;
    const int src = nidx[cell * 8 + n];
    A[wv][n][g] = gcent[src * G_GENES + g];
  }
  Vs[wv][lane] = Vws[cell * 64 + lane];
  if (lane < 8) lamS[wv][lane] = lamws[cell * 8 + lane];
  __syncthreads();

  float maxl = 0.f;
#pragma unroll
  for (int m = 0; m < 8; ++m) maxl = fmaxf(maxl, lamS[wv][m]);
  const float thr = maxl * 1e-8f;

#pragma unroll
  for (int q = 0; q < 4; ++q) {
    const int e = lane + (q << 6);
    const int m = e >> 5, g = e & 31;
    float acc = 0.f;
#pragma unroll
    for (int i = 0; i < 8; ++i) acc = fmaf(Vs[wv][i * 8 + m], A[wv][i][g], acc);
    const float l = lamS[wv][m];
    const float scm = (l > thr) ? sqrtf(1.0f / sqrtf(l)) : 0.0f;
    Ws[wv][m][g] = acc * scm;
  }
  __syncthreads();
  ushort_t* dst = Abf + (size_t)cell * K_PAD + IN_DIM;
#pragma unroll
  for (int r = 0; r < 16; ++r) {
    const int o = (r << 6) + lane;
    const int g = o >> 5, hh = o & 31;
    float acc = 0.f;
#pragma unroll
    for (int m = 0; m < 8; ++m) acc = fmaf(Ws[wv][m][g], Ws[wv][m][hh], acc);
    dst[o] = f2bf(acc);
  }
}

// ---------------- pack W1^T -> swizzled bf16 tiles [4 cb][95 t][256n x 32k] ----------------
// chunk ch = n*4 + cpos holds data k-chunk (cpos ^ ((n>>1)&3)); glds reads linear.
__global__ __launch_bounds__(256) void packb_kernel(const float* __restrict__ W1,
                                                    ushort_t* __restrict__ Bh) {
  const int cb = blockIdx.x;   // 0..3 column block (256 cols)
  const int t  = blockIdx.y;   // 0..94 k-step
  const int tid = threadIdx.x;
  __shared__ float L[32][260];
  const int k0 = t * 32, n0 = cb * 256;
  {
    const int kl = tid >> 3;
    const int nw = tid & 7;
#pragma unroll
    for (int u = 0; u < 8; ++u) {
      const int nl = (nw + u * 8) * 4;
      float4 v = make_float4(0.f, 0.f, 0.f, 0.f);
      if (k0 + kl < K_TOT) v = *(const float4*)(W1 + (size_t)(k0 + kl) * HID + n0 + nl);
      L[kl][nl + 0] = v.x; L[kl][nl + 1] = v.y; L[kl][nl + 2] = v.z; L[kl][nl + 3] = v.w;
    }
  }
  __syncthreads();
  const size_t tileBase = ((size_t)cb * NT + t) * 8192;
  const int n = tid;                       // chunk row = tid (0..255)
#pragma unroll
  for (int q = 0; q < 4; ++q) {            // cpos
    const int cdata = q ^ ((n >> 1) & 3);
    ushort_t hi[8];
#pragma unroll
    for (int e = 0; e < 8; ++e) {
      const int kl = cdata * 8 + e;
      const float v = (k0 + kl < K_TOT) ? L[kl][n] : 0.f;
      hi[e] = f2bf(v);
    }
    *(bf16x8*)(Bh + tileBase + ((size_t)n * 4 + q) * 8) = *(const bf16x8*)hi;
  }
}

// ---------------- GEMM1: h = relu(Abf @ W1 + b1), pure-glds pipeline ----------------
// 128x256 tile, 8 waves of 64x64, BK=32. A,B both bf16 via global_load_lds,
// 3 buffers each, tiles prefetched 2 ahead, vmcnt(3) + raw s_barrier per iter.
__global__ __launch_bounds__(512, 4) void gemm1_kernel(const ushort_t* __restrict__ Abf,
                                                       const ushort_t* __restrict__ Bh,
                                                       const float* __restrict__ b1,
                                                       ushort_t* __restrict__ h) {
  __shared__ ushort_t As[3][4096];    // [128 rows][32 k], chunk-swizzled, 24 KB
  __shared__ ushort_t Bs[3][8192];    // [256 rows][32 k], chunk-swizzled, 48 KB

  const int tid = threadIdx.x;
  const int id  = blockIdx.x;
  const int swz = (id & 7) * 64 + (id >> 3);   // XCD-bijective (512 % 8 == 0)
  const int cb  = swz >> 7, rb = swz & 127;
  const int row0 = rb << 7, col0 = cb << 8;

  const int lane = tid & 63, wv = tid >> 6;
  const int m_base = (wv >> 2) << 6, n_base = (wv & 3) << 6;
  const int l15 = lane & 15, l4 = lane >> 4;

  // per-thread glds source pointers (advance per tile)
  const int arow = tid >> 2, acpos = tid & 3;
  const int acdata = acpos ^ ((arow >> 1) & 3);
  const ushort_t* aptr = Abf + (size_t)(row0 + arow) * K_PAD + acdata * 8;
  const ushort_t* bptr = Bh + (size_t)cb * NT * 8192 + tid * 8;

  // fragment LDS offsets (ushort units)
  int aoff[4], boff[4];
#pragma unroll
  for (int i = 0; i < 4; ++i) {
    const int r = m_base + i * 16 + l15;
    aoff[i] = r * 32 + (l4 ^ ((r >> 1) & 3)) * 8;
  }
#pragma unroll
  for (int j = 0; j < 4; ++j) {
    const int r = n_base + j * 16 + l15;
    boff[j] = r * 32 + (l4 ^ ((r >> 1) & 3)) * 8;
  }

  f32x4 acc[4][4];
#pragma unroll
  for (int i = 0; i < 4; ++i)
#pragma unroll
    for (int j = 0; j < 4; ++j) acc[i][j] = (f32x4){0.f, 0.f, 0.f, 0.f};

  auto prefetch = [&](int buf) {
    glds16(aptr,        &As[buf][tid * 8]);
    glds16(bptr,        &Bs[buf][tid * 8]);
    glds16(bptr + 4096, &Bs[buf][tid * 8 + 4096]);
    aptr += 32;        // next k-tile (64 B)
    bptr += 8192;      // next B tile
  };
  auto compute = [&](int buf) {
    bf16x8 ah[4], bh[4];
#pragma unroll
    for (int i = 0; i < 4; ++i) ah[i] = *(const bf16x8*)(&As[buf][aoff[i]]);
#pragma unroll
    for (int j = 0; j < 4; ++j) bh[j] = *(const bf16x8*)(&Bs[buf][boff[j]]);
#pragma unroll
    for (int i = 0; i < 4; ++i)
#pragma unroll
      for (int j = 0; j < 4; ++j)
        acc[i][j] = __builtin_amdgcn_mfma_f32_16x16x32_bf16(ah[i], bh[j], acc[i][j], 0, 0, 0);
  };

  // prologue: tiles 0 -> buf0, 1 -> buf1
  prefetch(0);
  prefetch(1);
  asm volatile("s_waitcnt vmcnt(3)" ::: "memory");   // tile 0 landed
  __builtin_amdgcn_s_barrier();
  __builtin_amdgcn_sched_barrier(0);

  // 93 steps: compute tile t from buf t%3, prefetch tile t+2 into buf (t+2)%3
#define STEP(BUFC, BUFP) { prefetch(BUFP); compute(BUFC); \
    asm volatile("s_waitcnt vmcnt(3)" ::: "memory"); \
    __builtin_amdgcn_s_barrier(); \
    __builtin_amdgcn_sched_barrier(0); }
  for (int tt = 0; tt < 31; ++tt) {
    STEP(0, 2)
    STEP(1, 0)
    STEP(2, 1)
  }
#undef STEP
  // t = 93 (buf0): no prefetch; then full drain so tile 94 (buf1) is landed
  compute(0);
  asm volatile("s_waitcnt vmcnt(0)" ::: "memory");
  __builtin_amdgcn_s_barrier();
  __builtin_amdgcn_sched_barrier(0);
  // t = 94 (buf1)
  compute(1);

  float bb[4];
#pragma unroll
  for (int j = 0; j < 4; ++j) bb[j] = b1[col0 + n_base + j * 16 + l15];
#pragma unroll
  for (int i = 0; i < 4; ++i) {
    const int rbase = row0 + m_base + i * 16 + l4 * 4;
#pragma unroll
    for (int j = 0; j < 4; ++j) {
      const int c = col0 + n_base + j * 16 + l15;
#pragma unroll
      for (int q = 0; q < 4; ++q) {
        const float v = fmaxf(acc[i][j][q] + bb[j], 0.f);
        h[(size_t)(rbase + q) * HID + c] = f2bf(v);
      }
    }
  }
}

// ---------------- pack W2 -> W2t bf16 [32][1024] (pad 30->32) ----------------
__global__ __launch_bounds__(256) void packw2_kernel(const float* __restrict__ W2,
                                                     ushort_t* __restrict__ W2t) {
  const int k = blockIdx.x * 256 + threadIdx.x;
#pragma unroll
  for (int o = 0; o < 32; ++o) {
    const float v = (o < OUT_DIM) ? W2[k * OUT_DIM + o] : 0.f;
    W2t[o * HID + k] = f2bf(v);
  }
}

// ---------------- GEMM2: out = h @ W2 + b2 via bf16 MFMA ----------------
__global__ __launch_bounds__(256) void gemm2_kernel(const ushort_t* __restrict__ h,
                                                    const ushort_t* __restrict__ W2t,
                                                    const float* __restrict__ b2,
                                                    float* __restrict__ out) {
  const int tid = threadIdx.x;
  const int lane = tid & 63, wv = tid >> 6;
  const int rowt = wv & 1, colt = wv >> 1;
  const int l15 = lane & 15, l4 = lane >> 4;
  const int row0 = blockIdx.x * 32 + rowt * 16;
  const int col  = colt * 16 + l15;

  f32x4 acc = (f32x4){0.f, 0.f, 0.f, 0.f};
  const ushort_t* ha = h + (size_t)(row0 + l15) * HID + l4 * 8;
  const ushort_t* wb = W2t + (size_t)col * HID + l4 * 8;
#pragma unroll 8
  for (int k0 = 0; k0 < HID; k0 += 32) {
    const bf16x8 av = *(const bf16x8*)(ha + k0);
    const bf16x8 bv = *(const bf16x8*)(wb + k0);
    acc = __builtin_amdgcn_mfma_f32_16x16x32_bf16(av, bv, acc, 0, 0, 0);
  }
  if (col < OUT_DIM) {
    const float bias = b2[col];
#pragma unroll
    for (int q = 0; q < 4; ++q) {
      const int r = row0 + l4 * 4 + q;
      out[(size_t)r * OUT_DIM + col] = acc[q] + bias;
    }
  }
}

extern "C" void kernel_launch(void* const* d_in, const int* in_sizes, int n_in,
                              void* d_out, int out_size, void* d_ws, size_t ws_size,
                              hipStream_t stream) {
  (void)in_sizes; (void)n_in; (void)out_size;
  const float* x      = (const float*)d_in[0];
  const float* coords = (const float*)d_in[1];
  const float* genes  = (const float*)d_in[2];
  const float* W1     = (const float*)d_in[3];
  const float* b1     = (const float*)d_in[4];
  const float* W2     = (const float*)d_in[5];
  const float* b2     = (const float*)d_in[6];
  float* out = (float*)d_out;

  char* ws = (char*)d_ws;
  size_t off = 0;
  auto alloc = [&](size_t bytes) -> void* {
    void* p = ws + off;
    off = (off + bytes + 255) & ~(size_t)255;
    return p;
  };
  ushort_t* Abf    = (ushort_t*)alloc((size_t)N_CELLS * K_PAD * 2);   // 99.6 MB
  ushort_t* hbf    = (ushort_t*)alloc((size_t)N_CELLS * HID * 2);     // 33.5 MB
  ushort_t* Bh     = (ushort_t*)alloc((size_t)4 * NT * 8192 * 2);     // 6.2 MB
  ushort_t* W2t    = (ushort_t*)alloc((size_t)32 * HID * 2);          // 64 KB
  float*    gcent  = (float*)alloc((size_t)N_CELLS * G_GENES * 4);
  float*    Gws    = (float*)alloc((size_t)N_CELLS * 64 * 4);
  float*    Vws    = (float*)alloc((size_t)N_CELLS * 64 * 4);
  float*    lamws  = (float*)alloc((size_t)N_CELLS * 8 * 4);
  int*      nidx   = (int*)alloc((size_t)N_CELLS * 8 * 4);
  double*   part   = (double*)alloc((size_t)128 * 32 * 8);
  float*    meanv  = (float*)alloc(G_GENES * 4);
  int*      binCnt = (int*)alloc((size_t)NBINS * 4);
  int*      binSt  = (int*)alloc((size_t)(NBINS + 1) * 4);
  int*      cursor = (int*)alloc((size_t)NBINS * 4);
  int*      binOf  = (int*)alloc((size_t)N_CELLS * 4);
  int*      binPts = (int*)alloc((size_t)N_CELLS * 4);
  if (off > ws_size) return;

  hipMemsetAsync(binCnt, 0, (size_t)NBINS * 4, stream);

  hipLaunchKernelGGL(packb_kernel, dim3(4, NT),   dim3(256), 0, stream, W1, Bh);
  hipLaunchKernelGGL(packw2_kernel,dim3(4),       dim3(256), 0, stream, W2, W2t);
  hipLaunchKernelGGL(convx_kernel, dim3(N_CELLS), dim3(256), 0, stream, x, Abf);
  hipLaunchKernelGGL(mean_part,    dim3(128),     dim3(256), 0, stream, genes, part);
  hipLaunchKernelGGL(mean_fin,     dim3(1),       dim3(64),  0, stream, part, meanv);
  hipLaunchKernelGGL(center_kernel,dim3(2048),    dim3(256), 0, stream, genes, meanv, gcent);
  hipLaunchKernelGGL(bin_count,    dim3(64),      dim3(256), 0, stream, coords, binCnt, binOf);
  hipLaunchKernelGGL(bin_scan,     dim3(1),       dim3(256), 0, stream, binCnt, binSt, cursor);
  hipLaunchKernelGGL(bin_scatter,  dim3(64),      dim3(256), 0, stream, binOf, cursor, binPts);
  hipLaunchKernelGGL(knn_search,   dim3(64),      dim3(256), 0, stream, coords, binSt, binPts, nidx);
  hipLaunchKernelGGL(gram_kernel,  dim3(4096),    dim3(256), 0, stream, gcent, nidx, Gws);
  hipLaunchKernelGGL(jacobi_kernel,dim3(64),      dim3(256), 0, stream, Gws, Vws, lamws);
  hipLaunchKernelGGL(recon_kernel, dim3(4096),    dim3(256), 0, stream, gcent, nidx, Vws, lamws, Abf);
  hipLaunchKernelGGL(gemm1_kernel, dim3(512),     dim3(512), 0, stream, Abf, Bh, b1, hbf);
  hipLaunchKernelGGL(gemm2_kernel, dim3(512),     dim3(256), 0, stream, hbf, W2t, b2, out);
}

// Round 7
// 328.031 us; speedup vs baseline: 6.1003x; 1.1166x over previous
//
#include <hip/hip_runtime.h>
#include <hip/hip_bf16.h>
#include <math.h>

#define N_CELLS 16384
#define G_GENES 32
#define IN_DIM  2000
#define HID     1024
#define OUT_DIM 30
#define K_TOT   3024      // IN_DIM + 1024
#define K_PAD   3040      // 95 * 32
#define NT      95
#define GRID_B  128
#define NBINS   (GRID_B * GRID_B)
#define SCELL   (100.0f / (float)GRID_B)
#define CSCALE  0.37796447300922722721f   // 1/sqrt(7)

typedef unsigned short ushort_t;
typedef __attribute__((ext_vector_type(8))) short bf16x8;
typedef __attribute__((ext_vector_type(4))) short bf16x4;
typedef __attribute__((ext_vector_type(4))) float f32x4;

__device__ __forceinline__ ushort_t f2bf(float v) {
  return __builtin_bit_cast(ushort_t, __float2bfloat16(v));
}

// global_load_lds: 16B per lane, LDS dest = wave-uniform base + lane*16
__device__ __forceinline__ void glds16(const void* g, void* l) {
  __builtin_amdgcn_global_load_lds(
      (const __attribute__((address_space(1))) unsigned int*)g,
      (__attribute__((address_space(3))) unsigned int*)l, 16, 0, 0);
}

// ---------------- mean (two-stage, deterministic f64) ----------------
__global__ __launch_bounds__(256) void mean_part(const float* __restrict__ genes,
                                                 double* __restrict__ part) {
  const int b = blockIdx.x;
  const int tid = threadIdx.x;
  const int g = tid & 31, cs = tid >> 5;
  double acc = 0.0;
#pragma unroll
  for (int it = 0; it < 16; ++it) {
    const int cell = b * 128 + cs + it * 8;
    acc += (double)genes[cell * G_GENES + g];
  }
  __shared__ double red[256];
  red[tid] = acc;
  __syncthreads();
  if (tid < 32) {
    double s = red[tid];
#pragma unroll
    for (int u = 1; u < 8; ++u) s += red[tid + u * 32];
    part[b * 32 + tid] = s;
  }
}

__global__ __launch_bounds__(64) void mean_fin(const double* __restrict__ part,
                                               float* __restrict__ meanv) {
  const int g = threadIdx.x;
  if (g >= 32) return;
  double s = 0.0;
  for (int b = 0; b < 128; ++b) s += part[b * 32 + g];
  meanv[g] = (float)(s / (double)N_CELLS);
}

// ---------------- convert x -> Abf (bf16), lane-contiguous phases ----------------
__global__ __launch_bounds__(256) void convx_kernel(const float* __restrict__ x,
                                                    ushort_t* __restrict__ Abf) {
  const int row = blockIdx.x;
  const int t = threadIdx.x;
  if (t < 250) {
#pragma unroll
    for (int ph = 0; ph < 2; ++ph) {
      const int col = ph * 1000 + t * 4;            // 16B-coalesced loads, 8B stores
      const float4 v = *(const float4*)(x + (size_t)row * IN_DIM + col);
      ushort_t o[4] = { f2bf(v.x), f2bf(v.y), f2bf(v.z), f2bf(v.w) };
      *(bf16x4*)(Abf + (size_t)row * K_PAD + col) = *(const bf16x4*)o;
    }
  } else if (t < 252) {
    const bf16x8 z = (bf16x8){0, 0, 0, 0, 0, 0, 0, 0};
    *(bf16x8*)(Abf + (size_t)row * K_PAD + K_TOT + (t - 250) * 8) = z;
  }
}

// ---------------- grid-binned exact kNN ----------------
__global__ __launch_bounds__(256) void bin_count(const float* __restrict__ coords,
                                                 int* __restrict__ cnt,
                                                 int* __restrict__ binOf) {
  const int i = blockIdx.x * 256 + threadIdx.x;
  const float2 p = ((const float2*)coords)[i];
  const float inv_s = (float)GRID_B / 100.0f;
  const int bx = min(GRID_B - 1, max(0, (int)(p.x * inv_s)));
  const int by = min(GRID_B - 1, max(0, (int)(p.y * inv_s)));
  const int b = by * GRID_B + bx;
  binOf[i] = b;
  atomicAdd(&cnt[b], 1);
}

__global__ __launch_bounds__(256) void bin_scan(const int* __restrict__ cnt,
                                                int* __restrict__ binStart,
                                                int* __restrict__ cursor) {
  __shared__ int ps[256];
  const int tid = threadIdx.x;
  int s = 0;
  for (int i = 0; i < 64; ++i) s += cnt[tid * 64 + i];
  ps[tid] = s;
  __syncthreads();
  for (int off = 1; off < 256; off <<= 1) {
    const int add = (tid >= off) ? ps[tid - off] : 0;
    __syncthreads();
    ps[tid] += add;
    __syncthreads();
  }
  int run = ps[tid] - s;
  for (int i = 0; i < 64; ++i) {
    const int b = tid * 64 + i;
    binStart[b] = run;
    cursor[b] = run;
    run += cnt[b];
  }
  if (tid == 255) binStart[NBINS] = run;
}

__global__ __launch_bounds__(256) void bin_scatter(const int* __restrict__ binOf,
                                                   int* __restrict__ cursor,
                                                   int* __restrict__ binPts) {
  const int i = blockIdx.x * 256 + threadIdx.x;
  const int pos = atomicAdd(&cursor[binOf[i]], 1);
  binPts[pos] = i;
}

// one cell per thread; 256 blocks x 64 threads -> every CU active
__global__ __launch_bounds__(64) void knn_search(const float* __restrict__ coords,
                                                 const int* __restrict__ binStart,
                                                 const int* __restrict__ binPts,
                                                 int* __restrict__ nidx) {
  const int cell = blockIdx.x * 64 + threadIdx.x;
  const float qx = coords[cell * 2 + 0], qy = coords[cell * 2 + 1];
  const float sqi = __fadd_rn(__fmul_rn(qx, qx), __fmul_rn(qy, qy));
  const float inv_s = (float)GRID_B / 100.0f;
  const int bx = min(GRID_B - 1, max(0, (int)(qx * inv_s)));
  const int by = min(GRID_B - 1, max(0, (int)(qy * inv_s)));

  unsigned long long kk[8];
#pragma unroll
  for (int i = 0; i < 8; ++i) kk[i] = ~0ull;

  auto scan_bin = [&](int bxx, int byy) {
    if (bxx < 0 || bxx >= GRID_B || byy < 0 || byy >= GRID_B) return;
    const int b = byy * GRID_B + bxx;
    const int s = binStart[b], e = binStart[b + 1];
    for (int p = s; p < e; ++p) {
      const int j = binPts[p];
      const float2 pc = ((const float2*)coords)[j];
      const float sqj = __fadd_rn(__fmul_rn(pc.x, pc.x), __fmul_rn(pc.y, pc.y));
      const float dot = __fmaf_rn(qy, pc.y, __fmul_rn(qx, pc.x));
      const float d2  = __fsub_rn(__fadd_rn(sqi, sqj), __fmul_rn(2.0f, dot));
      unsigned int sb = __float_as_uint(d2);
      sb = (sb & 0x80000000u) ? ~sb : (sb | 0x80000000u);
      unsigned long long key = ((unsigned long long)sb << 32) | (unsigned int)j;
      if (key < kk[7]) {
#pragma unroll
        for (int q2 = 0; q2 < 8; ++q2) {
          const bool lt = key < kk[q2];
          const unsigned long long tmp = kk[q2];
          kk[q2] = lt ? key : kk[q2];
          key = lt ? tmp : key;
        }
      }
    }
  };

  bool done = false;
  for (int r = 0; r < GRID_B; ++r) {
    if (!done) {
      if (r == 0) {
        scan_bin(bx, by);
      } else {
        for (int dx = -r; dx <= r; ++dx) { scan_bin(bx + dx, by - r); scan_bin(bx + dx, by + r); }
        for (int dy = -r + 1; dy <= r - 1; ++dy) { scan_bin(bx - r, by + dy); scan_bin(bx + r, by + dy); }
      }
      if (kk[7] != ~0ull) {
        const unsigned int sb = (unsigned int)(kk[7] >> 32);
        const float wd2 = __uint_as_float((sb & 0x80000000u) ? (sb ^ 0x80000000u) : ~sb);
        const float bnd = (float)r * SCELL;
        if (wd2 < bnd * bnd * 0.998f - 0.05f) done = true;
      }
    }
    if (!__any(!done)) break;
  }
#pragma unroll
  for (int i = 0; i < 8; ++i) nidx[cell * 8 + i] = (int)(kk[i] & 0xFFFFFFFFu);
}

// ---------------- Gram: centering fused (bit-identical expression) ----------------
__global__ __launch_bounds__(256) void gram_kernel(const float* __restrict__ genes,
                                                   const float* __restrict__ meanv,
                                                   const int* __restrict__ nidx,
                                                   float* __restrict__ Gws) {
  const int wv = threadIdx.x >> 6, lane = threadIdx.x & 63;
  const int cell = blockIdx.x * 4 + wv;
  __shared__ float A[4][8][33];
#pragma unroll
  for (int q = 0; q < 4; ++q) {
    const int e = lane + (q << 6);
    const int n = e >> 5, g = e & 31;
    const int src = nidx[cell * 8 + n];
    A[wv][n][g] = (genes[src * G_GENES + g] - meanv[g]) * CSCALE;
  }
  __syncthreads();
  const int i = lane >> 3, j = lane & 7;
  float acc = 0.f;
#pragma unroll
  for (int g = 0; g < 32; ++g) acc = fmaf(A[wv][i][g], A[wv][j][g], acc);
  Gws[cell * 64 + lane] = acc;
}

// ---------------- 8x8 Jacobi: one cell per lane; 256 blocks x 64 ----------------
__global__ __launch_bounds__(64) void jacobi_kernel(const float* __restrict__ Gws,
                                                    float* __restrict__ Vws,
                                                    float* __restrict__ lamws) {
  const int cell = blockIdx.x * 64 + threadIdx.x;
  float Gm[8][8], V[8][8];
#pragma unroll
  for (int e = 0; e < 64; ++e) Gm[e >> 3][e & 7] = Gws[cell * 64 + e];
#pragma unroll
  for (int i = 0; i < 8; ++i)
#pragma unroll
    for (int j = 0; j < 8; ++j) V[i][j] = (i == j) ? 1.0f : 0.0f;

  for (int sweep = 0; sweep < 6; ++sweep) {   // 6 sweeps: quadratic conv, machine-prec for 8x8
#pragma unroll
    for (int p = 0; p < 7; ++p) {
#pragma unroll
      for (int q = p + 1; q < 8; ++q) {
        const float apq = Gm[p][q];
        const float app = Gm[p][p], aqq = Gm[q][q];
        float t;
        if (apq != 0.0f) {
          const float tau = (aqq - app) / (2.0f * apq);
          const float r = sqrtf(fmaf(tau, tau, 1.0f));
          t = copysignf(1.0f, tau) / (fabsf(tau) + r);
        } else {
          t = 0.0f;
        }
        const float c = 1.0f / sqrtf(fmaf(t, t, 1.0f));
        const float s = t * c;
#pragma unroll
        for (int r2 = 0; r2 < 8; ++r2) {
          const float gp = Gm[p][r2], gq = Gm[q][r2];
          Gm[p][r2] = fmaf(c, gp, -s * gq);
          Gm[q][r2] = fmaf(s, gp,  c * gq);
        }
#pragma unroll
        for (int r2 = 0; r2 < 8; ++r2) {
          const float gp = Gm[r2][p], gq = Gm[r2][q];
          Gm[r2][p] = fmaf(c, gp, -s * gq);
          Gm[r2][q] = fmaf(s, gp,  c * gq);
        }
#pragma unroll
        for (int r2 = 0; r2 < 8; ++r2) {
          const float vp = V[r2][p], vq = V[r2][q];
          V[r2][p] = fmaf(c, vp, -s * vq);
          V[r2][q] = fmaf(s, vp,  c * vq);
        }
      }
    }
  }
#pragma unroll
  for (int e = 0; e < 64; ++e) Vws[cell * 64 + e] = V[e >> 3][e & 7];
#pragma unroll
  for (int m = 0; m < 8; ++m) lamws[cell * 8 + m] = Gm[m][m];
}

// ---------------- covet (bf16) -> Abf cols 2000..3023; centering fused ----------------
__global__ __launch_bounds__(256) void recon_kernel(const float* __restrict__ genes,
                                                    const float* __restrict__ meanv,
                                                    const int* __restrict__ nidx,
                                                    const float* __restrict__ Vws,
                                                    const float* __restrict__ lamws,
                                                    ushort_t* __restrict__ Abf) {
  const int wv = threadIdx.x >> 6, lane = threadIdx.x & 63;
  const int cell = blockIdx.x * 4 + wv;
  __shared__ float A[4][8][33];
  __shared__ float Ws[4][8][33];
  __shared__ float Vs[4][64];
  __shared__ float lamS[4][8];
#pragma unroll
  for (int q = 0; q < 4; ++q) {
    const int e = lane + (q << 6);
    const int n = e >> 5, g = e & 31;
    const int src = nidx[cell * 8 + n];
    A[wv][n][g] = (genes[src * G_GENES + g] - meanv[g]) * CSCALE;
  }
  Vs[wv][lane] = Vws[cell * 64 + lane];
  if (lane < 8) lamS[wv][lane] = lamws[cell * 8 + lane];
  __syncthreads();

  float maxl = 0.f;
#pragma unroll
  for (int m = 0; m < 8; ++m) maxl = fmaxf(maxl, lamS[wv][m]);
  const float thr = maxl * 1e-8f;

#pragma unroll
  for (int q = 0; q < 4; ++q) {
    const int e = lane + (q << 6);
    const int m = e >> 5, g = e & 31;
    float acc = 0.f;
#pragma unroll
    for (int i = 0; i < 8; ++i) acc = fmaf(Vs[wv][i * 8 + m], A[wv][i][g], acc);
    const float l = lamS[wv][m];
    const float scm = (l > thr) ? sqrtf(1.0f / sqrtf(l)) : 0.0f;
    Ws[wv][m][g] = acc * scm;
  }
  __syncthreads();
  ushort_t* dst = Abf + (size_t)cell * K_PAD + IN_DIM;
#pragma unroll
  for (int r = 0; r < 16; ++r) {
    const int o = (r << 6) + lane;
    const int g = o >> 5, hh = o & 31;
    float acc = 0.f;
#pragma unroll
    for (int m = 0; m < 8; ++m) acc = fmaf(Ws[wv][m][g], Ws[wv][m][hh], acc);
    dst[o] = f2bf(acc);
  }
}

// ---------------- pack W1^T -> swizzled bf16 tiles [4 cb][95 t][256n x 32k] ----------------
__global__ __launch_bounds__(256) void packb_kernel(const float* __restrict__ W1,
                                                    ushort_t* __restrict__ Bh) {
  const int cb = blockIdx.x;   // 0..3 column block (256 cols)
  const int t  = blockIdx.y;   // 0..94 k-step
  const int tid = threadIdx.x;
  __shared__ float L[32][260];
  const int k0 = t * 32, n0 = cb * 256;
  {
    const int kl = tid >> 3;
    const int nw = tid & 7;
#pragma unroll
    for (int u = 0; u < 8; ++u) {
      const int nl = (nw + u * 8) * 4;
      float4 v = make_float4(0.f, 0.f, 0.f, 0.f);
      if (k0 + kl < K_TOT) v = *(const float4*)(W1 + (size_t)(k0 + kl) * HID + n0 + nl);
      L[kl][nl + 0] = v.x; L[kl][nl + 1] = v.y; L[kl][nl + 2] = v.z; L[kl][nl + 3] = v.w;
    }
  }
  __syncthreads();
  const size_t tileBase = ((size_t)cb * NT + t) * 8192;
  const int n = tid;
#pragma unroll
  for (int q = 0; q < 4; ++q) {
    const int cdata = q ^ ((n >> 1) & 3);
    ushort_t hi[8];
#pragma unroll
    for (int e = 0; e < 8; ++e) {
      const int kl = cdata * 8 + e;
      const float v = (k0 + kl < K_TOT) ? L[kl][n] : 0.f;
      hi[e] = f2bf(v);
    }
    *(bf16x8*)(Bh + tileBase + ((size_t)n * 4 + q) * 8) = *(const bf16x8*)hi;
  }
}

// ---------------- GEMM1: h = relu(Abf @ W1 + b1), pure-glds pipeline ----------------
// 128x256 tile, 8 waves of 64x64, BK=32, 3 buffers, vmcnt(3)+raw barrier per iter.
// Grid: rb-major per XCD -> each A row-panel lives in exactly one XCD L2.
__global__ __launch_bounds__(512, 4) void gemm1_kernel(const ushort_t* __restrict__ Abf,
                                                       const ushort_t* __restrict__ Bh,
                                                       const float* __restrict__ b1,
                                                       ushort_t* __restrict__ h) {
  __shared__ ushort_t As[3][4096];
  __shared__ ushort_t Bs[3][8192];

  const int tid = threadIdx.x;
  const int id  = blockIdx.x;
  const int xcd = id & 7, local = id >> 3;     // bijective: 8 x 64
  const int rb  = (xcd << 4) + (local & 15);   // 16 contiguous row-panels per XCD
  const int cb  = local >> 4;                  // all 4 col-blocks inside the XCD
  const int row0 = rb << 7, col0 = cb << 8;

  const int lane = tid & 63, wv = tid >> 6;
  const int m_base = (wv >> 2) << 6, n_base = (wv & 3) << 6;
  const int l15 = lane & 15, l4 = lane >> 4;

  const int arow = tid >> 2, acpos = tid & 3;
  const int acdata = acpos ^ ((arow >> 1) & 3);
  const ushort_t* aptr = Abf + (size_t)(row0 + arow) * K_PAD + acdata * 8;
  const ushort_t* bptr = Bh + (size_t)cb * NT * 8192 + tid * 8;

  int aoff[4], boff[4];
#pragma unroll
  for (int i = 0; i < 4; ++i) {
    const int r = m_base + i * 16 + l15;
    aoff[i] = r * 32 + (l4 ^ ((r >> 1) & 3)) * 8;
  }
#pragma unroll
  for (int j = 0; j < 4; ++j) {
    const int r = n_base + j * 16 + l15;
    boff[j] = r * 32 + (l4 ^ ((r >> 1) & 3)) * 8;
  }

  f32x4 acc[4][4];
#pragma unroll
  for (int i = 0; i < 4; ++i)
#pragma unroll
    for (int j = 0; j < 4; ++j) acc[i][j] = (f32x4){0.f, 0.f, 0.f, 0.f};

  auto prefetch = [&](int buf) {
    glds16(aptr,        &As[buf][tid * 8]);
    glds16(bptr,        &Bs[buf][tid * 8]);
    glds16(bptr + 4096, &Bs[buf][tid * 8 + 4096]);
    aptr += 32;
    bptr += 8192;
  };
  auto compute = [&](int buf) {
    bf16x8 ah[4], bh[4];
#pragma unroll
    for (int i = 0; i < 4; ++i) ah[i] = *(const bf16x8*)(&As[buf][aoff[i]]);
#pragma unroll
    for (int j = 0; j < 4; ++j) bh[j] = *(const bf16x8*)(&Bs[buf][boff[j]]);
#pragma unroll
    for (int i = 0; i < 4; ++i)
#pragma unroll
      for (int j = 0; j < 4; ++j)
        acc[i][j] = __builtin_amdgcn_mfma_f32_16x16x32_bf16(ah[i], bh[j], acc[i][j], 0, 0, 0);
  };

  prefetch(0);
  prefetch(1);
  asm volatile("s_waitcnt vmcnt(3)" ::: "memory");
  __builtin_amdgcn_s_barrier();
  __builtin_amdgcn_sched_barrier(0);

#define STEP(BUFC, BUFP) { prefetch(BUFP); compute(BUFC); \
    asm volatile("s_waitcnt vmcnt(3)" ::: "memory"); \
    __builtin_amdgcn_s_barrier(); \
    __builtin_amdgcn_sched_barrier(0); }
  for (int tt = 0; tt < 31; ++tt) {
    STEP(0, 2)
    STEP(1, 0)
    STEP(2, 1)
  }
#undef STEP
  compute(0);
  asm volatile("s_waitcnt vmcnt(0)" ::: "memory");
  __builtin_amdgcn_s_barrier();
  __builtin_amdgcn_sched_barrier(0);
  compute(1);

  float bb[4];
#pragma unroll
  for (int j = 0; j < 4; ++j) bb[j] = b1[col0 + n_base + j * 16 + l15];
#pragma unroll
  for (int i = 0; i < 4; ++i) {
    const int rbase = row0 + m_base + i * 16 + l4 * 4;
#pragma unroll
    for (int j = 0; j < 4; ++j) {
      const int c = col0 + n_base + j * 16 + l15;
#pragma unroll
      for (int q = 0; q < 4; ++q) {
        const float v = fmaxf(acc[i][j][q] + bb[j], 0.f);
        h[(size_t)(rbase + q) * HID + c] = f2bf(v);
      }
    }
  }
}

// ---------------- pack W2 -> W2t bf16 [32][1024] (pad 30->32) ----------------
__global__ __launch_bounds__(256) void packw2_kernel(const float* __restrict__ W2,
                                                     ushort_t* __restrict__ W2t) {
  const int k = blockIdx.x * 256 + threadIdx.x;
#pragma unroll
  for (int o = 0; o < 32; ++o) {
    const float v = (o < OUT_DIM) ? W2[k * OUT_DIM + o] : 0.f;
    W2t[o * HID + k] = f2bf(v);
  }
}

// ---------------- GEMM2: out = h @ W2 + b2 via bf16 MFMA ----------------
__global__ __launch_bounds__(256) void gemm2_kernel(const ushort_t* __restrict__ h,
                                                    const ushort_t* __restrict__ W2t,
                                                    const float* __restrict__ b2,
                                                    float* __restrict__ out) {
  const int tid = threadIdx.x;
  const int lane = tid & 63, wv = tid >> 6;
  const int rowt = wv & 1, colt = wv >> 1;
  const int l15 = lane & 15, l4 = lane >> 4;
  const int row0 = blockIdx.x * 32 + rowt * 16;
  const int col  = colt * 16 + l15;

  f32x4 acc = (f32x4){0.f, 0.f, 0.f, 0.f};
  const ushort_t* ha = h + (size_t)(row0 + l15) * HID + l4 * 8;
  const ushort_t* wb = W2t + (size_t)col * HID + l4 * 8;
#pragma unroll 8
  for (int k0 = 0; k0 < HID; k0 += 32) {
    const bf16x8 av = *(const bf16x8*)(ha + k0);
    const bf16x8 bv = *(const bf16x8*)(wb + k0);
    acc = __builtin_amdgcn_mfma_f32_16x16x32_bf16(av, bv, acc, 0, 0, 0);
  }
  if (col < OUT_DIM) {
    const float bias = b2[col];
#pragma unroll
    for (int q = 0; q < 4; ++q) {
      const int r = row0 + l4 * 4 + q;
      out[(size_t)r * OUT_DIM + col] = acc[q] + bias;
    }
  }
}

extern "C" void kernel_launch(void* const* d_in, const int* in_sizes, int n_in,
                              void* d_out, int out_size, void* d_ws, size_t ws_size,
                              hipStream_t stream) {
  (void)in_sizes; (void)n_in; (void)out_size;
  const float* x      = (const float*)d_in[0];
  const float* coords = (const float*)d_in[1];
  const float* genes  = (const float*)d_in[2];
  const float* W1     = (const float*)d_in[3];
  const float* b1     = (const float*)d_in[4];
  const float* W2     = (const float*)d_in[5];
  const float* b2     = (const float*)d_in[6];
  float* out = (float*)d_out;

  char* ws = (char*)d_ws;
  size_t off = 0;
  auto alloc = [&](size_t bytes) -> void* {
    void* p = ws + off;
    off = (off + bytes + 255) & ~(size_t)255;
    return p;
  };
  ushort_t* Abf    = (ushort_t*)alloc((size_t)N_CELLS * K_PAD * 2);   // 99.6 MB
  ushort_t* hbf    = (ushort_t*)alloc((size_t)N_CELLS * HID * 2);     // 33.5 MB
  ushort_t* Bh     = (ushort_t*)alloc((size_t)4 * NT * 8192 * 2);     // 6.2 MB
  ushort_t* W2t    = (ushort_t*)alloc((size_t)32 * HID * 2);          // 64 KB
  float*    Gws    = (float*)alloc((size_t)N_CELLS * 64 * 4);
  float*    Vws    = (float*)alloc((size_t)N_CELLS * 64 * 4);
  float*    lamws  = (float*)alloc((size_t)N_CELLS * 8 * 4);
  int*      nidx   = (int*)alloc((size_t)N_CELLS * 8 * 4);
  double*   part   = (double*)alloc((size_t)128 * 32 * 8);
  float*    meanv  = (float*)alloc(G_GENES * 4);
  int*      binCnt = (int*)alloc((size_t)NBINS * 4);
  int*      binSt  = (int*)alloc((size_t)(NBINS + 1) * 4);
  int*      cursor = (int*)alloc((size_t)NBINS * 4);
  int*      binOf  = (int*)alloc((size_t)N_CELLS * 4);
  int*      binPts = (int*)alloc((size_t)N_CELLS * 4);
  if (off > ws_size) return;

  hipMemsetAsync(binCnt, 0, (size_t)NBINS * 4, stream);

  hipLaunchKernelGGL(packb_kernel, dim3(4, NT),   dim3(256), 0, stream, W1, Bh);
  hipLaunchKernelGGL(packw2_kernel,dim3(4),       dim3(256), 0, stream, W2, W2t);
  hipLaunchKernelGGL(convx_kernel, dim3(N_CELLS), dim3(256), 0, stream, x, Abf);
  hipLaunchKernelGGL(mean_part,    dim3(128),     dim3(256), 0, stream, genes, part);
  hipLaunchKernelGGL(mean_fin,     dim3(1),       dim3(64),  0, stream, part, meanv);
  hipLaunchKernelGGL(bin_count,    dim3(64),      dim3(256), 0, stream, coords, binCnt, binOf);
  hipLaunchKernelGGL(bin_scan,     dim3(1),       dim3(256), 0, stream, binCnt, binSt, cursor);
  hipLaunchKernelGGL(bin_scatter,  dim3(64),      dim3(256), 0, stream, binOf, cursor, binPts);
  hipLaunchKernelGGL(knn_search,   dim3(256),     dim3(64),  0, stream, coords, binSt, binPts, nidx);
  hipLaunchKernelGGL(gram_kernel,  dim3(4096),    dim3(256), 0, stream, genes, meanv, nidx, Gws);
  hipLaunchKernelGGL(jacobi_kernel,dim3(256),     dim3(64),  0, stream, Gws, Vws, lamws);
  hipLaunchKernelGGL(recon_kernel, dim3(4096),    dim3(256), 0, stream, genes, meanv, nidx, Vws, lamws, Abf);
  hipLaunchKernelGGL(gemm1_kernel, dim3(512),     dim3(512), 0, stream, Abf, Bh, b1, hbf);
  hipLaunchKernelGGL(gemm2_kernel, dim3(512),     dim3(256), 0, stream, hbf, W2t, b2, out);
}

// Round 8
// 293.101 us; speedup vs baseline: 6.8273x; 1.1192x over previous
//
#include <hip/hip_runtime.h>
#include <hip/hip_bf16.h>
#include <math.h>

#define N_CELLS 16384
#define G_GENES 32
#define IN_DIM  2000
#define HID     1024
#define OUT_DIM 30
#define K_TOT   3024      // IN_DIM + 1024
#define K_PAD   3040      // 95 * 32
#define NT      95
#define GRID_B  128
#define NBINS   (GRID_B * GRID_B)
#define SCELL   (100.0f / (float)GRID_B)
#define CSCALE  0.37796447300922722721f   // 1/sqrt(7)

typedef unsigned short ushort_t;
typedef __attribute__((ext_vector_type(8))) short bf16x8;
typedef __attribute__((ext_vector_type(4))) short bf16x4;
typedef __attribute__((ext_vector_type(4))) float f32x4;

__device__ __forceinline__ ushort_t f2bf(float v) {
  return __builtin_bit_cast(ushort_t, __float2bfloat16(v));
}

// global_load_lds: 16B per lane, LDS dest = wave-uniform base + lane*16
__device__ __forceinline__ void glds16(const void* g, void* l) {
  __builtin_amdgcn_global_load_lds(
      (const __attribute__((address_space(1))) unsigned int*)g,
      (__attribute__((address_space(3))) unsigned int*)l, 16, 0, 0);
}

// ============ fused pre-pass: packb | packw2 | convx | mean_part | bin_count ============
// all mutually independent; one launch -> concurrent occupancy.
__global__ __launch_bounds__(256) void fused_pre(const float* __restrict__ x,
                                                 const float* __restrict__ W1,
                                                 const float* __restrict__ W2,
                                                 const float* __restrict__ genes,
                                                 const float* __restrict__ coords,
                                                 ushort_t* __restrict__ Abf,
                                                 ushort_t* __restrict__ Bh,
                                                 ushort_t* __restrict__ W2t,
                                                 double* __restrict__ part,
                                                 int* __restrict__ cnt,
                                                 int* __restrict__ binOf) {
  __shared__ float L[32][260];
  __shared__ double red[256];
  const int bid = blockIdx.x;
  const int tid = threadIdx.x;

  if (bid < 380) {
    // ---- packb: W1^T -> swizzled bf16 tiles [4 cb][95 t][256n x 32k] ----
    const int cb = bid / NT, t = bid % NT;
    const int k0 = t * 32, n0 = cb * 256;
    {
      const int kl = tid >> 3;
      const int nw = tid & 7;
#pragma unroll
      for (int u = 0; u < 8; ++u) {
        const int nl = (nw + u * 8) * 4;
        float4 v = make_float4(0.f, 0.f, 0.f, 0.f);
        if (k0 + kl < K_TOT) v = *(const float4*)(W1 + (size_t)(k0 + kl) * HID + n0 + nl);
        L[kl][nl + 0] = v.x; L[kl][nl + 1] = v.y; L[kl][nl + 2] = v.z; L[kl][nl + 3] = v.w;
      }
    }
    __syncthreads();
    const size_t tileBase = ((size_t)cb * NT + t) * 8192;
    const int n = tid;
#pragma unroll
    for (int q = 0; q < 4; ++q) {
      const int cdata = q ^ ((n >> 1) & 3);
      ushort_t hi[8];
#pragma unroll
      for (int e = 0; e < 8; ++e) {
        const int kl = cdata * 8 + e;
        const float v = (k0 + kl < K_TOT) ? L[kl][n] : 0.f;
        hi[e] = f2bf(v);
      }
      *(bf16x8*)(Bh + tileBase + ((size_t)n * 4 + q) * 8) = *(const bf16x8*)hi;
    }
  } else if (bid < 384) {
    // ---- packw2 ----
    const int k = (bid - 380) * 256 + tid;
#pragma unroll
    for (int o = 0; o < 32; ++o) {
      const float v = (o < OUT_DIM) ? W2[k * OUT_DIM + o] : 0.f;
      W2t[o * HID + k] = f2bf(v);
    }
  } else if (bid < 2432) {
    // ---- convx: 8 rows per block ----
    const int rbase = (bid - 384) * 8;
#pragma unroll
    for (int rr = 0; rr < 8; ++rr) {
      const int row = rbase + rr;
      if (tid < 250) {
#pragma unroll
        for (int ph = 0; ph < 2; ++ph) {
          const int col = ph * 1000 + tid * 4;
          const float4 v = *(const float4*)(x + (size_t)row * IN_DIM + col);
          ushort_t o[4] = { f2bf(v.x), f2bf(v.y), f2bf(v.z), f2bf(v.w) };
          *(bf16x4*)(Abf + (size_t)row * K_PAD + col) = *(const bf16x4*)o;
        }
      } else if (tid < 252) {
        const bf16x8 z = (bf16x8){0, 0, 0, 0, 0, 0, 0, 0};
        *(bf16x8*)(Abf + (size_t)row * K_PAD + K_TOT + (tid - 250) * 8) = z;
      }
    }
  } else if (bid < 2560) {
    // ---- mean_part ----
    const int b = bid - 2432;
    const int g = tid & 31, cs = tid >> 5;
    double acc = 0.0;
#pragma unroll
    for (int it = 0; it < 16; ++it) {
      const int cell = b * 128 + cs + it * 8;
      acc += (double)genes[cell * G_GENES + g];
    }
    red[tid] = acc;
    __syncthreads();
    if (tid < 32) {
      double s = red[tid];
#pragma unroll
      for (int u = 1; u < 8; ++u) s += red[tid + u * 32];
      part[b * 32 + tid] = s;
    }
  } else {
    // ---- bin_count ----
    const int i = (bid - 2560) * 256 + tid;
    const float2 p = ((const float2*)coords)[i];
    const float inv_s = (float)GRID_B / 100.0f;
    const int bx = min(GRID_B - 1, max(0, (int)(p.x * inv_s)));
    const int by = min(GRID_B - 1, max(0, (int)(p.y * inv_s)));
    const int b = by * GRID_B + bx;
    binOf[i] = b;
    atomicAdd(&cnt[b], 1);
  }
}

// ============ block 0: bin prefix-scan | block 1: mean finalize ============
__global__ __launch_bounds__(256) void scan_fin(const int* __restrict__ cnt,
                                                int* __restrict__ binStart,
                                                int* __restrict__ cursor,
                                                const double* __restrict__ part,
                                                float* __restrict__ meanv) {
  const int tid = threadIdx.x;
  if (blockIdx.x == 0) {
    __shared__ int ps[256];
    int s = 0;
    for (int i = 0; i < 64; ++i) s += cnt[tid * 64 + i];
    ps[tid] = s;
    __syncthreads();
    for (int off = 1; off < 256; off <<= 1) {
      const int add = (tid >= off) ? ps[tid - off] : 0;
      __syncthreads();
      ps[tid] += add;
      __syncthreads();
    }
    int run = ps[tid] - s;
    for (int i = 0; i < 64; ++i) {
      const int b = tid * 64 + i;
      binStart[b] = run;
      cursor[b] = run;
      run += cnt[b];
    }
    if (tid == 255) binStart[NBINS] = run;
  } else {
    if (tid < 32) {
      double s = 0.0;
      for (int b = 0; b < 128; ++b) s += part[b * 32 + tid];
      meanv[tid] = (float)(s / (double)N_CELLS);
    }
  }
}

// ---------------- scatter: also build bin-sorted coords stream ----------------
__global__ __launch_bounds__(256) void bin_scatter(const float* __restrict__ coords,
                                                   const int* __restrict__ binOf,
                                                   int* __restrict__ cursor,
                                                   int* __restrict__ binPts,
                                                   float2* __restrict__ sxy) {
  const int i = blockIdx.x * 256 + threadIdx.x;
  const float2 p = ((const float2*)coords)[i];
  const int pos = atomicAdd(&cursor[binOf[i]], 1);
  binPts[pos] = i;
  sxy[pos] = p;
}

// ---------------- kNN: sorted-stream ring scan (row-run segments) ----------------
__global__ __launch_bounds__(128) void knn_search(const float* __restrict__ coords,
                                                  const int* __restrict__ binStart,
                                                  const int* __restrict__ binPts,
                                                  const float2* __restrict__ sxy,
                                                  int* __restrict__ nidx) {
  const int cell = blockIdx.x * 128 + threadIdx.x;
  const float qx = coords[cell * 2 + 0], qy = coords[cell * 2 + 1];
  const float sqi = __fadd_rn(__fmul_rn(qx, qx), __fmul_rn(qy, qy));
  const float inv_s = (float)GRID_B / 100.0f;
  const int bx = min(GRID_B - 1, max(0, (int)(qx * inv_s)));
  const int by = min(GRID_B - 1, max(0, (int)(qy * inv_s)));

  unsigned long long kk[8];
#pragma unroll
  for (int i = 0; i < 8; ++i) kk[i] = ~0ull;

  auto scan_seg = [&](int s, int e) {
    for (int p = s; p < e; ++p) {
      const float2 pc = sxy[p];        // contiguous stream
      const int j = binPts[p];         // contiguous stream (independent)
      const float sqj = __fadd_rn(__fmul_rn(pc.x, pc.x), __fmul_rn(pc.y, pc.y));
      const float dot = __fmaf_rn(qy, pc.y, __fmul_rn(qx, pc.x));
      const float d2  = __fsub_rn(__fadd_rn(sqi, sqj), __fmul_rn(2.0f, dot));
      unsigned int sb = __float_as_uint(d2);
      sb = (sb & 0x80000000u) ? ~sb : (sb | 0x80000000u);
      unsigned long long key = ((unsigned long long)sb << 32) | (unsigned int)j;
      if (key < kk[7]) {
#pragma unroll
        for (int q2 = 0; q2 < 8; ++q2) {
          const bool lt = key < kk[q2];
          const unsigned long long tmp = kk[q2];
          kk[q2] = lt ? key : kk[q2];
          key = lt ? tmp : key;
        }
      }
    }
  };

  bool done = false;
  for (int r = 0; r < GRID_B; ++r) {
    if (!done) {
      if (r == 0) {
        const int b = by * GRID_B + bx;
        scan_seg(binStart[b], binStart[b + 1]);
      } else {
        const int xlo = max(0, bx - r), xhi = min(GRID_B - 1, bx + r);
        if (by - r >= 0) {
          const int b0 = (by - r) * GRID_B;
          scan_seg(binStart[b0 + xlo], binStart[b0 + xhi + 1]);
        }
        if (by + r < GRID_B) {
          const int b0 = (by + r) * GRID_B;
          scan_seg(binStart[b0 + xlo], binStart[b0 + xhi + 1]);
        }
        for (int dy = -r + 1; dy <= r - 1; ++dy) {
          const int yy = by + dy;
          if (yy < 0 || yy >= GRID_B) continue;
          if (bx - r >= 0) { const int b = yy * GRID_B + bx - r; scan_seg(binStart[b], binStart[b + 1]); }
          if (bx + r < GRID_B) { const int b = yy * GRID_B + bx + r; scan_seg(binStart[b], binStart[b + 1]); }
        }
      }
      if (kk[7] != ~0ull) {
        const unsigned int sb = (unsigned int)(kk[7] >> 32);
        const float wd2 = __uint_as_float((sb & 0x80000000u) ? (sb ^ 0x80000000u) : ~sb);
        const float bnd = (float)r * SCELL;
        if (wd2 < bnd * bnd * 0.998f - 0.05f) done = true;
      }
    }
    if (!__any(!done)) break;
  }
#pragma unroll
  for (int i = 0; i < 8; ++i) nidx[cell * 8 + i] = (int)(kk[i] & 0xFFFFFFFFu);
}

// ---------------- Gram -> transposed [64][N_CELLS] layout ----------------
// cell mapping XCD-swizzled so each 64B line of GwsT is written within one XCD.
__global__ __launch_bounds__(256) void gram_kernel(const float* __restrict__ genes,
                                                   const float* __restrict__ meanv,
                                                   const int* __restrict__ nidx,
                                                   float* __restrict__ GwsT) {
  const int wv = threadIdx.x >> 6, lane = threadIdx.x & 63;
  const int bidl = (blockIdx.x & 7) * 512 + (blockIdx.x >> 3);   // bijective 4096
  const int cell = bidl * 4 + wv;
  __shared__ float A[4][8][33];
#pragma unroll
  for (int q = 0; q < 4; ++q) {
    const int e = lane + (q << 6);
    const int n = e >> 5, g = e & 31;
    const int src = nidx[cell * 8 + n];
    A[wv][n][g] = (genes[src * G_GENES + g] - meanv[g]) * CSCALE;
  }
  __syncthreads();
  const int i = lane >> 3, j = lane & 7;
  float acc = 0.f;
#pragma unroll
  for (int g = 0; g < 32; ++g) acc = fmaf(A[wv][i][g], A[wv][j][g], acc);
  GwsT[(size_t)lane * N_CELLS + cell] = acc;
}

// ---------------- 8x8 Jacobi: lane=cell, all I/O coalesced via transposed layout ----------------
__global__ __launch_bounds__(64) void jacobi_kernel(const float* __restrict__ GwsT,
                                                    float* __restrict__ VwsT,
                                                    float* __restrict__ lamT) {
  const int cell = blockIdx.x * 64 + threadIdx.x;
  float Gm[8][8], V[8][8];
#pragma unroll
  for (int e = 0; e < 64; ++e) Gm[e >> 3][e & 7] = GwsT[(size_t)e * N_CELLS + cell];
#pragma unroll
  for (int i = 0; i < 8; ++i)
#pragma unroll
    for (int j = 0; j < 8; ++j) V[i][j] = (i == j) ? 1.0f : 0.0f;

  for (int sweep = 0; sweep < 6; ++sweep) {
#pragma unroll
    for (int p = 0; p < 7; ++p) {
#pragma unroll
      for (int q = p + 1; q < 8; ++q) {
        const float apq = Gm[p][q];
        const float app = Gm[p][p], aqq = Gm[q][q];
        float t;
        if (apq != 0.0f) {
          const float tau = (aqq - app) / (2.0f * apq);
          const float r = sqrtf(fmaf(tau, tau, 1.0f));
          t = copysignf(1.0f, tau) / (fabsf(tau) + r);
        } else {
          t = 0.0f;
        }
        const float c = 1.0f / sqrtf(fmaf(t, t, 1.0f));
        const float s = t * c;
#pragma unroll
        for (int r2 = 0; r2 < 8; ++r2) {
          const float gp = Gm[p][r2], gq = Gm[q][r2];
          Gm[p][r2] = fmaf(c, gp, -s * gq);
          Gm[q][r2] = fmaf(s, gp,  c * gq);
        }
#pragma unroll
        for (int r2 = 0; r2 < 8; ++r2) {
          const float gp = Gm[r2][p], gq = Gm[r2][q];
          Gm[r2][p] = fmaf(c, gp, -s * gq);
          Gm[r2][q] = fmaf(s, gp,  c * gq);
        }
#pragma unroll
        for (int r2 = 0; r2 < 8; ++r2) {
          const float vp = V[r2][p], vq = V[r2][q];
          V[r2][p] = fmaf(c, vp, -s * vq);
          V[r2][q] = fmaf(s, vp,  c * vq);
        }
      }
    }
  }
#pragma unroll
  for (int e = 0; e < 64; ++e) VwsT[(size_t)e * N_CELLS + cell] = V[e >> 3][e & 7];
#pragma unroll
  for (int m = 0; m < 8; ++m) lamT[(size_t)m * N_CELLS + cell] = Gm[m][m];
}

// ---------------- covet (bf16) -> Abf cols 2000..3023 ----------------
__global__ __launch_bounds__(256) void recon_kernel(const float* __restrict__ genes,
                                                    const float* __restrict__ meanv,
                                                    const int* __restrict__ nidx,
                                                    const float* __restrict__ VwsT,
                                                    const float* __restrict__ lamT,
                                                    ushort_t* __restrict__ Abf) {
  const int wv = threadIdx.x >> 6, lane = threadIdx.x & 63;
  const int cell = blockIdx.x * 4 + wv;
  __shared__ float A[4][8][33];
  __shared__ float Ws[4][8][33];
  __shared__ float Vs[4][64];
  __shared__ float lamS[4][8];
#pragma unroll
  for (int q = 0; q < 4; ++q) {
    const int e = lane + (q << 6);
    const int n = e >> 5, g = e & 31;
    const int src = nidx[cell * 8 + n];
    A[wv][n][g] = (genes[src * G_GENES + g] - meanv[g]) * CSCALE;
  }
  Vs[wv][lane] = VwsT[(size_t)lane * N_CELLS + cell];
  if (lane < 8) lamS[wv][lane] = lamT[(size_t)lane * N_CELLS + cell];
  __syncthreads();

  float maxl = 0.f;
#pragma unroll
  for (int m = 0; m < 8; ++m) maxl = fmaxf(maxl, lamS[wv][m]);
  const float thr = maxl * 1e-8f;

#pragma unroll
  for (int q = 0; q < 4; ++q) {
    const int e = lane + (q << 6);
    const int m = e >> 5, g = e & 31;
    float acc = 0.f;
#pragma unroll
    for (int i = 0; i < 8; ++i) acc = fmaf(Vs[wv][i * 8 + m], A[wv][i][g], acc);
    const float l = lamS[wv][m];
    const float scm = (l > thr) ? sqrtf(1.0f / sqrtf(l)) : 0.0f;
    Ws[wv][m][g] = acc * scm;
  }
  __syncthreads();
  ushort_t* dst = Abf + (size_t)cell * K_PAD + IN_DIM;
#pragma unroll
  for (int r = 0; r < 16; ++r) {
    const int o = (r << 6) + lane;
    const int g = o >> 5, hh = o & 31;
    float acc = 0.f;
#pragma unroll
    for (int m = 0; m < 8; ++m) acc = fmaf(Ws[wv][m][g], Ws[wv][m][hh], acc);
    dst[o] = f2bf(acc);
  }
}

// ---------------- GEMM1: h = relu(Abf @ W1 + b1), pure-glds pipeline ----------------
__global__ __launch_bounds__(512, 4) void gemm1_kernel(const ushort_t* __restrict__ Abf,
                                                       const ushort_t* __restrict__ Bh,
                                                       const float* __restrict__ b1,
                                                       ushort_t* __restrict__ h) {
  __shared__ ushort_t As[3][4096];
  __shared__ ushort_t Bs[3][8192];

  const int tid = threadIdx.x;
  const int id  = blockIdx.x;
  const int xcd = id & 7, local = id >> 3;
  const int rb  = (xcd << 4) + (local & 15);
  const int cb  = local >> 4;
  const int row0 = rb << 7, col0 = cb << 8;

  const int lane = tid & 63, wv = tid >> 6;
  const int m_base = (wv >> 2) << 6, n_base = (wv & 3) << 6;
  const int l15 = lane & 15, l4 = lane >> 4;

  const int arow = tid >> 2, acpos = tid & 3;
  const int acdata = acpos ^ ((arow >> 1) & 3);
  const ushort_t* aptr = Abf + (size_t)(row0 + arow) * K_PAD + acdata * 8;
  const ushort_t* bptr = Bh + (size_t)cb * NT * 8192 + tid * 8;

  int aoff[4], boff[4];
#pragma unroll
  for (int i = 0; i < 4; ++i) {
    const int r = m_base + i * 16 + l15;
    aoff[i] = r * 32 + (l4 ^ ((r >> 1) & 3)) * 8;
  }
#pragma unroll
  for (int j = 0; j < 4; ++j) {
    const int r = n_base + j * 16 + l15;
    boff[j] = r * 32 + (l4 ^ ((r >> 1) & 3)) * 8;
  }

  f32x4 acc[4][4];
#pragma unroll
  for (int i = 0; i < 4; ++i)
#pragma unroll
    for (int j = 0; j < 4; ++j) acc[i][j] = (f32x4){0.f, 0.f, 0.f, 0.f};

  auto prefetch = [&](int buf) {
    glds16(aptr,        &As[buf][tid * 8]);
    glds16(bptr,        &Bs[buf][tid * 8]);
    glds16(bptr + 4096, &Bs[buf][tid * 8 + 4096]);
    aptr += 32;
    bptr += 8192;
  };
  auto compute = [&](int buf) {
    bf16x8 ah[4], bh[4];
#pragma unroll
    for (int i = 0; i < 4; ++i) ah[i] = *(const bf16x8*)(&As[buf][aoff[i]]);
#pragma unroll
    for (int j = 0; j < 4; ++j) bh[j] = *(const bf16x8*)(&Bs[buf][boff[j]]);
#pragma unroll
    for (int i = 0; i < 4; ++i)
#pragma unroll
      for (int j = 0; j < 4; ++j)
        acc[i][j] = __builtin_amdgcn_mfma_f32_16x16x32_bf16(ah[i], bh[j], acc[i][j], 0, 0, 0);
  };

  prefetch(0);
  prefetch(1);
  asm volatile("s_waitcnt vmcnt(3)" ::: "memory");
  __builtin_amdgcn_s_barrier();
  __builtin_amdgcn_sched_barrier(0);

#define STEP(BUFC, BUFP) { prefetch(BUFP); compute(BUFC); \
    asm volatile("s_waitcnt vmcnt(3)" ::: "memory"); \
    __builtin_amdgcn_s_barrier(); \
    __builtin_amdgcn_sched_barrier(0); }
  for (int tt = 0; tt < 31; ++tt) {
    STEP(0, 2)
    STEP(1, 0)
    STEP(2, 1)
  }
#undef STEP
  compute(0);
  asm volatile("s_waitcnt vmcnt(0)" ::: "memory");
  __builtin_amdgcn_s_barrier();
  __builtin_amdgcn_sched_barrier(0);
  compute(1);

  float bb[4];
#pragma unroll
  for (int j = 0; j < 4; ++j) bb[j] = b1[col0 + n_base + j * 16 + l15];
#pragma unroll
  for (int i = 0; i < 4; ++i) {
    const int rbase = row0 + m_base + i * 16 + l4 * 4;
#pragma unroll
    for (int j = 0; j < 4; ++j) {
      const int c = col0 + n_base + j * 16 + l15;
#pragma unroll
      for (int q = 0; q < 4; ++q) {
        const float v = fmaxf(acc[i][j][q] + bb[j], 0.f);
        h[(size_t)(rbase + q) * HID + c] = f2bf(v);
      }
    }
  }
}

// ---------------- GEMM2: out = h @ W2 + b2 via bf16 MFMA ----------------
__global__ __launch_bounds__(256) void gemm2_kernel(const ushort_t* __restrict__ h,
                                                    const ushort_t* __restrict__ W2t,
                                                    const float* __restrict__ b2,
                                                    float* __restrict__ out) {
  const int tid = threadIdx.x;
  const int lane = tid & 63, wv = tid >> 6;
  const int rowt = wv & 1, colt = wv >> 1;
  const int l15 = lane & 15, l4 = lane >> 4;
  const int row0 = blockIdx.x * 32 + rowt * 16;
  const int col  = colt * 16 + l15;

  f32x4 acc = (f32x4){0.f, 0.f, 0.f, 0.f};
  const ushort_t* ha = h + (size_t)(row0 + l15) * HID + l4 * 8;
  const ushort_t* wb = W2t + (size_t)col * HID + l4 * 8;
#pragma unroll 8
  for (int k0 = 0; k0 < HID; k0 += 32) {
    const bf16x8 av = *(const bf16x8*)(ha + k0);
    const bf16x8 bv = *(const bf16x8*)(wb + k0);
    acc = __builtin_amdgcn_mfma_f32_16x16x32_bf16(av, bv, acc, 0, 0, 0);
  }
  if (col < OUT_DIM) {
    const float bias = b2[col];
#pragma unroll
    for (int q = 0; q < 4; ++q) {
      const int r = row0 + l4 * 4 + q;
      out[(size_t)r * OUT_DIM + col] = acc[q] + bias;
    }
  }
}

extern "C" void kernel_launch(void* const* d_in, const int* in_sizes, int n_in,
                              void* d_out, int out_size, void* d_ws, size_t ws_size,
                              hipStream_t stream) {
  (void)in_sizes; (void)n_in; (void)out_size;
  const float* x      = (const float*)d_in[0];
  const float* coords = (const float*)d_in[1];
  const float* genes  = (const float*)d_in[2];
  const float* W1     = (const float*)d_in[3];
  const float* b1     = (const float*)d_in[4];
  const float* W2     = (const float*)d_in[5];
  const float* b2     = (const float*)d_in[6];
  float* out = (float*)d_out;

  char* ws = (char*)d_ws;
  size_t off = 0;
  auto alloc = [&](size_t bytes) -> void* {
    void* p = ws + off;
    off = (off + bytes + 255) & ~(size_t)255;
    return p;
  };
  ushort_t* Abf    = (ushort_t*)alloc((size_t)N_CELLS * K_PAD * 2);   // 99.6 MB
  ushort_t* hbf    = (ushort_t*)alloc((size_t)N_CELLS * HID * 2);     // 33.5 MB
  ushort_t* Bh     = (ushort_t*)alloc((size_t)4 * NT * 8192 * 2);     // 6.2 MB
  ushort_t* W2t    = (ushort_t*)alloc((size_t)32 * HID * 2);          // 64 KB
  float*    GwsT   = (float*)alloc((size_t)64 * N_CELLS * 4);
  float*    VwsT   = (float*)alloc((size_t)64 * N_CELLS * 4);
  float*    lamT   = (float*)alloc((size_t)8 * N_CELLS * 4);
  int*      nidx   = (int*)alloc((size_t)N_CELLS * 8 * 4);
  double*   part   = (double*)alloc((size_t)128 * 32 * 8);
  float*    meanv  = (float*)alloc(G_GENES * 4);
  int*      binCnt = (int*)alloc((size_t)NBINS * 4);
  int*      binSt  = (int*)alloc((size_t)(NBINS + 1) * 4);
  int*      cursor = (int*)alloc((size_t)NBINS * 4);
  int*      binOf  = (int*)alloc((size_t)N_CELLS * 4);
  int*      binPts = (int*)alloc((size_t)N_CELLS * 4);
  float2*   sxy    = (float2*)alloc((size_t)N_CELLS * 8);
  if (off > ws_size) return;

  hipMemsetAsync(binCnt, 0, (size_t)NBINS * 4, stream);

  hipLaunchKernelGGL(fused_pre,   dim3(2624),  dim3(256), 0, stream,
                     x, W1, W2, genes, coords, Abf, Bh, W2t, part, binCnt, binOf);
  hipLaunchKernelGGL(scan_fin,    dim3(2),     dim3(256), 0, stream, binCnt, binSt, cursor, part, meanv);
  hipLaunchKernelGGL(bin_scatter, dim3(64),    dim3(256), 0, stream, coords, binOf, cursor, binPts, sxy);
  hipLaunchKernelGGL(knn_search,  dim3(128),   dim3(128), 0, stream, coords, binSt, binPts, sxy, nidx);
  hipLaunchKernelGGL(gram_kernel, dim3(4096),  dim3(256), 0, stream, genes, meanv, nidx, GwsT);
  hipLaunchKernelGGL(jacobi_kernel, dim3(256), dim3(64),  0, stream, GwsT, VwsT, lamT);
  hipLaunchKernelGGL(recon_kernel,  dim3(4096), dim3(256), 0, stream, genes, meanv, nidx, VwsT, lamT, Abf);
  hipLaunchKernelGGL(gemm1_kernel,  dim3(512),  dim3(512), 0, stream, Abf, Bh, b1, hbf);
  hipLaunchKernelGGL(gemm2_kernel,  dim3(512),  dim3(256), 0, stream, hbf, W2t, b2, out);
}

// Round 9
// 287.263 us; speedup vs baseline: 6.9660x; 1.0203x over previous
//
#include <hip/hip_runtime.h>
#include <hip/hip_bf16.h>
#include <math.h>

#define N_CELLS 16384
#define G_GENES 32
#define IN_DIM  2000
#define HID     1024
#define OUT_DIM 30
#define K_TOT   3024      // IN_DIM + 1024
#define K_PAD   3040      // 95 * 32
#define NT      95
#define GRID_B  128
#define NBINS   (GRID_B * GRID_B)
#define SCELL   (100.0f / (float)GRID_B)
#define CSCALE  0.37796447300922722721f   // 1/sqrt(7)

typedef unsigned short ushort_t;
typedef __attribute__((ext_vector_type(8))) short bf16x8;
typedef __attribute__((ext_vector_type(4))) short bf16x4;
typedef __attribute__((ext_vector_type(4))) float f32x4;

__device__ __forceinline__ ushort_t f2bf(float v) {
  return __builtin_bit_cast(ushort_t, __float2bfloat16(v));
}

// global_load_lds: 16B per lane, LDS dest = wave-uniform base + lane*16
__device__ __forceinline__ void glds16(const void* g, void* l) {
  __builtin_amdgcn_global_load_lds(
      (const __attribute__((address_space(1))) unsigned int*)g,
      (__attribute__((address_space(3))) unsigned int*)l, 16, 0, 0);
}

// ============ fused pre-pass: packb | packw2 | convx | mean_part | bin_count ============
__global__ __launch_bounds__(256) void fused_pre(const float* __restrict__ x,
                                                 const float* __restrict__ W1,
                                                 const float* __restrict__ W2,
                                                 const float* __restrict__ genes,
                                                 const float* __restrict__ coords,
                                                 ushort_t* __restrict__ Abf,
                                                 ushort_t* __restrict__ Bh,
                                                 ushort_t* __restrict__ W2t,
                                                 double* __restrict__ part,
                                                 int* __restrict__ cnt,
                                                 int* __restrict__ binOf) {
  __shared__ float L[32][260];
  __shared__ double red[256];
  const int bid = blockIdx.x;
  const int tid = threadIdx.x;

  if (bid < 380) {
    // ---- packb: W1^T -> swizzled bf16 tiles [4 cb][95 t][256n x 32k] ----
    const int cb = bid / NT, t = bid % NT;
    const int k0 = t * 32, n0 = cb * 256;
    {
      const int kl = tid >> 3;
      const int nw = tid & 7;
#pragma unroll
      for (int u = 0; u < 8; ++u) {
        const int nl = (nw + u * 8) * 4;
        float4 v = make_float4(0.f, 0.f, 0.f, 0.f);
        if (k0 + kl < K_TOT) v = *(const float4*)(W1 + (size_t)(k0 + kl) * HID + n0 + nl);
        L[kl][nl + 0] = v.x; L[kl][nl + 1] = v.y; L[kl][nl + 2] = v.z; L[kl][nl + 3] = v.w;
      }
    }
    __syncthreads();
    const size_t tileBase = ((size_t)cb * NT + t) * 8192;
    const int n = tid;
#pragma unroll
    for (int q = 0; q < 4; ++q) {
      const int cdata = q ^ ((n >> 1) & 3);
      ushort_t hi[8];
#pragma unroll
      for (int e = 0; e < 8; ++e) {
        const int kl = cdata * 8 + e;
        const float v = (k0 + kl < K_TOT) ? L[kl][n] : 0.f;
        hi[e] = f2bf(v);
      }
      *(bf16x8*)(Bh + tileBase + ((size_t)n * 4 + q) * 8) = *(const bf16x8*)hi;
    }
  } else if (bid < 384) {
    // ---- packw2 ----
    const int k = (bid - 380) * 256 + tid;
#pragma unroll
    for (int o = 0; o < 32; ++o) {
      const float v = (o < OUT_DIM) ? W2[k * OUT_DIM + o] : 0.f;
      W2t[o * HID + k] = f2bf(v);
    }
  } else if (bid < 2432) {
    // ---- convx: 8 rows per block ----
    const int rbase = (bid - 384) * 8;
#pragma unroll
    for (int rr = 0; rr < 8; ++rr) {
      const int row = rbase + rr;
      if (tid < 250) {
#pragma unroll
        for (int ph = 0; ph < 2; ++ph) {
          const int col = ph * 1000 + tid * 4;
          const float4 v = *(const float4*)(x + (size_t)row * IN_DIM + col);
          ushort_t o[4] = { f2bf(v.x), f2bf(v.y), f2bf(v.z), f2bf(v.w) };
          *(bf16x4*)(Abf + (size_t)row * K_PAD + col) = *(const bf16x4*)o;
        }
      } else if (tid < 252) {
        const bf16x8 z = (bf16x8){0, 0, 0, 0, 0, 0, 0, 0};
        *(bf16x8*)(Abf + (size_t)row * K_PAD + K_TOT + (tid - 250) * 8) = z;
      }
    }
  } else if (bid < 2560) {
    // ---- mean_part ----
    const int b = bid - 2432;
    const int g = tid & 31, cs = tid >> 5;
    double acc = 0.0;
#pragma unroll
    for (int it = 0; it < 16; ++it) {
      const int cell = b * 128 + cs + it * 8;
      acc += (double)genes[cell * G_GENES + g];
    }
    red[tid] = acc;
    __syncthreads();
    if (tid < 32) {
      double s = red[tid];
#pragma unroll
      for (int u = 1; u < 8; ++u) s += red[tid + u * 32];
      part[b * 32 + tid] = s;
    }
  } else {
    // ---- bin_count ----
    const int i = (bid - 2560) * 256 + tid;
    const float2 p = ((const float2*)coords)[i];
    const float inv_s = (float)GRID_B / 100.0f;
    const int bx = min(GRID_B - 1, max(0, (int)(p.x * inv_s)));
    const int by = min(GRID_B - 1, max(0, (int)(p.y * inv_s)));
    const int b = by * GRID_B + bx;
    binOf[i] = b;
    atomicAdd(&cnt[b], 1);
  }
}

// ============ block 0: bin prefix-scan | block 1: mean finalize ============
__global__ __launch_bounds__(256) void scan_fin(const int* __restrict__ cnt,
                                                int* __restrict__ binStart,
                                                int* __restrict__ cursor,
                                                const double* __restrict__ part,
                                                float* __restrict__ meanv) {
  const int tid = threadIdx.x;
  if (blockIdx.x == 0) {
    __shared__ int ps[256];
    int s = 0;
    for (int i = 0; i < 64; ++i) s += cnt[tid * 64 + i];
    ps[tid] = s;
    __syncthreads();
    for (int off = 1; off < 256; off <<= 1) {
      const int add = (tid >= off) ? ps[tid - off] : 0;
      __syncthreads();
      ps[tid] += add;
      __syncthreads();
    }
    int run = ps[tid] - s;
    for (int i = 0; i < 64; ++i) {
      const int b = tid * 64 + i;
      binStart[b] = run;
      cursor[b] = run;
      run += cnt[b];
    }
    if (tid == 255) binStart[NBINS] = run;
  } else {
    if (tid < 32) {
      double s = 0.0;
      for (int b = 0; b < 128; ++b) s += part[b * 32 + tid];
      meanv[tid] = (float)(s / (double)N_CELLS);
    }
  }
}

// ---------------- scatter: also build bin-sorted coords stream ----------------
__global__ __launch_bounds__(256) void bin_scatter(const float* __restrict__ coords,
                                                   const int* __restrict__ binOf,
                                                   int* __restrict__ cursor,
                                                   int* __restrict__ binPts,
                                                   float2* __restrict__ sxy) {
  const int i = blockIdx.x * 256 + threadIdx.x;
  const float2 p = ((const float2*)coords)[i];
  const int pos = atomicAdd(&cursor[binOf[i]], 1);
  binPts[pos] = i;
  sxy[pos] = p;
}

// ---------------- kNN in BIN-SORTED order: wave lanes own neighboring cells ----------------
__global__ __launch_bounds__(128) void knn_search(const int* __restrict__ binStart,
                                                  const int* __restrict__ binPts,
                                                  const float2* __restrict__ sxy,
                                                  int* __restrict__ nidx) {
  const int rank = blockIdx.x * 128 + threadIdx.x;   // sorted position
  const int cell = binPts[rank];
  const float2 qv = sxy[rank];                       // == coords[cell], bit-identical
  const float qx = qv.x, qy = qv.y;
  const float sqi = __fadd_rn(__fmul_rn(qx, qx), __fmul_rn(qy, qy));
  const float inv_s = (float)GRID_B / 100.0f;
  const int bx = min(GRID_B - 1, max(0, (int)(qx * inv_s)));
  const int by = min(GRID_B - 1, max(0, (int)(qy * inv_s)));

  unsigned long long kk[8];
#pragma unroll
  for (int i = 0; i < 8; ++i) kk[i] = ~0ull;

  auto scan_seg = [&](int s, int e) {
    for (int p = s; p < e; ++p) {
      const float2 pc = sxy[p];
      const int j = binPts[p];
      const float sqj = __fadd_rn(__fmul_rn(pc.x, pc.x), __fmul_rn(pc.y, pc.y));
      const float dot = __fmaf_rn(qy, pc.y, __fmul_rn(qx, pc.x));
      const float d2  = __fsub_rn(__fadd_rn(sqi, sqj), __fmul_rn(2.0f, dot));
      unsigned int sb = __float_as_uint(d2);
      sb = (sb & 0x80000000u) ? ~sb : (sb | 0x80000000u);
      unsigned long long key = ((unsigned long long)sb << 32) | (unsigned int)j;
      if (key < kk[7]) {
#pragma unroll
        for (int q2 = 0; q2 < 8; ++q2) {
          const bool lt = key < kk[q2];
          const unsigned long long tmp = kk[q2];
          kk[q2] = lt ? key : kk[q2];
          key = lt ? tmp : key;
        }
      }
    }
  };

  bool done = false;
  for (int r = 0; r < GRID_B; ++r) {
    if (!done) {
      if (r == 0) {
        const int b = by * GRID_B + bx;
        scan_seg(binStart[b], binStart[b + 1]);
      } else {
        const int xlo = max(0, bx - r), xhi = min(GRID_B - 1, bx + r);
        if (by - r >= 0) {
          const int b0 = (by - r) * GRID_B;
          scan_seg(binStart[b0 + xlo], binStart[b0 + xhi + 1]);
        }
        if (by + r < GRID_B) {
          const int b0 = (by + r) * GRID_B;
          scan_seg(binStart[b0 + xlo], binStart[b0 + xhi + 1]);
        }
        for (int dy = -r + 1; dy <= r - 1; ++dy) {
          const int yy = by + dy;
          if (yy < 0 || yy >= GRID_B) continue;
          if (bx - r >= 0) { const int b = yy * GRID_B + bx - r; scan_seg(binStart[b], binStart[b + 1]); }
          if (bx + r < GRID_B) { const int b = yy * GRID_B + bx + r; scan_seg(binStart[b], binStart[b + 1]); }
        }
      }
      if (kk[7] != ~0ull) {
        const unsigned int sb = (unsigned int)(kk[7] >> 32);
        const float wd2 = __uint_as_float((sb & 0x80000000u) ? (sb ^ 0x80000000u) : ~sb);
        const float bnd = (float)r * SCELL;
        if (wd2 < bnd * bnd * 0.998f - 0.05f) done = true;
      }
    }
    if (!__any(!done)) break;
  }
#pragma unroll
  for (int i = 0; i < 8; ++i) nidx[cell * 8 + i] = (int)(kk[i] & 0xFFFFFFFFu);
}

// ---------------- Gram -> transposed [64][N_CELLS] layout ----------------
__global__ __launch_bounds__(256) void gram_kernel(const float* __restrict__ genes,
                                                   const float* __restrict__ meanv,
                                                   const int* __restrict__ nidx,
                                                   float* __restrict__ GwsT) {
  const int wv = threadIdx.x >> 6, lane = threadIdx.x & 63;
  const int bidl = (blockIdx.x & 7) * 512 + (blockIdx.x >> 3);   // bijective 4096
  const int cell = bidl * 4 + wv;
  __shared__ float A[4][8][33];
#pragma unroll
  for (int q = 0; q < 4; ++q) {
    const int e = lane + (q << 6);
    const int n = e >> 5, g = e & 31;
    const int src = nidx[cell * 8 + n];
    A[wv][n][g] = (genes[src * G_GENES + g] - meanv[g]) * CSCALE;
  }
  __syncthreads();
  const int i = lane >> 3, j = lane & 7;
  float acc = 0.f;
#pragma unroll
  for (int g = 0; g < 32; ++g) acc = fmaf(A[wv][i][g], A[wv][j][g], acc);
  GwsT[(size_t)lane * N_CELLS + cell] = acc;
}

// ---------------- 8x8 Jacobi: lane=cell, all I/O coalesced ----------------
__global__ __launch_bounds__(64) void jacobi_kernel(const float* __restrict__ GwsT,
                                                    float* __restrict__ VwsT,
                                                    float* __restrict__ lamT) {
  const int cell = blockIdx.x * 64 + threadIdx.x;
  float Gm[8][8], V[8][8];
#pragma unroll
  for (int e = 0; e < 64; ++e) Gm[e >> 3][e & 7] = GwsT[(size_t)e * N_CELLS + cell];
#pragma unroll
  for (int i = 0; i < 8; ++i)
#pragma unroll
    for (int j = 0; j < 8; ++j) V[i][j] = (i == j) ? 1.0f : 0.0f;

  for (int sweep = 0; sweep < 6; ++sweep) {
#pragma unroll
    for (int p = 0; p < 7; ++p) {
#pragma unroll
      for (int q = p + 1; q < 8; ++q) {
        const float apq = Gm[p][q];
        const float app = Gm[p][p], aqq = Gm[q][q];
        float t;
        if (apq != 0.0f) {
          const float tau = (aqq - app) / (2.0f * apq);
          const float r = sqrtf(fmaf(tau, tau, 1.0f));
          t = copysignf(1.0f, tau) / (fabsf(tau) + r);
        } else {
          t = 0.0f;
        }
        const float c = 1.0f / sqrtf(fmaf(t, t, 1.0f));
        const float s = t * c;
#pragma unroll
        for (int r2 = 0; r2 < 8; ++r2) {
          const float gp = Gm[p][r2], gq = Gm[q][r2];
          Gm[p][r2] = fmaf(c, gp, -s * gq);
          Gm[q][r2] = fmaf(s, gp,  c * gq);
        }
#pragma unroll
        for (int r2 = 0; r2 < 8; ++r2) {
          const float gp = Gm[r2][p], gq = Gm[r2][q];
          Gm[r2][p] = fmaf(c, gp, -s * gq);
          Gm[r2][q] = fmaf(s, gp,  c * gq);
        }
#pragma unroll
        for (int r2 = 0; r2 < 8; ++r2) {
          const float vp = V[r2][p], vq = V[r2][q];
          V[r2][p] = fmaf(c, vp, -s * vq);
          V[r2][q] = fmaf(s, vp,  c * vq);
        }
      }
    }
  }
#pragma unroll
  for (int e = 0; e < 64; ++e) VwsT[(size_t)e * N_CELLS + cell] = V[e >> 3][e & 7];
#pragma unroll
  for (int m = 0; m < 8; ++m) lamT[(size_t)m * N_CELLS + cell] = Gm[m][m];
}

// ---------------- covet (bf16) -> Abf cols 2000..3023 ----------------
__global__ __launch_bounds__(256) void recon_kernel(const float* __restrict__ genes,
                                                    const float* __restrict__ meanv,
                                                    const int* __restrict__ nidx,
                                                    const float* __restrict__ VwsT,
                                                    const float* __restrict__ lamT,
                                                    ushort_t* __restrict__ Abf) {
  const int wv = threadIdx.x >> 6, lane = threadIdx.x & 63;
  const int cell = blockIdx.x * 4 + wv;
  __shared__ float A[4][8][33];
  __shared__ float Ws[4][8][33];
  __shared__ float Vs[4][64];
  __shared__ float lamS[4][8];
#pragma unroll
  for (int q = 0; q < 4; ++q) {
    const int e = lane + (q << 6);
    const int n = e >> 5, g = e & 31;
    const int src = nidx[cell * 8 + n];
    A[wv][n][g] = (genes[src * G_GENES + g] - meanv[g]) * CSCALE;
  }
  Vs[wv][lane] = VwsT[(size_t)lane * N_CELLS + cell];
  if (lane < 8) lamS[wv][lane] = lamT[(size_t)lane * N_CELLS + cell];
  __syncthreads();

  float maxl = 0.f;
#pragma unroll
  for (int m = 0; m < 8; ++m) maxl = fmaxf(maxl, lamS[wv][m]);
  const float thr = maxl * 1e-8f;

#pragma unroll
  for (int q = 0; q < 4; ++q) {
    const int e = lane + (q << 6);
    const int m = e >> 5, g = e & 31;
    float acc = 0.f;
#pragma unroll
    for (int i = 0; i < 8; ++i) acc = fmaf(Vs[wv][i * 8 + m], A[wv][i][g], acc);
    const float l = lamS[wv][m];
    const float scm = (l > thr) ? sqrtf(1.0f / sqrtf(l)) : 0.0f;
    Ws[wv][m][g] = acc * scm;
  }
  __syncthreads();
  ushort_t* dst = Abf + (size_t)cell * K_PAD + IN_DIM;
#pragma unroll
  for (int r = 0; r < 16; ++r) {
    const int o = (r << 6) + lane;
    const int g = o >> 5, hh = o & 31;
    float acc = 0.f;
#pragma unroll
    for (int m = 0; m < 8; ++m) acc = fmaf(Ws[wv][m][g], Ws[wv][m][hh], acc);
    dst[o] = f2bf(acc);
  }
}

// ---------------- GEMM1: deeper pipeline — A 4-buf (3-iter lead), B 3-buf (2-iter) ----------------
// Per iter issue order: B(t+2)x2 then A(t+3); vmcnt(4) retires exactly {A(t+1), B(t+1)x2}.
__global__ __launch_bounds__(512, 4) void gemm1_kernel(const ushort_t* __restrict__ Abf,
                                                       const ushort_t* __restrict__ Bh,
                                                       const float* __restrict__ b1,
                                                       ushort_t* __restrict__ h) {
  __shared__ ushort_t As[4][4096];   // 32 KB
  __shared__ ushort_t Bs[3][8192];   // 48 KB  -> 80 KB total, 2 blocks/CU

  const int tid = threadIdx.x;
  const int id  = blockIdx.x;
  const int xcd = id & 7, local = id >> 3;
  const int rb  = (xcd << 4) + (local & 15);
  const int cb  = local >> 4;
  const int row0 = rb << 7, col0 = cb << 8;

  const int lane = tid & 63, wv = tid >> 6;
  const int m_base = (wv >> 2) << 6, n_base = (wv & 3) << 6;
  const int l15 = lane & 15, l4 = lane >> 4;

  const int arow = tid >> 2, acpos = tid & 3;
  const int acdata = acpos ^ ((arow >> 1) & 3);
  const ushort_t* aptr = Abf + (size_t)(row0 + arow) * K_PAD + acdata * 8;
  const ushort_t* bptr = Bh + (size_t)cb * NT * 8192 + tid * 8;

  int aoff[4], boff[4];
#pragma unroll
  for (int i = 0; i < 4; ++i) {
    const int r = m_base + i * 16 + l15;
    aoff[i] = r * 32 + (l4 ^ ((r >> 1) & 3)) * 8;
  }
#pragma unroll
  for (int j = 0; j < 4; ++j) {
    const int r = n_base + j * 16 + l15;
    boff[j] = r * 32 + (l4 ^ ((r >> 1) & 3)) * 8;
  }

  f32x4 acc[4][4];
#pragma unroll
  for (int i = 0; i < 4; ++i)
#pragma unroll
    for (int j = 0; j < 4; ++j) acc[i][j] = (f32x4){0.f, 0.f, 0.f, 0.f};

  auto gldsA = [&](int buf) {
    glds16(aptr, &As[buf][tid * 8]);
    aptr += 32;
  };
  auto gldsB = [&](int buf) {
    glds16(bptr,        &Bs[buf][tid * 8]);
    glds16(bptr + 4096, &Bs[buf][tid * 8 + 4096]);
    bptr += 8192;
  };
  auto compute = [&](int ab, int bb) {
    bf16x8 ah[4], bh[4];
#pragma unroll
    for (int i = 0; i < 4; ++i) ah[i] = *(const bf16x8*)(&As[ab][aoff[i]]);
#pragma unroll
    for (int j = 0; j < 4; ++j) bh[j] = *(const bf16x8*)(&Bs[bb][boff[j]]);
#pragma unroll
    for (int i = 0; i < 4; ++i)
#pragma unroll
      for (int j = 0; j < 4; ++j)
        acc[i][j] = __builtin_amdgcn_mfma_f32_16x16x32_bf16(ah[i], bh[j], acc[i][j], 0, 0, 0);
  };

  // prologue: queue = [A0, B0x2, A1, B1x2, A2]; vmcnt(4) retires A0,B0x2
  gldsA(0); gldsB(0);
  gldsA(1); gldsB(1);
  gldsA(2);
  asm volatile("s_waitcnt vmcnt(4)" ::: "memory");
  __builtin_amdgcn_s_barrier();
  __builtin_amdgcn_sched_barrier(0);

  // steady state: t = 0..91
  for (int t = 0; t < 92; ++t) {
    gldsB((t + 2) % 3);
    gldsA((t + 3) & 3);
    compute(t & 3, t % 3);
    asm volatile("s_waitcnt vmcnt(4)" ::: "memory");   // retires A(t+1), B(t+1)x2
    __builtin_amdgcn_s_barrier();
    __builtin_amdgcn_sched_barrier(0);
  }
  // t = 92: issue B(94); vmcnt(3) retires A93,B93x2
  gldsB(94 % 3);
  compute(92 & 3, 92 % 3);
  asm volatile("s_waitcnt vmcnt(3)" ::: "memory");
  __builtin_amdgcn_s_barrier();
  __builtin_amdgcn_sched_barrier(0);
  // t = 93: drain remaining A94,B94x2
  compute(93 & 3, 93 % 3);
  asm volatile("s_waitcnt vmcnt(0)" ::: "memory");
  __builtin_amdgcn_s_barrier();
  __builtin_amdgcn_sched_barrier(0);
  // t = 94
  compute(94 & 3, 94 % 3);

  float bb[4];
#pragma unroll
  for (int j = 0; j < 4; ++j) bb[j] = b1[col0 + n_base + j * 16 + l15];
#pragma unroll
  for (int i = 0; i < 4; ++i) {
    const int rbase = row0 + m_base + i * 16 + l4 * 4;
#pragma unroll
    for (int j = 0; j < 4; ++j) {
      const int c = col0 + n_base + j * 16 + l15;
#pragma unroll
      for (int q = 0; q < 4; ++q) {
        const float v = fmaxf(acc[i][j][q] + bb[j], 0.f);
        h[(size_t)(rbase + q) * HID + c] = f2bf(v);
      }
    }
  }
}

// ---------------- GEMM2: out = h @ W2 + b2 via bf16 MFMA ----------------
__global__ __launch_bounds__(256) void gemm2_kernel(const ushort_t* __restrict__ h,
                                                    const ushort_t* __restrict__ W2t,
                                                    const float* __restrict__ b2,
                                                    float* __restrict__ out) {
  const int tid = threadIdx.x;
  const int lane = tid & 63, wv = tid >> 6;
  const int rowt = wv & 1, colt = wv >> 1;
  const int l15 = lane & 15, l4 = lane >> 4;
  const int row0 = blockIdx.x * 32 + rowt * 16;
  const int col  = colt * 16 + l15;

  f32x4 acc = (f32x4){0.f, 0.f, 0.f, 0.f};
  const ushort_t* ha = h + (size_t)(row0 + l15) * HID + l4 * 8;
  const ushort_t* wb = W2t + (size_t)col * HID + l4 * 8;
#pragma unroll 8
  for (int k0 = 0; k0 < HID; k0 += 32) {
    const bf16x8 av = *(const bf16x8*)(ha + k0);
    const bf16x8 bv = *(const bf16x8*)(wb + k0);
    acc = __builtin_amdgcn_mfma_f32_16x16x32_bf16(av, bv, acc, 0, 0, 0);
  }
  if (col < OUT_DIM) {
    const float bias = b2[col];
#pragma unroll
    for (int q = 0; q < 4; ++q) {
      const int r = row0 + l4 * 4 + q;
      out[(size_t)r * OUT_DIM + col] = acc[q] + bias;
    }
  }
}

extern "C" void kernel_launch(void* const* d_in, const int* in_sizes, int n_in,
                              void* d_out, int out_size, void* d_ws, size_t ws_size,
                              hipStream_t stream) {
  (void)in_sizes; (void)n_in; (void)out_size;
  const float* x      = (const float*)d_in[0];
  const float* coords = (const float*)d_in[1];
  const float* genes  = (const float*)d_in[2];
  const float* W1     = (const float*)d_in[3];
  const float* b1     = (const float*)d_in[4];
  const float* W2     = (const float*)d_in[5];
  const float* b2     = (const float*)d_in[6];
  float* out = (float*)d_out;

  char* ws = (char*)d_ws;
  size_t off = 0;
  auto alloc = [&](size_t bytes) -> void* {
    void* p = ws + off;
    off = (off + bytes + 255) & ~(size_t)255;
    return p;
  };
  ushort_t* Abf    = (ushort_t*)alloc((size_t)N_CELLS * K_PAD * 2);   // 99.6 MB
  ushort_t* hbf    = (ushort_t*)alloc((size_t)N_CELLS * HID * 2);     // 33.5 MB
  ushort_t* Bh     = (ushort_t*)alloc((size_t)4 * NT * 8192 * 2);     // 6.2 MB
  ushort_t* W2t    = (ushort_t*)alloc((size_t)32 * HID * 2);          // 64 KB
  float*    GwsT   = (float*)alloc((size_t)64 * N_CELLS * 4);
  float*    VwsT   = (float*)alloc((size_t)64 * N_CELLS * 4);
  float*    lamT   = (float*)alloc((size_t)8 * N_CELLS * 4);
  int*      nidx   = (int*)alloc((size_t)N_CELLS * 8 * 4);
  double*   part   = (double*)alloc((size_t)128 * 32 * 8);
  float*    meanv  = (float*)alloc(G_GENES * 4);
  int*      binCnt = (int*)alloc((size_t)NBINS * 4);
  int*      binSt  = (int*)alloc((size_t)(NBINS + 1) * 4);
  int*      cursor = (int*)alloc((size_t)NBINS * 4);
  int*      binOf  = (int*)alloc((size_t)N_CELLS * 4);
  int*      binPts = (int*)alloc((size_t)N_CELLS * 4);
  float2*   sxy    = (float2*)alloc((size_t)N_CELLS * 8);
  if (off > ws_size) return;

  hipMemsetAsync(binCnt, 0, (size_t)NBINS * 4, stream);

  hipLaunchKernelGGL(fused_pre,   dim3(2624),  dim3(256), 0, stream,
                     x, W1, W2, genes, coords, Abf, Bh, W2t, part, binCnt, binOf);
  hipLaunchKernelGGL(scan_fin,    dim3(2),     dim3(256), 0, stream, binCnt, binSt, cursor, part, meanv);
  hipLaunchKernelGGL(bin_scatter, dim3(64),    dim3(256), 0, stream, coords, binOf, cursor, binPts, sxy);
  hipLaunchKernelGGL(knn_search,  dim3(128),   dim3(128), 0, stream, binSt, binPts, sxy, nidx);
  hipLaunchKernelGGL(gram_kernel, dim3(4096),  dim3(256), 0, stream, genes, meanv, nidx, GwsT);
  hipLaunchKernelGGL(jacobi_kernel, dim3(256), dim3(64),  0, stream, GwsT, VwsT, lamT);
  hipLaunchKernelGGL(recon_kernel,  dim3(4096), dim3(256), 0, stream, genes, meanv, nidx, VwsT, lamT, Abf);
  hipLaunchKernelGGL(gemm1_kernel,  dim3(512),  dim3(512), 0, stream, Abf, Bh, b1, hbf);
  hipLaunchKernelGGL(gemm2_kernel,  dim3(512),  dim3(256), 0, stream, hbf, W2t, b2, out);
}